// Round 5
// baseline (2865.887 us; speedup 1.0000x reference)
//
#include <hip/hip_runtime.h>
#include <hip/hip_bf16.h>

#define NN 50000
#define NE 800000
#define NG 3
#define NB 256
#define NSCB 196  // ceil(NN/256)

#define OFF_FUSED ((size_t)0)
#define OFF_EMB   ((size_t)NN * 64)
#define OFF_G     (OFF_EMB + (size_t)NN * 256)
#define OFF_HID   (OFF_G + (size_t)NB * 64)
#define OFF_ATTN  (OFF_HID + (size_t)3 * NN * 64)

// k_vsum split geometry
#define VS_CH 1024                 // n per block
#define VS_S  49                   // ceil(NN / VS_CH)
#define VS_KS (VS_S * 4)           // partial slices (per wave)

typedef unsigned short u16;

__device__ __forceinline__ float bf2f(u16 u) {
  union { unsigned int i; float f; } v; v.i = ((unsigned int)u) << 16; return v.f;
}
__device__ __forceinline__ u16 f2bf(float f) {
  unsigned int x = __float_as_uint(f);
  unsigned int r = (x + 0x7FFFu + ((x >> 16) & 1u)) >> 16;
  return (u16)r;
}
__device__ __forceinline__ float ldf(const void* p, size_t i, int f32) {
  return f32 ? ((const float*)p)[i] : bf2f(((const u16*)p)[i]);
}
__device__ __forceinline__ int ld_src(const void* ei, int e, int i64) {
  return i64 ? (int)((const long long*)ei)[e] : ((const int*)ei)[e];
}
__device__ __forceinline__ int ld_dst(const void* ei, int e, int i64) {
  return i64 ? (int)((const long long*)ei)[(size_t)NE + e] : ((const int*)ei)[(size_t)NE + e];
}

// ---- dtype detection ----
__global__ void k_detect(const void* x, const void* ei, int* flags) {
  if (threadIdx.x != 0 || blockIdx.x != 0) return;
  const u16* xw = (const u16*)x;
  int sane = 0;
  for (int i = 0; i < 64; ++i) {
    unsigned ex = (xw[2 * i] >> 7) & 0xFF;  // exponent field if bf16
    sane += (ex >= 96 && ex <= 141);
  }
  flags[0] = (sane < 48) ? 1 : 0;  // 1 => inputs are float32
  const int* e32 = (const int*)ei;
  int zeros = 0;
  for (int t = 1; t < 32; t += 2) zeros += (e32[t] == 0);
  flags[1] = (zeros >= 12) ? 1 : 0;  // 1 => edge_index is int64
}

// ---- degree accumulation ----
__global__ void k_deg(const void* ei, const void* aew, const int* __restrict__ flags,
                      float* __restrict__ deg, unsigned* __restrict__ cnt) {
  int e = blockIdx.x * 256 + threadIdx.x;
  if (e >= NE) return;
  int f32 = flags[0], i64 = flags[1];
  int d = ld_dst(ei, e, i64);
  atomicAdd(&cnt[d], 1u);
  atomicAdd(&deg[d],          ldf(aew, e, f32));
  atomicAdd(&deg[NN + d],     ldf(aew, (size_t)NE + e, f32));
  atomicAdd(&deg[2 * NN + d], ldf(aew, (size_t)2 * NE + e, f32));
}

__global__ void k_dis(float* __restrict__ deg, const unsigned* __restrict__ cnt,
                      float* __restrict__ dis2) {
  int i = blockIdx.x * 256 + threadIdx.x;
  if (i < 3 * NN) deg[i] = rsqrtf(deg[i] + 1.0f);
  if (i < NN) dis2[i] = rsqrtf((float)cnt[i] + 1.0f);
}

// ---- 3-phase exclusive scan of cnt -> row_ptr ----
__global__ __launch_bounds__(256) void k_sc1(const unsigned* __restrict__ cnt,
                                             unsigned* __restrict__ bsum) {
  int b = blockIdx.x, tid = threadIdx.x, i = b * 256 + tid;
  unsigned v = (i < NN) ? cnt[i] : 0u;
  #pragma unroll
  for (int off = 32; off > 0; off >>= 1) v += __shfl_down(v, off);
  __shared__ unsigned w4[4];
  if ((tid & 63) == 0) w4[tid >> 6] = v;
  __syncthreads();
  if (tid == 0) bsum[b] = w4[0] + w4[1] + w4[2] + w4[3];
}
__global__ __launch_bounds__(256) void k_sc2(const unsigned* __restrict__ bsum,
                                             unsigned* __restrict__ boff,
                                             unsigned* __restrict__ row_ptr) {
  int tid = threadIdx.x, lane = tid & 63, w = tid >> 6;
  unsigned v = (tid < NSCB) ? bsum[tid] : 0u;
  unsigned x = v;
  #pragma unroll
  for (int off = 1; off < 64; off <<= 1) {
    unsigned y = __shfl_up(x, off);
    if (lane >= off) x += y;
  }
  __shared__ unsigned w4[4];
  if (lane == 63) w4[w] = x;
  __syncthreads();
  unsigned woff = 0;
  #pragma unroll
  for (int k = 0; k < 4; ++k) woff += (k < w) ? w4[k] : 0u;
  if (tid < NSCB) boff[tid] = woff + x - v;
  if (tid == 255) row_ptr[NN] = woff + x;
}
__global__ __launch_bounds__(256) void k_sc3(const unsigned* __restrict__ cnt,
                                             const unsigned* __restrict__ boff,
                                             unsigned* __restrict__ row_ptr) {
  int b = blockIdx.x, tid = threadIdx.x, lane = tid & 63, w = tid >> 6;
  int i = b * 256 + tid;
  unsigned v = (i < NN) ? cnt[i] : 0u;
  unsigned x = v;
  #pragma unroll
  for (int off = 1; off < 64; off <<= 1) {
    unsigned y = __shfl_up(x, off);
    if (lane >= off) x += y;
  }
  __shared__ unsigned w4[4];
  if (lane == 63) w4[w] = x;
  __syncthreads();
  unsigned woff = 0;
  #pragma unroll
  for (int k = 0; k < 4; ++k) woff += (k < w) ? w4[k] : 0u;
  if (i < NN) row_ptr[i] = boff[b] + woff + x - v;
}

// ---- CSR fill ----
__global__ void k_fill(const void* ei, const int* __restrict__ flags,
                       const unsigned* __restrict__ row_ptr,
                       unsigned* __restrict__ fill, unsigned* __restrict__ col) {
  int e = blockIdx.x * 256 + threadIdx.x;
  if (e >= NE) return;
  int d = ld_dst(ei, e, flags[1]);
  unsigned pos = row_ptr[d] + atomicAdd(&fill[d], 1u);
  col[pos] = (unsigned)e;
}

// ---- h1[N,64] = x[N,256] @ W1[256,64] via LDS + shfl matvec ----
__global__ __launch_bounds__(256) void k_h1(const void* x, const void* W1,
                                            const int* __restrict__ flags,
                                            float* __restrict__ h1) {
  __shared__ u16 W1L[256 * 64];
  int tid = threadIdx.x;
  int f32 = flags[0];
  for (int i = tid; i < 256 * 64; i += 256)
    W1L[i] = f32 ? f2bf(((const float*)W1)[i]) : ((const u16*)W1)[i];
  __syncthreads();
  int wid = tid >> 6, lane = tid & 63;
  int n = blockIdx.x * 4 + wid;
  if (n >= NN) return;
  float xv[4];
  #pragma unroll
  for (int kk = 0; kk < 4; ++kk) xv[kk] = ldf(x, (size_t)n * 256 + kk * 64 + lane, f32);
  float acc = 0.f;
  #pragma unroll
  for (int kk = 0; kk < 4; ++kk) {
    for (int j = 0; j < 64; ++j) {
      float a = __shfl(xv[kk], j);
      acc += a * bf2f(W1L[(kk * 64 + j) * 64 + lane]);
    }
  }
  h1[(size_t)n * 64 + lane] = acc;
}

// ---- gather layer1 (3 graphs) + attention fusion ----
__global__ __launch_bounds__(256) void k_hidden(
    const float* __restrict__ h1, const void* ei,
    const unsigned* __restrict__ row_ptr, const unsigned* __restrict__ col,
    const void* aew, const float* __restrict__ deg_dis,
    const void* Wf, const void* bfv, const void* qf, const void* b1,
    const int* __restrict__ flags, float* __restrict__ dout) {
  __shared__ u16 WfL[3 * 64 * 64];   // bf16 to halve LDS -> higher occupancy
  __shared__ float qfL[192], bfL[192], b1L[64];
  int tid = threadIdx.x;
  int f32 = flags[0], i64 = flags[1];
  for (int i = tid; i < 3 * 64 * 64; i += 256)
    WfL[i] = f32 ? f2bf(((const float*)Wf)[i]) : ((const u16*)Wf)[i];
  if (tid < 192) { qfL[tid] = ldf(qf, tid, f32); bfL[tid] = ldf(bfv, tid, f32); }
  if (tid < 64) b1L[tid] = ldf(b1, tid, f32);
  __syncthreads();
  int wid = tid >> 6, lane = tid & 63;
  int n = blockIdx.x * 4 + wid;
  if (n >= NN) return;

  float dd0 = deg_dis[n], dd1 = deg_dis[NN + n], dd2 = deg_dis[2 * NN + n];
  float hv = h1[(size_t)n * 64 + lane];
  float acc0 = hv * dd0 * dd0, acc1 = hv * dd1 * dd1, acc2 = hv * dd2 * dd2;

  unsigned beg = row_ptr[n], end = row_ptr[n + 1];
  for (unsigned base = beg; base < end; base += 64) {
    unsigned rem = end - base;
    int m = (rem > 64u) ? 64 : (int)rem;
    int s = 0; float w0 = 0.f, w1 = 0.f, w2 = 0.f;
    if (lane < m) {
      unsigned e = col[base + lane];
      s = ld_src(ei, (int)e, i64);
      w0 = deg_dis[s]          * ldf(aew, e, f32)                  * dd0;
      w1 = deg_dis[NN + s]     * ldf(aew, (size_t)NE + e, f32)     * dd1;
      w2 = deg_dis[2 * NN + s] * ldf(aew, (size_t)2 * NE + e, f32) * dd2;
    }
    for (int j = 0; j < m; ++j) {
      int sj = __shfl(s, j);
      float hs = h1[(size_t)sj * 64 + lane];
      acc0 += hs * __shfl(w0, j);
      acc1 += hs * __shfl(w1, j);
      acc2 += hs * __shfl(w2, j);
    }
  }
  float b1v = b1L[lane];
  float hid0 = fmaxf(acc0 + b1v, 0.f);
  float hid1 = fmaxf(acc1 + b1v, 0.f);
  float hid2 = fmaxf(acc2 + b1v, 0.f);
  dout[OFF_HID + ((size_t)0 * NN + n) * 64 + lane] = hid0;
  dout[OFF_HID + ((size_t)1 * NN + n) * 64 + lane] = hid1;
  dout[OFF_HID + ((size_t)2 * NN + n) * 64 + lane] = hid2;

  float t0 = bfL[lane], t1 = bfL[64 + lane], t2 = bfL[128 + lane];
  for (int k = 0; k < 64; ++k) {
    float h0 = __shfl(hid0, k), h1v = __shfl(hid1, k), h2v = __shfl(hid2, k);
    t0 += h0  * bf2f(WfL[k * 64 + lane]);
    t1 += h1v * bf2f(WfL[4096 + k * 64 + lane]);
    t2 += h2v * bf2f(WfL[8192 + k * 64 + lane]);
  }
  t0 = tanhf(t0); t1 = tanhf(t1); t2 = tanhf(t2);
  float s0 = t0 * qfL[lane], s1 = t1 * qfL[64 + lane], s2 = t2 * qfL[128 + lane];
  #pragma unroll
  for (int off = 32; off > 0; off >>= 1) {
    s0 += __shfl_xor(s0, off);
    s1 += __shfl_xor(s1, off);
    s2 += __shfl_xor(s2, off);
  }
  float mx = fmaxf(s0, fmaxf(s1, s2));
  float e0 = expf(s0 - mx), e1 = expf(s1 - mx), e2 = expf(s2 - mx);
  float inv = 1.0f / (e0 + e1 + e2);
  float a0 = e0 * inv, a1 = e1 * inv, a2 = e2 * inv;
  float fv = a0 * hid0 + a1 * hid1 + a2 * hid2;
  dout[OFF_FUSED + (size_t)n * 64 + lane] = fv;
  if (lane < 3) dout[OFF_ATTN + (size_t)n * 3 + lane] =
                    (lane == 0 ? a0 : (lane == 1 ? a1 : a2));
}

// ---- layer2 fused: agg = sym-aggregate(fused) in 64-dim, emb = relu(agg@W2+b2) ----
__global__ __launch_bounds__(256) void k_emb(
    const void* ei,
    const unsigned* __restrict__ row_ptr, const unsigned* __restrict__ col,
    const float* __restrict__ dis2, const void* W2, const void* b2,
    const int* __restrict__ flags, float* __restrict__ dout) {
  __shared__ u16 W2L[64 * 256];
  __shared__ float b2L[256];
  int tid = threadIdx.x;
  int f32 = flags[0], i64 = flags[1];
  for (int i = tid; i < 64 * 256; i += 256)
    W2L[i] = f32 ? f2bf(((const float*)W2)[i]) : ((const u16*)W2)[i];
  b2L[tid] = ldf(b2, tid, f32);
  __syncthreads();
  const float* fused = dout + OFF_FUSED;
  int wid = tid >> 6, lane = tid & 63;
  int n = blockIdx.x * 4 + wid;
  if (n >= NN) return;
  float dd = dis2[n];
  float av = fused[(size_t)n * 64 + lane] * dd * dd;
  unsigned beg = row_ptr[n], end = row_ptr[n + 1];
  for (unsigned base = beg; base < end; base += 64) {
    unsigned rem = end - base;
    int m = (rem > 64u) ? 64 : (int)rem;
    int s = 0; float w = 0.f;
    if (lane < m) {
      unsigned e = col[base + lane];
      s = ld_src(ei, (int)e, i64);
      w = dis2[s] * dd;
    }
    for (int j = 0; j < m; ++j) {
      int sj = __shfl(s, j);
      av += fused[(size_t)sj * 64 + lane] * __shfl(w, j);
    }
  }
  float acc[4] = {b2L[lane * 4], b2L[lane * 4 + 1], b2L[lane * 4 + 2], b2L[lane * 4 + 3]};
  for (int k = 0; k < 64; ++k) {
    float a = __shfl(av, k);
    ushort4 wv = *(const ushort4*)(&W2L[k * 256 + lane * 4]);
    acc[0] += a * bf2f(wv.x); acc[1] += a * bf2f(wv.y);
    acc[2] += a * bf2f(wv.z); acc[3] += a * bf2f(wv.w);
  }
  #pragma unroll
  for (int c = 0; c < 4; ++c)
    dout[OFF_EMB + (size_t)n * 256 + lane * 4 + c] = fmaxf(acc[c], 0.f);
}

// ---- vsum = graph_neigh @ fused, split over n; partials, no atomics ----
// grid: (VS_S, 16). block 256 = 4 waves; wave w covers n-range [sp*1024 + w*256, +256).
// partial slice ks = sp*4+w. part[(ks*256 + b)*64 + j], rsp[ks*256 + b].
__global__ __launch_bounds__(256) void k_vsum(const void* gn,
                                              const float* __restrict__ dout,
                                              const int* __restrict__ flags,
                                              float* __restrict__ part,
                                              float* __restrict__ rsp) {
  const float* fused = dout + OFF_FUSED;
  int tid = threadIdx.x, w = tid >> 6, lane = tid & 63;
  int f32 = flags[0];
  int sp = blockIdx.x, bg = blockIdx.y;
  int b0 = bg * 16;
  int n0 = sp * VS_CH + w * 256;
  float acc[16], rs16[16];
  #pragma unroll
  for (int i = 0; i < 16; ++i) { acc[i] = 0.f; rs16[i] = 0.f; }
  #pragma unroll 1
  for (int it = 0; it < 4; ++it) {
    int n = n0 + it * 64;
    float gnv[16];
    #pragma unroll
    for (int bb = 0; bb < 16; ++bb) {
      float g = 0.f;
      if (n + lane < NN) g = ldf(gn, (size_t)(b0 + bb) * NN + n + lane, f32);
      gnv[bb] = g;
      rs16[bb] += g;
    }
    #pragma unroll
    for (int j = 0; j < 64; ++j) {
      float fv = (n + j < NN) ? fused[(size_t)(n + j) * 64 + lane] : 0.f;
      #pragma unroll
      for (int bb = 0; bb < 16; ++bb)
        acc[bb] += __shfl(gnv[bb], j) * fv;
    }
  }
  int ks = sp * 4 + w;
  #pragma unroll
  for (int bb = 0; bb < 16; ++bb) {
    part[((size_t)ks * 256 + b0 + bb) * 64 + lane] = acc[bb];
    float r = rs16[bb];
    #pragma unroll
    for (int off = 32; off > 0; off >>= 1) r += __shfl_xor(r, off);
    if (lane == 0) rsp[ks * 256 + b0 + bb] = r;
  }
}

// ---- g finalize: reduce partials, divide by row_sum, L2 normalize ----
__global__ __launch_bounds__(64) void k_gfinal(const float* __restrict__ part,
                                               const float* __restrict__ rsp,
                                               float* __restrict__ dout) {
  int b = blockIdx.x, j = threadIdx.x;
  float acc = 0.f, rs = 0.f;
  for (int k = 0; k < VS_KS; ++k) {
    acc += part[((size_t)k * 256 + b) * 64 + j];
    rs  += rsp[k * 256 + b];
  }
  float v = acc / rs;
  float sq = v * v;
  #pragma unroll
  for (int off = 32; off > 0; off >>= 1) sq += __shfl_xor(sq, off);
  float nrm = sqrtf(sq);
  dout[OFF_G + (size_t)b * 64 + j] = v / fmaxf(nrm, 1e-12f);
}

extern "C" void kernel_launch(void* const* d_in, const int* in_sizes, int n_in,
                              void* d_out, int out_size, void* d_ws, size_t ws_size,
                              hipStream_t stream) {
  const void* x   = d_in[0];
  const void* ei  = d_in[1];
  const void* gn  = d_in[2];
  const void* aew = d_in[3];
  const void* W1  = d_in[4];
  const void* b1  = d_in[5];
  const void* W2  = d_in[6];
  const void* b2  = d_in[7];
  const void* Wf  = d_in[8];
  const void* bfv = d_in[9];
  const void* qf  = d_in[10];

  char* ws = (char*)d_ws;
  size_t off = 0;
  auto alloc = [&](size_t bytes) -> void* {
    void* p = ws + off;
    off += (bytes + 255) & ~(size_t)255;
    return p;
  };
  // zero-init region (atomically accumulated buffers only)
  float*    deg     = (float*)alloc((size_t)3 * NN * 4);
  unsigned* cnt     = (unsigned*)alloc((size_t)NN * 4);
  unsigned* fill    = (unsigned*)alloc((size_t)NN * 4);
  size_t zero_bytes = off;
  int*      flags   = (int*)alloc(64);
  float*    dis2    = (float*)alloc((size_t)NN * 4);
  unsigned* row_ptr = (unsigned*)alloc((size_t)(NN + 1) * 4);
  unsigned* bsum    = (unsigned*)alloc((size_t)NSCB * 4);
  unsigned* boff    = (unsigned*)alloc((size_t)NSCB * 4);
  unsigned* col     = (unsigned*)alloc((size_t)NE * 4);
  float*    h1      = (float*)alloc((size_t)NN * 64 * 4);
  float*    part    = (float*)alloc((size_t)VS_KS * NB * 64 * 4);
  float*    rsp     = (float*)alloc((size_t)VS_KS * NB * 4);

  float* dout = (float*)d_out;

  hipMemsetAsync(d_ws, 0, zero_bytes, stream);
  k_detect<<<1, 64, 0, stream>>>(x, ei, flags);
  k_deg<<<(NE + 255) / 256, 256, 0, stream>>>(ei, aew, flags, deg, cnt);
  k_dis<<<(3 * NN + 255) / 256, 256, 0, stream>>>(deg, cnt, dis2);
  k_sc1<<<NSCB, 256, 0, stream>>>(cnt, bsum);
  k_sc2<<<1, 256, 0, stream>>>(bsum, boff, row_ptr);
  k_sc3<<<NSCB, 256, 0, stream>>>(cnt, boff, row_ptr);
  k_fill<<<(NE + 255) / 256, 256, 0, stream>>>(ei, flags, row_ptr, fill, col);
  k_h1<<<(NN + 3) / 4, 256, 0, stream>>>(x, W1, flags, h1);
  k_hidden<<<(NN + 3) / 4, 256, 0, stream>>>(h1, ei, row_ptr, col, aew, deg,
                                             Wf, bfv, qf, b1, flags, dout);
  k_emb<<<(NN + 3) / 4, 256, 0, stream>>>(ei, row_ptr, col, dis2, W2, b2, flags, dout);
  {
    dim3 g(VS_S, 16);
    k_vsum<<<g, 256, 0, stream>>>(gn, dout, flags, part, rsp);
  }
  k_gfinal<<<NB, 64, 0, stream>>>(part, rsp, dout);
}

// Round 6
// 1258.175 us; speedup vs baseline: 2.2778x; 2.2778x over previous
//
#include <hip/hip_runtime.h>
#include <hip/hip_bf16.h>

#define NN 50000
#define NE 800000
#define NG 3
#define NB 256
#define NSCB 196  // ceil(NN/256)

#define OFF_FUSED ((size_t)0)
#define OFF_EMB   ((size_t)NN * 64)
#define OFF_G     (OFF_EMB + (size_t)NN * 256)
#define OFF_HID   (OFF_G + (size_t)NB * 64)
#define OFF_ATTN  (OFF_HID + (size_t)3 * NN * 64)

// k_vsum geometry: 196 chunks of 256 nodes; 7 chunks/block -> 28 k-splits
#define VS_CPB 7
#define VS_KS  28

typedef unsigned short u16;

__device__ __forceinline__ float bf2f(u16 u) {
  union { unsigned int i; float f; } v; v.i = ((unsigned int)u) << 16; return v.f;
}
__device__ __forceinline__ u16 f2bf(float f) {
  unsigned int x = __float_as_uint(f);
  unsigned int r = (x + 0x7FFFu + ((x >> 16) & 1u)) >> 16;
  return (u16)r;
}
__device__ __forceinline__ float ldf(const void* p, size_t i, int f32) {
  return f32 ? ((const float*)p)[i] : bf2f(((const u16*)p)[i]);
}
__device__ __forceinline__ int ld_src(const void* ei, int e, int i64) {
  return i64 ? (int)((const long long*)ei)[e] : ((const int*)ei)[e];
}
__device__ __forceinline__ int ld_dst(const void* ei, int e, int i64) {
  return i64 ? (int)((const long long*)ei)[(size_t)NE + e] : ((const int*)ei)[(size_t)NE + e];
}

// ---- dtype detection ----
__global__ void k_detect(const void* x, const void* ei, int* flags) {
  if (threadIdx.x != 0 || blockIdx.x != 0) return;
  const u16* xw = (const u16*)x;
  int sane = 0;
  for (int i = 0; i < 64; ++i) {
    unsigned ex = (xw[2 * i] >> 7) & 0xFF;  // exponent field if bf16
    sane += (ex >= 96 && ex <= 141);
  }
  flags[0] = (sane < 48) ? 1 : 0;  // 1 => inputs are float32
  const int* e32 = (const int*)ei;
  int zeros = 0;
  for (int t = 1; t < 32; t += 2) zeros += (e32[t] == 0);
  flags[1] = (zeros >= 12) ? 1 : 0;  // 1 => edge_index is int64
}

// ---- degree accumulation ----
__global__ void k_deg(const void* ei, const void* aew, const int* __restrict__ flags,
                      float* __restrict__ deg, unsigned* __restrict__ cnt) {
  int e = blockIdx.x * 256 + threadIdx.x;
  if (e >= NE) return;
  int f32 = flags[0], i64 = flags[1];
  int d = ld_dst(ei, e, i64);
  atomicAdd(&cnt[d], 1u);
  atomicAdd(&deg[d],          ldf(aew, e, f32));
  atomicAdd(&deg[NN + d],     ldf(aew, (size_t)NE + e, f32));
  atomicAdd(&deg[2 * NN + d], ldf(aew, (size_t)2 * NE + e, f32));
}

__global__ void k_dis(float* __restrict__ deg, const unsigned* __restrict__ cnt,
                      float* __restrict__ dis2) {
  int i = blockIdx.x * 256 + threadIdx.x;
  if (i < 3 * NN) deg[i] = rsqrtf(deg[i] + 1.0f);
  if (i < NN) dis2[i] = rsqrtf((float)cnt[i] + 1.0f);
}

// ---- 3-phase exclusive scan of cnt -> row_ptr ----
__global__ __launch_bounds__(256) void k_sc1(const unsigned* __restrict__ cnt,
                                             unsigned* __restrict__ bsum) {
  int b = blockIdx.x, tid = threadIdx.x, i = b * 256 + tid;
  unsigned v = (i < NN) ? cnt[i] : 0u;
  #pragma unroll
  for (int off = 32; off > 0; off >>= 1) v += __shfl_down(v, off);
  __shared__ unsigned w4[4];
  if ((tid & 63) == 0) w4[tid >> 6] = v;
  __syncthreads();
  if (tid == 0) bsum[b] = w4[0] + w4[1] + w4[2] + w4[3];
}
__global__ __launch_bounds__(256) void k_sc2(const unsigned* __restrict__ bsum,
                                             unsigned* __restrict__ boff,
                                             unsigned* __restrict__ row_ptr) {
  int tid = threadIdx.x, lane = tid & 63, w = tid >> 6;
  unsigned v = (tid < NSCB) ? bsum[tid] : 0u;
  unsigned x = v;
  #pragma unroll
  for (int off = 1; off < 64; off <<= 1) {
    unsigned y = __shfl_up(x, off);
    if (lane >= off) x += y;
  }
  __shared__ unsigned w4[4];
  if (lane == 63) w4[w] = x;
  __syncthreads();
  unsigned woff = 0;
  #pragma unroll
  for (int k = 0; k < 4; ++k) woff += (k < w) ? w4[k] : 0u;
  if (tid < NSCB) boff[tid] = woff + x - v;
  if (tid == 255) row_ptr[NN] = woff + x;
}
__global__ __launch_bounds__(256) void k_sc3(const unsigned* __restrict__ cnt,
                                             const unsigned* __restrict__ boff,
                                             unsigned* __restrict__ row_ptr) {
  int b = blockIdx.x, tid = threadIdx.x, lane = tid & 63, w = tid >> 6;
  int i = b * 256 + tid;
  unsigned v = (i < NN) ? cnt[i] : 0u;
  unsigned x = v;
  #pragma unroll
  for (int off = 1; off < 64; off <<= 1) {
    unsigned y = __shfl_up(x, off);
    if (lane >= off) x += y;
  }
  __shared__ unsigned w4[4];
  if (lane == 63) w4[w] = x;
  __syncthreads();
  unsigned woff = 0;
  #pragma unroll
  for (int k = 0; k < 4; ++k) woff += (k < w) ? w4[k] : 0u;
  if (i < NN) row_ptr[i] = boff[b] + woff + x - v;
}

// ---- CSR fill ----
__global__ void k_fill(const void* ei, const int* __restrict__ flags,
                       const unsigned* __restrict__ row_ptr,
                       unsigned* __restrict__ fill, unsigned* __restrict__ col) {
  int e = blockIdx.x * 256 + threadIdx.x;
  if (e >= NE) return;
  int d = ld_dst(ei, e, flags[1]);
  unsigned pos = row_ptr[d] + atomicAdd(&fill[d], 1u);
  col[pos] = (unsigned)e;
}

// ---- h1[N,64] = x[N,256] @ W1[256,64] via LDS + shfl matvec ----
__global__ __launch_bounds__(256) void k_h1(const void* x, const void* W1,
                                            const int* __restrict__ flags,
                                            float* __restrict__ h1) {
  __shared__ u16 W1L[256 * 64];
  int tid = threadIdx.x;
  int f32 = flags[0];
  for (int i = tid; i < 256 * 64; i += 256)
    W1L[i] = f32 ? f2bf(((const float*)W1)[i]) : ((const u16*)W1)[i];
  __syncthreads();
  int wid = tid >> 6, lane = tid & 63;
  int n = blockIdx.x * 4 + wid;
  if (n >= NN) return;
  float xv[4];
  #pragma unroll
  for (int kk = 0; kk < 4; ++kk) xv[kk] = ldf(x, (size_t)n * 256 + kk * 64 + lane, f32);
  float acc = 0.f;
  #pragma unroll
  for (int kk = 0; kk < 4; ++kk) {
    for (int j = 0; j < 64; ++j) {
      float a = __shfl(xv[kk], j);
      acc += a * bf2f(W1L[(kk * 64 + j) * 64 + lane]);
    }
  }
  h1[(size_t)n * 64 + lane] = acc;
}

// ---- gather layer1 (3 graphs) + attention fusion ----
__global__ __launch_bounds__(256) void k_hidden(
    const float* __restrict__ h1, const void* ei,
    const unsigned* __restrict__ row_ptr, const unsigned* __restrict__ col,
    const void* aew, const float* __restrict__ deg_dis,
    const void* Wf, const void* bfv, const void* qf, const void* b1,
    const int* __restrict__ flags, float* __restrict__ dout) {
  __shared__ u16 WfL[3 * 64 * 64];   // bf16 to halve LDS -> higher occupancy
  __shared__ float qfL[192], bfL[192], b1L[64];
  int tid = threadIdx.x;
  int f32 = flags[0], i64 = flags[1];
  for (int i = tid; i < 3 * 64 * 64; i += 256)
    WfL[i] = f32 ? f2bf(((const float*)Wf)[i]) : ((const u16*)Wf)[i];
  if (tid < 192) { qfL[tid] = ldf(qf, tid, f32); bfL[tid] = ldf(bfv, tid, f32); }
  if (tid < 64) b1L[tid] = ldf(b1, tid, f32);
  __syncthreads();
  int wid = tid >> 6, lane = tid & 63;
  int n = blockIdx.x * 4 + wid;
  if (n >= NN) return;

  float dd0 = deg_dis[n], dd1 = deg_dis[NN + n], dd2 = deg_dis[2 * NN + n];
  float hv = h1[(size_t)n * 64 + lane];
  float acc0 = hv * dd0 * dd0, acc1 = hv * dd1 * dd1, acc2 = hv * dd2 * dd2;

  unsigned beg = row_ptr[n], end = row_ptr[n + 1];
  for (unsigned base = beg; base < end; base += 64) {
    unsigned rem = end - base;
    int m = (rem > 64u) ? 64 : (int)rem;
    int s = 0; float w0 = 0.f, w1 = 0.f, w2 = 0.f;
    if (lane < m) {
      unsigned e = col[base + lane];
      s = ld_src(ei, (int)e, i64);
      w0 = deg_dis[s]          * ldf(aew, e, f32)                  * dd0;
      w1 = deg_dis[NN + s]     * ldf(aew, (size_t)NE + e, f32)     * dd1;
      w2 = deg_dis[2 * NN + s] * ldf(aew, (size_t)2 * NE + e, f32) * dd2;
    }
    for (int j = 0; j < m; ++j) {
      int sj = __shfl(s, j);
      float hs = h1[(size_t)sj * 64 + lane];
      acc0 += hs * __shfl(w0, j);
      acc1 += hs * __shfl(w1, j);
      acc2 += hs * __shfl(w2, j);
    }
  }
  float b1v = b1L[lane];
  float hid0 = fmaxf(acc0 + b1v, 0.f);
  float hid1 = fmaxf(acc1 + b1v, 0.f);
  float hid2 = fmaxf(acc2 + b1v, 0.f);
  dout[OFF_HID + ((size_t)0 * NN + n) * 64 + lane] = hid0;
  dout[OFF_HID + ((size_t)1 * NN + n) * 64 + lane] = hid1;
  dout[OFF_HID + ((size_t)2 * NN + n) * 64 + lane] = hid2;

  float t0 = bfL[lane], t1 = bfL[64 + lane], t2 = bfL[128 + lane];
  for (int k = 0; k < 64; ++k) {
    float h0 = __shfl(hid0, k), h1v = __shfl(hid1, k), h2v = __shfl(hid2, k);
    t0 += h0  * bf2f(WfL[k * 64 + lane]);
    t1 += h1v * bf2f(WfL[4096 + k * 64 + lane]);
    t2 += h2v * bf2f(WfL[8192 + k * 64 + lane]);
  }
  t0 = tanhf(t0); t1 = tanhf(t1); t2 = tanhf(t2);
  float s0 = t0 * qfL[lane], s1 = t1 * qfL[64 + lane], s2 = t2 * qfL[128 + lane];
  #pragma unroll
  for (int off = 32; off > 0; off >>= 1) {
    s0 += __shfl_xor(s0, off);
    s1 += __shfl_xor(s1, off);
    s2 += __shfl_xor(s2, off);
  }
  float mx = fmaxf(s0, fmaxf(s1, s2));
  float e0 = expf(s0 - mx), e1 = expf(s1 - mx), e2 = expf(s2 - mx);
  float inv = 1.0f / (e0 + e1 + e2);
  float a0 = e0 * inv, a1 = e1 * inv, a2 = e2 * inv;
  float fv = a0 * hid0 + a1 * hid1 + a2 * hid2;
  dout[OFF_FUSED + (size_t)n * 64 + lane] = fv;
  if (lane < 3) dout[OFF_ATTN + (size_t)n * 3 + lane] =
                    (lane == 0 ? a0 : (lane == 1 ? a1 : a2));
}

// ---- layer2 fused: agg = sym-aggregate(fused) in 64-dim, emb = relu(agg@W2+b2) ----
__global__ __launch_bounds__(256) void k_emb(
    const void* ei,
    const unsigned* __restrict__ row_ptr, const unsigned* __restrict__ col,
    const float* __restrict__ dis2, const void* W2, const void* b2,
    const int* __restrict__ flags, float* __restrict__ dout) {
  __shared__ u16 W2L[64 * 256];
  __shared__ float b2L[256];
  int tid = threadIdx.x;
  int f32 = flags[0], i64 = flags[1];
  for (int i = tid; i < 64 * 256; i += 256)
    W2L[i] = f32 ? f2bf(((const float*)W2)[i]) : ((const u16*)W2)[i];
  b2L[tid] = ldf(b2, tid, f32);
  __syncthreads();
  const float* fused = dout + OFF_FUSED;
  int wid = tid >> 6, lane = tid & 63;
  int n = blockIdx.x * 4 + wid;
  if (n >= NN) return;
  float dd = dis2[n];
  float av = fused[(size_t)n * 64 + lane] * dd * dd;
  unsigned beg = row_ptr[n], end = row_ptr[n + 1];
  for (unsigned base = beg; base < end; base += 64) {
    unsigned rem = end - base;
    int m = (rem > 64u) ? 64 : (int)rem;
    int s = 0; float w = 0.f;
    if (lane < m) {
      unsigned e = col[base + lane];
      s = ld_src(ei, (int)e, i64);
      w = dis2[s] * dd;
    }
    for (int j = 0; j < m; ++j) {
      int sj = __shfl(s, j);
      av += fused[(size_t)sj * 64 + lane] * __shfl(w, j);
    }
  }
  float acc[4] = {b2L[lane * 4], b2L[lane * 4 + 1], b2L[lane * 4 + 2], b2L[lane * 4 + 3]};
  for (int k = 0; k < 64; ++k) {
    float a = __shfl(av, k);
    ushort4 wv = *(const ushort4*)(&W2L[k * 256 + lane * 4]);
    acc[0] += a * bf2f(wv.x); acc[1] += a * bf2f(wv.y);
    acc[2] += a * bf2f(wv.z); acc[3] += a * bf2f(wv.w);
  }
  #pragma unroll
  for (int c = 0; c < 4; ++c)
    dout[OFF_EMB + (size_t)n * 256 + lane * 4 + c] = fmaxf(acc[c], 0.f);
}

// ---- vsum = graph_neigh @ fused (LDS-tiled GEMV, no shfl, no atomics) ----
// grid (VS_KS, 16); block 256 = 4 waves. Block (ks,bg): b-rows [bg*16, +16),
// n-chunks [ks*VS_CPB*256, +VS_CPB*256). Wave w owns b-rows bg*16 + w*4 .. +4.
__global__ __launch_bounds__(256) void k_vsum(const void* gn,
                                              const float* __restrict__ dout,
                                              const int* __restrict__ flags,
                                              float* __restrict__ part,
                                              float* __restrict__ rsp) {
  __shared__ float gnL[16][256];
  const float* fused = dout + OFF_FUSED;
  int tid = threadIdx.x, w = tid >> 6, lane = tid & 63;
  int f32 = flags[0];
  int ks = blockIdx.x, bg = blockIdx.y;
  int b0 = bg * 16;
  float acc[4] = {0.f, 0.f, 0.f, 0.f};
  float rs[4]  = {0.f, 0.f, 0.f, 0.f};
  for (int c = 0; c < VS_CPB; ++c) {
    int nbase = (ks * VS_CPB + c) * 256;
    __syncthreads();
    #pragma unroll
    for (int i = 0; i < 16; ++i) {
      int n = nbase + tid;
      gnL[i][tid] = (n < NN) ? ldf(gn, (size_t)(b0 + i) * NN + n, f32) : 0.f;
    }
    __syncthreads();
    #pragma unroll 4
    for (int n = 0; n < 256; ++n) {
      int gidx = nbase + n;
      float fv = (gidx < NN) ? fused[(size_t)gidx * 64 + lane] : 0.f;
      #pragma unroll
      for (int bb = 0; bb < 4; ++bb) {
        float g = gnL[w * 4 + bb][n];   // LDS broadcast
        rs[bb] += g;
        acc[bb] += g * fv;
      }
    }
  }
  #pragma unroll
  for (int bb = 0; bb < 4; ++bb) {
    int b = b0 + w * 4 + bb;
    part[((size_t)ks * 256 + b) * 64 + lane] = acc[bb];
    if (lane == 0) rsp[ks * 256 + b] = rs[bb];
  }
}

// ---- g finalize: reduce partials, divide by row_sum, L2 normalize ----
__global__ __launch_bounds__(64) void k_gfinal(const float* __restrict__ part,
                                               const float* __restrict__ rsp,
                                               float* __restrict__ dout) {
  int b = blockIdx.x, j = threadIdx.x;
  float acc = 0.f, rs = 0.f;
  for (int k = 0; k < VS_KS; ++k) {
    acc += part[((size_t)k * 256 + b) * 64 + j];
    rs  += rsp[k * 256 + b];
  }
  float v = acc / rs;
  float sq = v * v;
  #pragma unroll
  for (int off = 32; off > 0; off >>= 1) sq += __shfl_xor(sq, off);
  float nrm = sqrtf(sq);
  dout[OFF_G + (size_t)b * 64 + j] = v / fmaxf(nrm, 1e-12f);
}

extern "C" void kernel_launch(void* const* d_in, const int* in_sizes, int n_in,
                              void* d_out, int out_size, void* d_ws, size_t ws_size,
                              hipStream_t stream) {
  const void* x   = d_in[0];
  const void* ei  = d_in[1];
  const void* gn  = d_in[2];
  const void* aew = d_in[3];
  const void* W1  = d_in[4];
  const void* b1  = d_in[5];
  const void* W2  = d_in[6];
  const void* b2  = d_in[7];
  const void* Wf  = d_in[8];
  const void* bfv = d_in[9];
  const void* qf  = d_in[10];

  char* ws = (char*)d_ws;
  size_t off = 0;
  auto alloc = [&](size_t bytes) -> void* {
    void* p = ws + off;
    off += (bytes + 255) & ~(size_t)255;
    return p;
  };
  // zero-init region (atomically accumulated buffers only)
  float*    deg     = (float*)alloc((size_t)3 * NN * 4);
  unsigned* cnt     = (unsigned*)alloc((size_t)NN * 4);
  unsigned* fill    = (unsigned*)alloc((size_t)NN * 4);
  size_t zero_bytes = off;
  int*      flags   = (int*)alloc(64);
  float*    dis2    = (float*)alloc((size_t)NN * 4);
  unsigned* row_ptr = (unsigned*)alloc((size_t)(NN + 1) * 4);
  unsigned* bsum    = (unsigned*)alloc((size_t)NSCB * 4);
  unsigned* boff    = (unsigned*)alloc((size_t)NSCB * 4);
  unsigned* col     = (unsigned*)alloc((size_t)NE * 4);
  float*    h1      = (float*)alloc((size_t)NN * 64 * 4);
  float*    part    = (float*)alloc((size_t)VS_KS * NB * 64 * 4);
  float*    rsp     = (float*)alloc((size_t)VS_KS * NB * 4);

  float* dout = (float*)d_out;

  hipMemsetAsync(d_ws, 0, zero_bytes, stream);
  k_detect<<<1, 64, 0, stream>>>(x, ei, flags);
  k_deg<<<(NE + 255) / 256, 256, 0, stream>>>(ei, aew, flags, deg, cnt);
  k_dis<<<(3 * NN + 255) / 256, 256, 0, stream>>>(deg, cnt, dis2);
  k_sc1<<<NSCB, 256, 0, stream>>>(cnt, bsum);
  k_sc2<<<1, 256, 0, stream>>>(bsum, boff, row_ptr);
  k_sc3<<<NSCB, 256, 0, stream>>>(cnt, boff, row_ptr);
  k_fill<<<(NE + 255) / 256, 256, 0, stream>>>(ei, flags, row_ptr, fill, col);
  k_h1<<<(NN + 3) / 4, 256, 0, stream>>>(x, W1, flags, h1);
  k_hidden<<<(NN + 3) / 4, 256, 0, stream>>>(h1, ei, row_ptr, col, aew, deg,
                                             Wf, bfv, qf, b1, flags, dout);
  k_emb<<<(NN + 3) / 4, 256, 0, stream>>>(ei, row_ptr, col, dis2, W2, b2, flags, dout);
  {
    dim3 g(VS_KS, 16);
    k_vsum<<<g, 256, 0, stream>>>(gn, dout, flags, part, rsp);
  }
  k_gfinal<<<NB, 64, 0, stream>>>(part, rsp, dout);
}

// Round 7
// 969.542 us; speedup vs baseline: 2.9559x; 1.2977x over previous
//
#include <hip/hip_runtime.h>
#include <hip/hip_bf16.h>

#define NN 50000
#define NE 800000
#define NG 3
#define NB 256
#define NSCB 196  // ceil(NN/256)

#define OFF_FUSED ((size_t)0)
#define OFF_EMB   ((size_t)NN * 64)
#define OFF_G     (OFF_EMB + (size_t)NN * 256)
#define OFF_HID   (OFF_G + (size_t)NB * 64)
#define OFF_ATTN  (OFF_HID + (size_t)3 * NN * 64)

// k_vsum geometry: 49 n-chunks of 1024; 32 b-groups of 8 rows; slice = ks*4+wave
#define VS_NC 49
#define VS_SL (VS_NC * 4)

typedef unsigned short u16;

__device__ __forceinline__ float bf2f(u16 u) {
  union { unsigned int i; float f; } v; v.i = ((unsigned int)u) << 16; return v.f;
}
__device__ __forceinline__ u16 f2bf(float f) {
  unsigned int x = __float_as_uint(f);
  unsigned int r = (x + 0x7FFFu + ((x >> 16) & 1u)) >> 16;
  return (u16)r;
}
__device__ __forceinline__ float ldf(const void* p, size_t i, int f32) {
  return f32 ? ((const float*)p)[i] : bf2f(((const u16*)p)[i]);
}
__device__ __forceinline__ int ld_src(const void* ei, int e, int i64) {
  return i64 ? (int)((const long long*)ei)[e] : ((const int*)ei)[e];
}
__device__ __forceinline__ int ld_dst(const void* ei, int e, int i64) {
  return i64 ? (int)((const long long*)ei)[(size_t)NE + e] : ((const int*)ei)[(size_t)NE + e];
}

// ---- dtype detection ----
__global__ void k_detect(const void* x, const void* ei, int* flags) {
  if (threadIdx.x != 0 || blockIdx.x != 0) return;
  const u16* xw = (const u16*)x;
  int sane = 0;
  for (int i = 0; i < 64; ++i) {
    unsigned ex = (xw[2 * i] >> 7) & 0xFF;
    sane += (ex >= 96 && ex <= 141);
  }
  flags[0] = (sane < 48) ? 1 : 0;  // 1 => inputs are float32
  const int* e32 = (const int*)ei;
  int zeros = 0;
  for (int t = 1; t < 32; t += 2) zeros += (e32[t] == 0);
  flags[1] = (zeros >= 12) ? 1 : 0;  // 1 => edge_index is int64
}

// ---- degree accumulation ----
__global__ void k_deg(const void* ei, const void* aew, const int* __restrict__ flags,
                      float* __restrict__ deg, unsigned* __restrict__ cnt) {
  int e = blockIdx.x * 256 + threadIdx.x;
  if (e >= NE) return;
  int f32 = flags[0], i64 = flags[1];
  int d = ld_dst(ei, e, i64);
  atomicAdd(&cnt[d], 1u);
  atomicAdd(&deg[d],          ldf(aew, e, f32));
  atomicAdd(&deg[NN + d],     ldf(aew, (size_t)NE + e, f32));
  atomicAdd(&deg[2 * NN + d], ldf(aew, (size_t)2 * NE + e, f32));
}

__global__ void k_dis(float* __restrict__ deg, const unsigned* __restrict__ cnt,
                      float* __restrict__ dis2) {
  int i = blockIdx.x * 256 + threadIdx.x;
  if (i < 3 * NN) deg[i] = rsqrtf(deg[i] + 1.0f);
  if (i < NN) dis2[i] = rsqrtf((float)cnt[i] + 1.0f);
}

// ---- 3-phase exclusive scan of cnt -> row_ptr ----
__global__ __launch_bounds__(256) void k_sc1(const unsigned* __restrict__ cnt,
                                             unsigned* __restrict__ bsum) {
  int b = blockIdx.x, tid = threadIdx.x, i = b * 256 + tid;
  unsigned v = (i < NN) ? cnt[i] : 0u;
  #pragma unroll
  for (int off = 32; off > 0; off >>= 1) v += __shfl_down(v, off);
  __shared__ unsigned w4[4];
  if ((tid & 63) == 0) w4[tid >> 6] = v;
  __syncthreads();
  if (tid == 0) bsum[b] = w4[0] + w4[1] + w4[2] + w4[3];
}
__global__ __launch_bounds__(256) void k_sc2(const unsigned* __restrict__ bsum,
                                             unsigned* __restrict__ boff,
                                             unsigned* __restrict__ row_ptr) {
  int tid = threadIdx.x, lane = tid & 63, w = tid >> 6;
  unsigned v = (tid < NSCB) ? bsum[tid] : 0u;
  unsigned x = v;
  #pragma unroll
  for (int off = 1; off < 64; off <<= 1) {
    unsigned y = __shfl_up(x, off);
    if (lane >= off) x += y;
  }
  __shared__ unsigned w4[4];
  if (lane == 63) w4[w] = x;
  __syncthreads();
  unsigned woff = 0;
  #pragma unroll
  for (int k = 0; k < 4; ++k) woff += (k < w) ? w4[k] : 0u;
  if (tid < NSCB) boff[tid] = woff + x - v;
  if (tid == 255) row_ptr[NN] = woff + x;
}
__global__ __launch_bounds__(256) void k_sc3(const unsigned* __restrict__ cnt,
                                             const unsigned* __restrict__ boff,
                                             unsigned* __restrict__ row_ptr) {
  int b = blockIdx.x, tid = threadIdx.x, lane = tid & 63, w = tid >> 6;
  int i = b * 256 + tid;
  unsigned v = (i < NN) ? cnt[i] : 0u;
  unsigned x = v;
  #pragma unroll
  for (int off = 1; off < 64; off <<= 1) {
    unsigned y = __shfl_up(x, off);
    if (lane >= off) x += y;
  }
  __shared__ unsigned w4[4];
  if (lane == 63) w4[w] = x;
  __syncthreads();
  unsigned woff = 0;
  #pragma unroll
  for (int k = 0; k < 4; ++k) woff += (k < w) ? w4[k] : 0u;
  if (i < NN) row_ptr[i] = boff[b] + woff + x - v;
}

// ---- CSR fill with packed, pre-normalized edge data ----
// csr_s[pos] = src; csr_w[pos] = {dis0[s]*ew0, dis1[s]*ew1, dis2g[s]*ew2, dis2[s]}
__global__ void k_fill(const void* ei, const int* __restrict__ flags,
                       const unsigned* __restrict__ row_ptr,
                       const float* __restrict__ dis, const float* __restrict__ dis2,
                       const void* aew, unsigned* __restrict__ fill,
                       int* __restrict__ csr_s, float4* __restrict__ csr_w) {
  int e = blockIdx.x * 256 + threadIdx.x;
  if (e >= NE) return;
  int f32 = flags[0], i64 = flags[1];
  int s = ld_src(ei, e, i64);
  int d = ld_dst(ei, e, i64);
  unsigned pos = row_ptr[d] + atomicAdd(&fill[d], 1u);
  float w0 = dis[s]          * ldf(aew, e, f32);
  float w1 = dis[NN + s]     * ldf(aew, (size_t)NE + e, f32);
  float w2 = dis[2 * NN + s] * ldf(aew, (size_t)2 * NE + e, f32);
  csr_s[pos] = s;
  csr_w[pos] = make_float4(w0, w1, w2, dis2[s]);
}

// ---- h1 = x @ W1 (vectorized: 4 k-quarters in parallel, LDS broadcast) ----
__global__ __launch_bounds__(256) void k_h1v(const void* x, const void* W1,
                                             const int* __restrict__ flags,
                                             float* __restrict__ h1) {
  __shared__ u16 W1L[256 * 64];
  __shared__ float xL[4][256];
  int tid = threadIdx.x, f32 = flags[0];
  for (int i = tid; i < 256 * 64; i += 256)
    W1L[i] = f32 ? f2bf(((const float*)W1)[i]) : ((const u16*)W1)[i];
  #pragma unroll
  for (int r = 0; r < 4; ++r) {
    int row = blockIdx.x * 4 + r;
    xL[r][tid] = (row < NN) ? ldf(x, (size_t)row * 256 + tid, f32) : 0.f;
  }
  __syncthreads();
  int wid = tid >> 6, lane = tid & 63;
  int n = blockIdx.x * 4 + wid;
  if (n >= NN) return;
  int g = lane >> 4, dq = lane & 15;
  float acc[4] = {0.f, 0.f, 0.f, 0.f};
  #pragma unroll 8
  for (int kk = 0; kk < 64; ++kk) {
    int k = g * 64 + kk;
    float a = xL[wid][k];
    ushort4 wv = *(const ushort4*)&W1L[k * 64 + dq * 4];
    acc[0] += a * bf2f(wv.x); acc[1] += a * bf2f(wv.y);
    acc[2] += a * bf2f(wv.z); acc[3] += a * bf2f(wv.w);
  }
  #pragma unroll
  for (int c = 0; c < 4; ++c) {
    acc[c] += __shfl_xor(acc[c], 16);
    acc[c] += __shfl_xor(acc[c], 32);
  }
  if (lane < 16)
    *(float4*)&h1[(size_t)n * 64 + lane * 4] = make_float4(acc[0], acc[1], acc[2], acc[3]);
}

// ---- gather layer1 (3 graphs, vectorized) + attention fusion ----
__global__ __launch_bounds__(256) void k_hidden(
    const float* __restrict__ h1, const int* __restrict__ csr_s,
    const float4* __restrict__ csr_w, const unsigned* __restrict__ row_ptr,
    const float* __restrict__ deg_dis,
    const void* Wf, const void* bfv, const void* qf, const void* b1,
    const int* __restrict__ flags, float* __restrict__ dout) {
  __shared__ u16 WfL[3 * 64 * 64];
  __shared__ float qfL[192], bfL[192], b1L[64];
  int tid = threadIdx.x, f32 = flags[0];
  for (int i = tid; i < 3 * 64 * 64; i += 256)
    WfL[i] = f32 ? f2bf(((const float*)Wf)[i]) : ((const u16*)Wf)[i];
  if (tid < 192) { qfL[tid] = ldf(qf, tid, f32); bfL[tid] = ldf(bfv, tid, f32); }
  if (tid < 64) b1L[tid] = ldf(b1, tid, f32);
  __syncthreads();
  int wid = tid >> 6, lane = tid & 63;
  int n = blockIdx.x * 4 + wid;
  if (n >= NN) return;

  float dd0 = deg_dis[n], dd1 = deg_dis[NN + n], dd2 = deg_dis[2 * NN + n];
  float a0[4] = {0,0,0,0}, a1[4] = {0,0,0,0}, a2[4] = {0,0,0,0};
  int g = lane >> 4, dq = lane & 15;
  unsigned beg = row_ptr[n], end = row_ptr[n + 1];
  for (unsigned base = beg; base < end; base += 64) {
    unsigned rem = end - base;
    int m = (rem > 64u) ? 64 : (int)rem;
    int s = 0; float w0 = 0.f, w1 = 0.f, w2 = 0.f;
    if (lane < m) {
      s = csr_s[base + lane];
      float4 cw = csr_w[base + lane];
      w0 = cw.x * dd0; w1 = cw.y * dd1; w2 = cw.z * dd2;
    }
    int jmax = (m + 3) >> 2;
    for (int j = 0; j < jmax; ++j) {
      int idx = j * 4 + g;
      int sj = __shfl(s, idx);
      float u0 = __shfl(w0, idx), u1 = __shfl(w1, idx), u2 = __shfl(w2, idx);
      float4 hr = *(const float4*)&h1[(size_t)sj * 64 + dq * 4];
      a0[0] += u0 * hr.x; a0[1] += u0 * hr.y; a0[2] += u0 * hr.z; a0[3] += u0 * hr.w;
      a1[0] += u1 * hr.x; a1[1] += u1 * hr.y; a1[2] += u1 * hr.z; a1[3] += u1 * hr.w;
      a2[0] += u2 * hr.x; a2[1] += u2 * hr.y; a2[2] += u2 * hr.z; a2[3] += u2 * hr.w;
    }
  }
  #pragma unroll
  for (int c = 0; c < 4; ++c) {
    a0[c] += __shfl_xor(a0[c], 16); a0[c] += __shfl_xor(a0[c], 32);
    a1[c] += __shfl_xor(a1[c], 16); a1[c] += __shfl_xor(a1[c], 32);
    a2[c] += __shfl_xor(a2[c], 16); a2[c] += __shfl_xor(a2[c], 32);
  }
  // redistribute to lane=dim layout
  int srcl = lane >> 2, cc = lane & 3;
  float t0, t1, t2, t3, r0, r1, r2;
  t0 = __shfl(a0[0], srcl); t1 = __shfl(a0[1], srcl);
  t2 = __shfl(a0[2], srcl); t3 = __shfl(a0[3], srcl);
  r0 = cc == 0 ? t0 : cc == 1 ? t1 : cc == 2 ? t2 : t3;
  t0 = __shfl(a1[0], srcl); t1 = __shfl(a1[1], srcl);
  t2 = __shfl(a1[2], srcl); t3 = __shfl(a1[3], srcl);
  r1 = cc == 0 ? t0 : cc == 1 ? t1 : cc == 2 ? t2 : t3;
  t0 = __shfl(a2[0], srcl); t1 = __shfl(a2[1], srcl);
  t2 = __shfl(a2[2], srcl); t3 = __shfl(a2[3], srcl);
  r2 = cc == 0 ? t0 : cc == 1 ? t1 : cc == 2 ? t2 : t3;

  float selfv = h1[(size_t)n * 64 + lane];
  float b1v = b1L[lane];
  float hid0 = fmaxf(r0 + dd0 * dd0 * selfv + b1v, 0.f);
  float hid1 = fmaxf(r1 + dd1 * dd1 * selfv + b1v, 0.f);
  float hid2 = fmaxf(r2 + dd2 * dd2 * selfv + b1v, 0.f);
  dout[OFF_HID + ((size_t)0 * NN + n) * 64 + lane] = hid0;
  dout[OFF_HID + ((size_t)1 * NN + n) * 64 + lane] = hid1;
  dout[OFF_HID + ((size_t)2 * NN + n) * 64 + lane] = hid2;

  float t0a = bfL[lane], t1a = bfL[64 + lane], t2a = bfL[128 + lane];
  for (int k = 0; k < 64; ++k) {
    float h0 = __shfl(hid0, k), h1v = __shfl(hid1, k), h2v = __shfl(hid2, k);
    t0a += h0  * bf2f(WfL[k * 64 + lane]);
    t1a += h1v * bf2f(WfL[4096 + k * 64 + lane]);
    t2a += h2v * bf2f(WfL[8192 + k * 64 + lane]);
  }
  t0a = tanhf(t0a); t1a = tanhf(t1a); t2a = tanhf(t2a);
  float s0 = t0a * qfL[lane], s1 = t1a * qfL[64 + lane], s2 = t2a * qfL[128 + lane];
  #pragma unroll
  for (int off = 32; off > 0; off >>= 1) {
    s0 += __shfl_xor(s0, off);
    s1 += __shfl_xor(s1, off);
    s2 += __shfl_xor(s2, off);
  }
  float mx = fmaxf(s0, fmaxf(s1, s2));
  float e0 = expf(s0 - mx), e1 = expf(s1 - mx), e2 = expf(s2 - mx);
  float inv = 1.0f / (e0 + e1 + e2);
  float aw0 = e0 * inv, aw1 = e1 * inv, aw2 = e2 * inv;
  float fv = aw0 * hid0 + aw1 * hid1 + aw2 * hid2;
  dout[OFF_FUSED + (size_t)n * 64 + lane] = fv;
  if (lane < 3) dout[OFF_ATTN + (size_t)n * 3 + lane] =
                    (lane == 0 ? aw0 : (lane == 1 ? aw1 : aw2));
}

// ---- layer2 gather (vectorized, no LDS): agg = sym-aggregate(fused) ----
__global__ __launch_bounds__(256) void k_agg2(
    const int* __restrict__ csr_s, const float4* __restrict__ csr_w,
    const unsigned* __restrict__ row_ptr, const float* __restrict__ dis2,
    const float* __restrict__ dout, float* __restrict__ agg) {
  const float* fused = dout + OFF_FUSED;
  int tid = threadIdx.x, wid = tid >> 6, lane = tid & 63;
  int n = blockIdx.x * 4 + wid;
  if (n >= NN) return;
  float dd = dis2[n];
  float acc[4] = {0.f, 0.f, 0.f, 0.f};
  int g = lane >> 4, dq = lane & 15;
  unsigned beg = row_ptr[n], end = row_ptr[n + 1];
  for (unsigned base = beg; base < end; base += 64) {
    unsigned rem = end - base;
    int m = (rem > 64u) ? 64 : (int)rem;
    int s = 0; float w = 0.f;
    if (lane < m) {
      s = csr_s[base + lane];
      w = csr_w[base + lane].w * dd;
    }
    int jmax = (m + 3) >> 2;
    for (int j = 0; j < jmax; ++j) {
      int idx = j * 4 + g;
      int sj = __shfl(s, idx);
      float wj = __shfl(w, idx);
      float4 fr = *(const float4*)&fused[(size_t)sj * 64 + dq * 4];
      acc[0] += wj * fr.x; acc[1] += wj * fr.y;
      acc[2] += wj * fr.z; acc[3] += wj * fr.w;
    }
  }
  #pragma unroll
  for (int c = 0; c < 4; ++c) {
    acc[c] += __shfl_xor(acc[c], 16);
    acc[c] += __shfl_xor(acc[c], 32);
  }
  if (lane < 16) {
    float4 sf = *(const float4*)&fused[(size_t)n * 64 + lane * 4];
    float sw = dd * dd;
    *(float4*)&agg[(size_t)n * 64 + lane * 4] =
        make_float4(acc[0] + sw * sf.x, acc[1] + sw * sf.y,
                    acc[2] + sw * sf.z, acc[3] + sw * sf.w);
  }
}

// ---- emb = relu(agg @ W2 + b2) (LDS broadcast matvec, float4 out) ----
__global__ __launch_bounds__(256) void k_emb2(const float* __restrict__ agg,
                                              const void* W2, const void* b2,
                                              const int* __restrict__ flags,
                                              float* __restrict__ dout) {
  __shared__ u16 W2L[64 * 256];
  __shared__ float agL[4][64];
  __shared__ float b2L[256];
  int tid = threadIdx.x, f32 = flags[0];
  for (int i = tid; i < 64 * 256; i += 256)
    W2L[i] = f32 ? f2bf(((const float*)W2)[i]) : ((const u16*)W2)[i];
  b2L[tid] = ldf(b2, tid, f32);
  {
    int r = tid >> 6, c = tid & 63;
    int row = blockIdx.x * 4 + r;
    agL[r][c] = (row < NN) ? agg[(size_t)row * 64 + c] : 0.f;
  }
  __syncthreads();
  int wid = tid >> 6, lane = tid & 63;
  int n = blockIdx.x * 4 + wid;
  if (n >= NN) return;
  float acc0 = b2L[lane * 4], acc1 = b2L[lane * 4 + 1];
  float acc2 = b2L[lane * 4 + 2], acc3 = b2L[lane * 4 + 3];
  #pragma unroll 8
  for (int k = 0; k < 64; ++k) {
    float a = agL[wid][k];
    ushort4 wv = *(const ushort4*)&W2L[k * 256 + lane * 4];
    acc0 += a * bf2f(wv.x); acc1 += a * bf2f(wv.y);
    acc2 += a * bf2f(wv.z); acc3 += a * bf2f(wv.w);
  }
  *(float4*)&dout[OFF_EMB + (size_t)n * 256 + lane * 4] =
      make_float4(fmaxf(acc0, 0.f), fmaxf(acc1, 0.f),
                  fmaxf(acc2, 0.f), fmaxf(acc3, 0.f));
}

// ---- row sums of graph_neigh ----
__global__ __launch_bounds__(256) void k_rowsum(const void* gn,
                                                const int* __restrict__ flags,
                                                float* __restrict__ row_sum) {
  int b = blockIdx.x, tid = threadIdx.x, f32 = flags[0];
  float s = 0.f;
  for (int i = tid; i < NN; i += 256) s += ldf(gn, (size_t)b * NN + i, f32);
  int lane = tid & 63, wid = tid >> 6;
  #pragma unroll
  for (int off = 32; off > 0; off >>= 1) s += __shfl_down(s, off);
  __shared__ float w4[4];
  if (lane == 0) w4[wid] = s;
  __syncthreads();
  if (tid == 0) row_sum[b] = w4[0] + w4[1] + w4[2] + w4[3];
}

// ---- vsum = graph_neigh @ fused (LDS gn tiles, float4 fused, vectorized) ----
__global__ __launch_bounds__(256) void k_vsum(const void* gn,
                                              const float* __restrict__ dout,
                                              const int* __restrict__ flags,
                                              float* __restrict__ part) {
  __shared__ float gnL[8][1024];
  const float* fused = dout + OFF_FUSED;
  int tid = threadIdx.x, wid = tid >> 6, lane = tid & 63;
  int f32 = flags[0];
  int ks = blockIdx.x, bg = blockIdx.y;
  int nbase = ks * 1024;
  #pragma unroll
  for (int r = 0; r < 8; ++r) {
    #pragma unroll
    for (int i = 0; i < 4; ++i) {
      int colv = i * 256 + tid;
      int nn = nbase + colv;
      gnL[r][colv] = (nn < NN) ? ldf(gn, (size_t)(bg * 8 + r) * NN + nn, f32) : 0.f;
    }
  }
  __syncthreads();
  int g = lane >> 4, dq = lane & 15;
  float acc[8][4];
  #pragma unroll
  for (int r = 0; r < 8; ++r)
    #pragma unroll
    for (int c = 0; c < 4; ++c) acc[r][c] = 0.f;
  for (int i = 0; i < 64; ++i) {
    int nloc = wid * 256 + i * 4 + g;
    int nn = nbase + nloc;
    float4 fr = (nn < NN) ? *(const float4*)&fused[(size_t)nn * 64 + dq * 4]
                          : make_float4(0.f, 0.f, 0.f, 0.f);
    #pragma unroll
    for (int r = 0; r < 8; ++r) {
      float gv = gnL[r][nloc];
      acc[r][0] += gv * fr.x; acc[r][1] += gv * fr.y;
      acc[r][2] += gv * fr.z; acc[r][3] += gv * fr.w;
    }
  }
  #pragma unroll
  for (int r = 0; r < 8; ++r)
    #pragma unroll
    for (int c = 0; c < 4; ++c) {
      acc[r][c] += __shfl_xor(acc[r][c], 16);
      acc[r][c] += __shfl_xor(acc[r][c], 32);
    }
  if (lane < 16) {
    int slice = ks * 4 + wid;
    #pragma unroll
    for (int r = 0; r < 8; ++r)
      *(float4*)&part[((size_t)slice * 256 + bg * 8 + r) * 64 + lane * 4] =
          make_float4(acc[r][0], acc[r][1], acc[r][2], acc[r][3]);
  }
}

// ---- g finalize: reduce partials, divide by row_sum, L2 normalize ----
__global__ __launch_bounds__(64) void k_gfinal(const float* __restrict__ part,
                                               const float* __restrict__ row_sum,
                                               float* __restrict__ dout) {
  int b = blockIdx.x, j = threadIdx.x;
  float acc = 0.f;
  for (int k = 0; k < VS_SL; ++k) acc += part[((size_t)k * 256 + b) * 64 + j];
  float v = acc / row_sum[b];
  float sq = v * v;
  #pragma unroll
  for (int off = 32; off > 0; off >>= 1) sq += __shfl_xor(sq, off);
  float nrm = sqrtf(sq);
  dout[OFF_G + (size_t)b * 64 + j] = v / fmaxf(nrm, 1e-12f);
}

extern "C" void kernel_launch(void* const* d_in, const int* in_sizes, int n_in,
                              void* d_out, int out_size, void* d_ws, size_t ws_size,
                              hipStream_t stream) {
  const void* x   = d_in[0];
  const void* ei  = d_in[1];
  const void* gn  = d_in[2];
  const void* aew = d_in[3];
  const void* W1  = d_in[4];
  const void* b1  = d_in[5];
  const void* W2  = d_in[6];
  const void* b2  = d_in[7];
  const void* Wf  = d_in[8];
  const void* bfv = d_in[9];
  const void* qf  = d_in[10];

  char* ws = (char*)d_ws;
  size_t off = 0;
  auto alloc = [&](size_t bytes) -> void* {
    void* p = ws + off;
    off += (bytes + 255) & ~(size_t)255;
    return p;
  };
  // zero-init region (atomically accumulated buffers only)
  float*    deg     = (float*)alloc((size_t)3 * NN * 4);
  unsigned* cnt     = (unsigned*)alloc((size_t)NN * 4);
  unsigned* fill    = (unsigned*)alloc((size_t)NN * 4);
  size_t zero_bytes = off;
  int*      flags   = (int*)alloc(64);
  float*    dis2    = (float*)alloc((size_t)NN * 4);
  unsigned* row_ptr = (unsigned*)alloc((size_t)(NN + 1) * 4);
  unsigned* bsum    = (unsigned*)alloc((size_t)NSCB * 4);
  unsigned* boff    = (unsigned*)alloc((size_t)NSCB * 4);
  int*      csr_s   = (int*)alloc((size_t)NE * 4);
  float4*   csr_w   = (float4*)alloc((size_t)NE * 16);
  // time-shared region: h1 (k_h1v->k_hidden), agg (k_agg2->k_emb2), part (k_vsum->k_gfinal)
  size_t regA_bytes = (size_t)VS_SL * NB * 64 * 4;  // 12.85 MB >= h1/agg (12.8 MB)
  char*  regA       = (char*)alloc(regA_bytes);
  float* h1   = (float*)regA;
  float* agg  = (float*)regA;
  float* part = (float*)regA;
  float* row_sum = (float*)alloc((size_t)NB * 4);

  float* dout = (float*)d_out;

  hipMemsetAsync(d_ws, 0, zero_bytes, stream);
  k_detect<<<1, 64, 0, stream>>>(x, ei, flags);
  k_deg<<<(NE + 255) / 256, 256, 0, stream>>>(ei, aew, flags, deg, cnt);
  k_dis<<<(3 * NN + 255) / 256, 256, 0, stream>>>(deg, cnt, dis2);
  k_sc1<<<NSCB, 256, 0, stream>>>(cnt, bsum);
  k_sc2<<<1, 256, 0, stream>>>(bsum, boff, row_ptr);
  k_sc3<<<NSCB, 256, 0, stream>>>(cnt, boff, row_ptr);
  k_fill<<<(NE + 255) / 256, 256, 0, stream>>>(ei, flags, row_ptr, deg, dis2, aew,
                                               fill, csr_s, csr_w);
  k_h1v<<<(NN + 3) / 4, 256, 0, stream>>>(x, W1, flags, h1);
  k_hidden<<<(NN + 3) / 4, 256, 0, stream>>>(h1, csr_s, csr_w, row_ptr, deg,
                                             Wf, bfv, qf, b1, flags, dout);
  k_agg2<<<(NN + 3) / 4, 256, 0, stream>>>(csr_s, csr_w, row_ptr, dis2, dout, agg);
  k_emb2<<<(NN + 3) / 4, 256, 0, stream>>>(agg, W2, b2, flags, dout);
  k_rowsum<<<NB, 256, 0, stream>>>(gn, flags, row_sum);
  {
    dim3 gdim(VS_NC, 32);
    k_vsum<<<gdim, 256, 0, stream>>>(gn, dout, flags, part);
  }
  k_gfinal<<<NB, 64, 0, stream>>>(part, row_sum, dout);
}

// Round 8
// 919.441 us; speedup vs baseline: 3.1170x; 1.0545x over previous
//
#include <hip/hip_runtime.h>
#include <hip/hip_bf16.h>

#define NN 50000
#define NE 800000
#define NG 3
#define NB 256
#define NSCB 196  // ceil(NN/256)

#define OFF_FUSED ((size_t)0)
#define OFF_EMB   ((size_t)NN * 64)
#define OFF_G     (OFF_EMB + (size_t)NN * 256)
#define OFF_HID   (OFF_G + (size_t)NB * 64)
#define OFF_ATTN  (OFF_HID + (size_t)3 * NN * 64)

// k_vsum geometry: 49 n-chunks of 1024; 32 b-groups of 8 rows; slice = ks*4+wave
#define VS_NC 49
#define VS_SL (VS_NC * 4)

typedef unsigned short u16;

__device__ __forceinline__ float bf2f(u16 u) {
  union { unsigned int i; float f; } v; v.i = ((unsigned int)u) << 16; return v.f;
}
__device__ __forceinline__ u16 f2bf(float f) {
  unsigned int x = __float_as_uint(f);
  unsigned int r = (x + 0x7FFFu + ((x >> 16) & 1u)) >> 16;
  return (u16)r;
}
__device__ __forceinline__ float ldf(const void* p, size_t i, int f32) {
  return f32 ? ((const float*)p)[i] : bf2f(((const u16*)p)[i]);
}
__device__ __forceinline__ int ld_src(const void* ei, int e, int i64) {
  return i64 ? (int)((const long long*)ei)[e] : ((const int*)ei)[e];
}
__device__ __forceinline__ int ld_dst(const void* ei, int e, int i64) {
  return i64 ? (int)((const long long*)ei)[(size_t)NE + e] : ((const int*)ei)[(size_t)NE + e];
}

// ---- dtype detection ----
__global__ void k_detect(const void* x, const void* ei, int* flags) {
  if (threadIdx.x != 0 || blockIdx.x != 0) return;
  const u16* xw = (const u16*)x;
  int sane = 0;
  for (int i = 0; i < 64; ++i) {
    unsigned ex = (xw[2 * i] >> 7) & 0xFF;
    sane += (ex >= 96 && ex <= 141);
  }
  flags[0] = (sane < 48) ? 1 : 0;  // 1 => inputs are float32
  const int* e32 = (const int*)ei;
  int zeros = 0;
  for (int t = 1; t < 32; t += 2) zeros += (e32[t] == 0);
  flags[1] = (zeros >= 12) ? 1 : 0;  // 1 => edge_index is int64
}

// ---- degree accumulation ----
__global__ void k_deg(const void* ei, const void* aew, const int* __restrict__ flags,
                      float* __restrict__ deg, unsigned* __restrict__ cnt) {
  int e = blockIdx.x * 256 + threadIdx.x;
  if (e >= NE) return;
  int f32 = flags[0], i64 = flags[1];
  int d = ld_dst(ei, e, i64);
  atomicAdd(&cnt[d], 1u);
  atomicAdd(&deg[d],          ldf(aew, e, f32));
  atomicAdd(&deg[NN + d],     ldf(aew, (size_t)NE + e, f32));
  atomicAdd(&deg[2 * NN + d], ldf(aew, (size_t)2 * NE + e, f32));
}

__global__ void k_dis(float* __restrict__ deg, const unsigned* __restrict__ cnt,
                      float* __restrict__ dis2) {
  int i = blockIdx.x * 256 + threadIdx.x;
  if (i < 3 * NN) deg[i] = rsqrtf(deg[i] + 1.0f);
  if (i < NN) dis2[i] = rsqrtf((float)cnt[i] + 1.0f);
}

// ---- 3-phase exclusive scan of cnt -> row_ptr ----
__global__ __launch_bounds__(256) void k_sc1(const unsigned* __restrict__ cnt,
                                             unsigned* __restrict__ bsum) {
  int b = blockIdx.x, tid = threadIdx.x, i = b * 256 + tid;
  unsigned v = (i < NN) ? cnt[i] : 0u;
  #pragma unroll
  for (int off = 32; off > 0; off >>= 1) v += __shfl_down(v, off);
  __shared__ unsigned w4[4];
  if ((tid & 63) == 0) w4[tid >> 6] = v;
  __syncthreads();
  if (tid == 0) bsum[b] = w4[0] + w4[1] + w4[2] + w4[3];
}
__global__ __launch_bounds__(256) void k_sc2(const unsigned* __restrict__ bsum,
                                             unsigned* __restrict__ boff,
                                             unsigned* __restrict__ row_ptr) {
  int tid = threadIdx.x, lane = tid & 63, w = tid >> 6;
  unsigned v = (tid < NSCB) ? bsum[tid] : 0u;
  unsigned x = v;
  #pragma unroll
  for (int off = 1; off < 64; off <<= 1) {
    unsigned y = __shfl_up(x, off);
    if (lane >= off) x += y;
  }
  __shared__ unsigned w4[4];
  if (lane == 63) w4[w] = x;
  __syncthreads();
  unsigned woff = 0;
  #pragma unroll
  for (int k = 0; k < 4; ++k) woff += (k < w) ? w4[k] : 0u;
  if (tid < NSCB) boff[tid] = woff + x - v;
  if (tid == 255) row_ptr[NN] = woff + x;
}
__global__ __launch_bounds__(256) void k_sc3(const unsigned* __restrict__ cnt,
                                             const unsigned* __restrict__ boff,
                                             unsigned* __restrict__ row_ptr) {
  int b = blockIdx.x, tid = threadIdx.x, lane = tid & 63, w = tid >> 6;
  int i = b * 256 + tid;
  unsigned v = (i < NN) ? cnt[i] : 0u;
  unsigned x = v;
  #pragma unroll
  for (int off = 1; off < 64; off <<= 1) {
    unsigned y = __shfl_up(x, off);
    if (lane >= off) x += y;
  }
  __shared__ unsigned w4[4];
  if (lane == 63) w4[w] = x;
  __syncthreads();
  unsigned woff = 0;
  #pragma unroll
  for (int k = 0; k < 4; ++k) woff += (k < w) ? w4[k] : 0u;
  if (i < NN) row_ptr[i] = boff[b] + woff + x - v;
}

// ---- CSR fill with packed, pre-normalized edge data ----
__global__ void k_fill(const void* ei, const int* __restrict__ flags,
                       const unsigned* __restrict__ row_ptr,
                       const float* __restrict__ dis, const float* __restrict__ dis2,
                       const void* aew, unsigned* __restrict__ fill,
                       int* __restrict__ csr_s, float4* __restrict__ csr_w) {
  int e = blockIdx.x * 256 + threadIdx.x;
  if (e >= NE) return;
  int f32 = flags[0], i64 = flags[1];
  int s = ld_src(ei, e, i64);
  int d = ld_dst(ei, e, i64);
  unsigned pos = row_ptr[d] + atomicAdd(&fill[d], 1u);
  float w0 = dis[s]          * ldf(aew, e, f32);
  float w1 = dis[NN + s]     * ldf(aew, (size_t)NE + e, f32);
  float w2 = dis[2 * NN + s] * ldf(aew, (size_t)2 * NE + e, f32);
  csr_s[pos] = s;
  csr_w[pos] = make_float4(w0, w1, w2, dis2[s]);
}

// ---- h1 = x @ W1 (vectorized: 4 k-quarters in parallel, LDS broadcast) ----
__global__ __launch_bounds__(256) void k_h1v(const void* x, const void* W1,
                                             const int* __restrict__ flags,
                                             float* __restrict__ h1) {
  __shared__ u16 W1L[256 * 64];
  __shared__ float xL[4][256];
  int tid = threadIdx.x, f32 = flags[0];
  for (int i = tid; i < 256 * 64; i += 256)
    W1L[i] = f32 ? f2bf(((const float*)W1)[i]) : ((const u16*)W1)[i];
  #pragma unroll
  for (int r = 0; r < 4; ++r) {
    int row = blockIdx.x * 4 + r;
    xL[r][tid] = (row < NN) ? ldf(x, (size_t)row * 256 + tid, f32) : 0.f;
  }
  __syncthreads();
  int wid = tid >> 6, lane = tid & 63;
  int n = blockIdx.x * 4 + wid;
  if (n >= NN) return;
  int g = lane >> 4, dq = lane & 15;
  float acc[4] = {0.f, 0.f, 0.f, 0.f};
  #pragma unroll 8
  for (int kk = 0; kk < 64; ++kk) {
    int k = g * 64 + kk;
    float a = xL[wid][k];
    ushort4 wv = *(const ushort4*)&W1L[k * 64 + dq * 4];
    acc[0] += a * bf2f(wv.x); acc[1] += a * bf2f(wv.y);
    acc[2] += a * bf2f(wv.z); acc[3] += a * bf2f(wv.w);
  }
  #pragma unroll
  for (int c = 0; c < 4; ++c) {
    acc[c] += __shfl_xor(acc[c], 16);
    acc[c] += __shfl_xor(acc[c], 32);
  }
  if (lane < 16)
    *(float4*)&h1[(size_t)n * 64 + lane * 4] = make_float4(acc[0], acc[1], acc[2], acc[3]);
}

// ---- gather layer1 (3 graphs) + attention fusion ----
__global__ __launch_bounds__(256) void k_hidden(
    const float* __restrict__ h1, const int* __restrict__ csr_s,
    const float4* __restrict__ csr_w, const unsigned* __restrict__ row_ptr,
    const float* __restrict__ deg_dis,
    const void* Wf, const void* bfv, const void* qf, const void* b1,
    const int* __restrict__ flags, float* __restrict__ dout) {
  __shared__ u16 WfL[3 * 64 * 64];     // 24 KB bf16
  __shared__ float4 eWL[4][64];        // 4 KB per-wave edge staging
  __shared__ float qfL[192], bfL[192], b1L[64];
  int tid = threadIdx.x, f32 = flags[0];
  for (int i = tid; i < 3 * 64 * 64; i += 256)
    WfL[i] = f32 ? f2bf(((const float*)Wf)[i]) : ((const u16*)Wf)[i];
  if (tid < 192) { qfL[tid] = ldf(qf, tid, f32); bfL[tid] = ldf(bfv, tid, f32); }
  if (tid < 64) b1L[tid] = ldf(b1, tid, f32);
  __syncthreads();
  int wid = tid >> 6, lane = tid & 63;
  int n = blockIdx.x * 4 + wid;
  if (n >= NN) return;

  float dd0 = deg_dis[n], dd1 = deg_dis[NN + n], dd2 = deg_dis[2 * NN + n];
  float a0[4] = {0,0,0,0}, a1[4] = {0,0,0,0}, a2[4] = {0,0,0,0};
  int g = lane >> 4, dq = lane & 15;
  unsigned beg = row_ptr[n], end = row_ptr[n + 1];
  for (unsigned base = beg; base < end; base += 64) {
    unsigned rem = end - base;
    int m = (rem > 64u) ? 64 : (int)rem;
    // stage chunk: ALL lanes write (zeros for tail) -> no stale entries
    float4 st = make_float4(0.f, 0.f, 0.f, __int_as_float(0));
    if (lane < m) {
      float4 cw = csr_w[base + lane];
      int s = csr_s[base + lane];
      st = make_float4(cw.x * dd0, cw.y * dd1, cw.z * dd2, __int_as_float(s));
    }
    eWL[wid][lane] = st;   // same-wave LDS ops are in-order; no barrier needed
    int jmax = (m + 3) >> 2;
    for (int j = 0; j < jmax; ++j) {
      float4 e = eWL[wid][j * 4 + g];   // one broadcast ds_read_b128
      int sj = __float_as_int(e.w);
      float4 hr = *(const float4*)&h1[(size_t)sj * 64 + dq * 4];
      a0[0] += e.x * hr.x; a0[1] += e.x * hr.y; a0[2] += e.x * hr.z; a0[3] += e.x * hr.w;
      a1[0] += e.y * hr.x; a1[1] += e.y * hr.y; a1[2] += e.y * hr.z; a1[3] += e.y * hr.w;
      a2[0] += e.z * hr.x; a2[1] += e.z * hr.y; a2[2] += e.z * hr.z; a2[3] += e.z * hr.w;
    }
  }
  #pragma unroll
  for (int c = 0; c < 4; ++c) {
    a0[c] += __shfl_xor(a0[c], 16); a0[c] += __shfl_xor(a0[c], 32);
    a1[c] += __shfl_xor(a1[c], 16); a1[c] += __shfl_xor(a1[c], 32);
    a2[c] += __shfl_xor(a2[c], 16); a2[c] += __shfl_xor(a2[c], 32);
  }
  // redistribute to lane=dim layout
  int srcl = lane >> 2, cc = lane & 3;
  float t0, t1, t2, t3, r0, r1, r2;
  t0 = __shfl(a0[0], srcl); t1 = __shfl(a0[1], srcl);
  t2 = __shfl(a0[2], srcl); t3 = __shfl(a0[3], srcl);
  r0 = cc == 0 ? t0 : cc == 1 ? t1 : cc == 2 ? t2 : t3;
  t0 = __shfl(a1[0], srcl); t1 = __shfl(a1[1], srcl);
  t2 = __shfl(a1[2], srcl); t3 = __shfl(a1[3], srcl);
  r1 = cc == 0 ? t0 : cc == 1 ? t1 : cc == 2 ? t2 : t3;
  t0 = __shfl(a2[0], srcl); t1 = __shfl(a2[1], srcl);
  t2 = __shfl(a2[2], srcl); t3 = __shfl(a2[3], srcl);
  r2 = cc == 0 ? t0 : cc == 1 ? t1 : cc == 2 ? t2 : t3;

  float selfv = h1[(size_t)n * 64 + lane];
  float b1v = b1L[lane];
  float hid0 = fmaxf(r0 + dd0 * dd0 * selfv + b1v, 0.f);
  float hid1 = fmaxf(r1 + dd1 * dd1 * selfv + b1v, 0.f);
  float hid2 = fmaxf(r2 + dd2 * dd2 * selfv + b1v, 0.f);
  dout[OFF_HID + ((size_t)0 * NN + n) * 64 + lane] = hid0;
  dout[OFF_HID + ((size_t)1 * NN + n) * 64 + lane] = hid1;
  dout[OFF_HID + ((size_t)2 * NN + n) * 64 + lane] = hid2;

  // attention matvec, k-split: group g handles k in [g*16, +16), lane dq -> 4 j-cols
  float u0[4] = {0,0,0,0}, u1[4] = {0,0,0,0}, u2[4] = {0,0,0,0};
  #pragma unroll 4
  for (int kk = 0; kk < 16; ++kk) {
    int k = g * 16 + kk;
    float h0 = __shfl(hid0, k), h1b = __shfl(hid1, k), h2b = __shfl(hid2, k);
    ushort4 w0v = *(const ushort4*)&WfL[k * 64 + dq * 4];
    ushort4 w1v = *(const ushort4*)&WfL[4096 + k * 64 + dq * 4];
    ushort4 w2v = *(const ushort4*)&WfL[8192 + k * 64 + dq * 4];
    u0[0] += h0 * bf2f(w0v.x); u0[1] += h0 * bf2f(w0v.y);
    u0[2] += h0 * bf2f(w0v.z); u0[3] += h0 * bf2f(w0v.w);
    u1[0] += h1b * bf2f(w1v.x); u1[1] += h1b * bf2f(w1v.y);
    u1[2] += h1b * bf2f(w1v.z); u1[3] += h1b * bf2f(w1v.w);
    u2[0] += h2b * bf2f(w2v.x); u2[1] += h2b * bf2f(w2v.y);
    u2[2] += h2b * bf2f(w2v.z); u2[3] += h2b * bf2f(w2v.w);
  }
  #pragma unroll
  for (int c = 0; c < 4; ++c) {
    u0[c] += __shfl_xor(u0[c], 16); u0[c] += __shfl_xor(u0[c], 32);
    u1[c] += __shfl_xor(u1[c], 16); u1[c] += __shfl_xor(u1[c], 32);
    u2[c] += __shfl_xor(u2[c], 16); u2[c] += __shfl_xor(u2[c], 32);
  }
  float p0 = 0.f, p1 = 0.f, p2 = 0.f;
  #pragma unroll
  for (int c = 0; c < 4; ++c) {
    int j = dq * 4 + c;
    p0 += tanhf(u0[c] + bfL[j])       * qfL[j];
    p1 += tanhf(u1[c] + bfL[64 + j])  * qfL[64 + j];
    p2 += tanhf(u2[c] + bfL[128 + j]) * qfL[128 + j];
  }
  #pragma unroll
  for (int off = 1; off < 16; off <<= 1) {
    p0 += __shfl_xor(p0, off);
    p1 += __shfl_xor(p1, off);
    p2 += __shfl_xor(p2, off);
  }
  float mx = fmaxf(p0, fmaxf(p1, p2));
  float e0 = expf(p0 - mx), e1 = expf(p1 - mx), e2 = expf(p2 - mx);
  float inv = 1.0f / (e0 + e1 + e2);
  float aw0 = e0 * inv, aw1 = e1 * inv, aw2 = e2 * inv;
  float fv = aw0 * hid0 + aw1 * hid1 + aw2 * hid2;
  dout[OFF_FUSED + (size_t)n * 64 + lane] = fv;
  if (lane < 3) dout[OFF_ATTN + (size_t)n * 3 + lane] =
                    (lane == 0 ? aw0 : (lane == 1 ? aw1 : aw2));
}

// ---- layer2 gather (packed LDS staging): agg = sym-aggregate(fused) ----
__global__ __launch_bounds__(256) void k_agg2(
    const int* __restrict__ csr_s, const float4* __restrict__ csr_w,
    const unsigned* __restrict__ row_ptr, const float* __restrict__ dis2,
    const float* __restrict__ dout, float* __restrict__ agg) {
  __shared__ uint2 eL[4][64];
  const float* fused = dout + OFF_FUSED;
  int tid = threadIdx.x, wid = tid >> 6, lane = tid & 63;
  int n = blockIdx.x * 4 + wid;
  if (n >= NN) return;
  float dd = dis2[n];
  float acc[4] = {0.f, 0.f, 0.f, 0.f};
  int g = lane >> 4, dq = lane & 15;
  unsigned beg = row_ptr[n], end = row_ptr[n + 1];
  for (unsigned base = beg; base < end; base += 64) {
    unsigned rem = end - base;
    int m = (rem > 64u) ? 64 : (int)rem;
    uint2 st = make_uint2(0u, 0u);
    if (lane < m)
      st = make_uint2((unsigned)csr_s[base + lane],
                      __float_as_uint(csr_w[base + lane].w * dd));
    eL[wid][lane] = st;
    int jmax = (m + 3) >> 2;
    for (int j = 0; j < jmax; ++j) {
      uint2 e = eL[wid][j * 4 + g];
      int sj = (int)e.x;
      float wj = __uint_as_float(e.y);
      float4 fr = *(const float4*)&fused[(size_t)sj * 64 + dq * 4];
      acc[0] += wj * fr.x; acc[1] += wj * fr.y;
      acc[2] += wj * fr.z; acc[3] += wj * fr.w;
    }
  }
  #pragma unroll
  for (int c = 0; c < 4; ++c) {
    acc[c] += __shfl_xor(acc[c], 16);
    acc[c] += __shfl_xor(acc[c], 32);
  }
  if (lane < 16) {
    float4 sf = *(const float4*)&fused[(size_t)n * 64 + lane * 4];
    float sw = dd * dd;
    *(float4*)&agg[(size_t)n * 64 + lane * 4] =
        make_float4(acc[0] + sw * sf.x, acc[1] + sw * sf.y,
                    acc[2] + sw * sf.z, acc[3] + sw * sf.w);
  }
}

// ---- emb = relu(agg @ W2 + b2) (LDS broadcast matvec, float4 out) ----
__global__ __launch_bounds__(256) void k_emb2(const float* __restrict__ agg,
                                              const void* W2, const void* b2,
                                              const int* __restrict__ flags,
                                              float* __restrict__ dout) {
  __shared__ u16 W2L[64 * 256];
  __shared__ float agL[4][64];
  __shared__ float b2L[256];
  int tid = threadIdx.x, f32 = flags[0];
  for (int i = tid; i < 64 * 256; i += 256)
    W2L[i] = f32 ? f2bf(((const float*)W2)[i]) : ((const u16*)W2)[i];
  b2L[tid] = ldf(b2, tid, f32);
  {
    int r = tid >> 6, c = tid & 63;
    int row = blockIdx.x * 4 + r;
    agL[r][c] = (row < NN) ? agg[(size_t)row * 64 + c] : 0.f;
  }
  __syncthreads();
  int wid = tid >> 6, lane = tid & 63;
  int n = blockIdx.x * 4 + wid;
  if (n >= NN) return;
  float acc0 = b2L[lane * 4], acc1 = b2L[lane * 4 + 1];
  float acc2 = b2L[lane * 4 + 2], acc3 = b2L[lane * 4 + 3];
  #pragma unroll 8
  for (int k = 0; k < 64; ++k) {
    float a = agL[wid][k];
    ushort4 wv = *(const ushort4*)&W2L[k * 256 + lane * 4];
    acc0 += a * bf2f(wv.x); acc1 += a * bf2f(wv.y);
    acc2 += a * bf2f(wv.z); acc3 += a * bf2f(wv.w);
  }
  *(float4*)&dout[OFF_EMB + (size_t)n * 256 + lane * 4] =
      make_float4(fmaxf(acc0, 0.f), fmaxf(acc1, 0.f),
                  fmaxf(acc2, 0.f), fmaxf(acc3, 0.f));
}

// ---- vsum = graph_neigh @ fused (LDS gn tiles) + fused row sums ----
__global__ __launch_bounds__(256) void k_vsum(const void* gn,
                                              const float* __restrict__ dout,
                                              const int* __restrict__ flags,
                                              float* __restrict__ part,
                                              float* __restrict__ rspart) {
  __shared__ float gnL[8][1024];
  const float* fused = dout + OFF_FUSED;
  int tid = threadIdx.x, wid = tid >> 6, lane = tid & 63;
  int f32 = flags[0];
  int ks = blockIdx.x, bg = blockIdx.y;
  int nbase = ks * 1024;
  #pragma unroll
  for (int r = 0; r < 8; ++r) {
    #pragma unroll
    for (int i = 0; i < 4; ++i) {
      int colv = i * 256 + tid;
      int nn = nbase + colv;
      gnL[r][colv] = (nn < NN) ? ldf(gn, (size_t)(bg * 8 + r) * NN + nn, f32) : 0.f;
    }
  }
  __syncthreads();
  // row sums from staged tile: wave wid handles rows {2*wid, 2*wid+1}
  #pragma unroll
  for (int rr = 0; rr < 2; ++rr) {
    int r = wid * 2 + rr;
    float s = 0.f;
    #pragma unroll
    for (int i = 0; i < 16; ++i) s += gnL[r][i * 64 + lane];
    #pragma unroll
    for (int off = 32; off > 0; off >>= 1) s += __shfl_down(s, off);
    if (lane == 0) rspart[(size_t)ks * 256 + bg * 8 + r] = s;
  }
  int g = lane >> 4, dq = lane & 15;
  float acc[8][4];
  #pragma unroll
  for (int r = 0; r < 8; ++r)
    #pragma unroll
    for (int c = 0; c < 4; ++c) acc[r][c] = 0.f;
  for (int i = 0; i < 64; ++i) {
    int nloc = wid * 256 + i * 4 + g;
    int nn = nbase + nloc;
    float4 fr = (nn < NN) ? *(const float4*)&fused[(size_t)nn * 64 + dq * 4]
                          : make_float4(0.f, 0.f, 0.f, 0.f);
    #pragma unroll
    for (int r = 0; r < 8; ++r) {
      float gv = gnL[r][nloc];
      acc[r][0] += gv * fr.x; acc[r][1] += gv * fr.y;
      acc[r][2] += gv * fr.z; acc[r][3] += gv * fr.w;
    }
  }
  #pragma unroll
  for (int r = 0; r < 8; ++r)
    #pragma unroll
    for (int c = 0; c < 4; ++c) {
      acc[r][c] += __shfl_xor(acc[r][c], 16);
      acc[r][c] += __shfl_xor(acc[r][c], 32);
    }
  if (lane < 16) {
    int slice = ks * 4 + wid;
    #pragma unroll
    for (int r = 0; r < 8; ++r)
      *(float4*)&part[((size_t)slice * 256 + bg * 8 + r) * 64 + lane * 4] =
          make_float4(acc[r][0], acc[r][1], acc[r][2], acc[r][3]);
  }
}

// ---- g finalize: reduce partials, divide by row_sum, L2 normalize ----
__global__ __launch_bounds__(64) void k_gfinal(const float* __restrict__ part,
                                               const float* __restrict__ rspart,
                                               float* __restrict__ dout) {
  int b = blockIdx.x, j = threadIdx.x;
  float acc = 0.f;
  for (int k = 0; k < VS_SL; ++k) acc += part[((size_t)k * 256 + b) * 64 + j];
  float rs = 0.f;
  for (int k = 0; k < VS_NC; ++k) rs += rspart[(size_t)k * 256 + b];
  float v = acc / rs;
  float sq = v * v;
  #pragma unroll
  for (int off = 32; off > 0; off >>= 1) sq += __shfl_xor(sq, off);
  float nrm = sqrtf(sq);
  dout[OFF_G + (size_t)b * 64 + j] = v / fmaxf(nrm, 1e-12f);
}

extern "C" void kernel_launch(void* const* d_in, const int* in_sizes, int n_in,
                              void* d_out, int out_size, void* d_ws, size_t ws_size,
                              hipStream_t stream) {
  const void* x   = d_in[0];
  const void* ei  = d_in[1];
  const void* gn  = d_in[2];
  const void* aew = d_in[3];
  const void* W1  = d_in[4];
  const void* b1  = d_in[5];
  const void* W2  = d_in[6];
  const void* b2  = d_in[7];
  const void* Wf  = d_in[8];
  const void* bfv = d_in[9];
  const void* qf  = d_in[10];

  char* ws = (char*)d_ws;
  size_t off = 0;
  auto alloc = [&](size_t bytes) -> void* {
    void* p = ws + off;
    off += (bytes + 255) & ~(size_t)255;
    return p;
  };
  // zero-init region (atomically accumulated buffers only)
  float*    deg     = (float*)alloc((size_t)3 * NN * 4);
  unsigned* cnt     = (unsigned*)alloc((size_t)NN * 4);
  unsigned* fill    = (unsigned*)alloc((size_t)NN * 4);
  size_t zero_bytes = off;
  int*      flags   = (int*)alloc(64);
  float*    dis2    = (float*)alloc((size_t)NN * 4);
  unsigned* row_ptr = (unsigned*)alloc((size_t)(NN + 1) * 4);
  unsigned* bsum    = (unsigned*)alloc((size_t)NSCB * 4);
  unsigned* boff    = (unsigned*)alloc((size_t)NSCB * 4);
  int*      csr_s   = (int*)alloc((size_t)NE * 4);
  float4*   csr_w   = (float4*)alloc((size_t)NE * 16);
  // time-shared region: h1 (k_h1v->k_hidden), agg (k_agg2->k_emb2), part (k_vsum->k_gfinal)
  size_t regA_bytes = (size_t)VS_SL * NB * 64 * 4;
  char*  regA       = (char*)alloc(regA_bytes);
  float* h1   = (float*)regA;
  float* agg  = (float*)regA;
  float* part = (float*)regA;
  float* rspart = (float*)alloc((size_t)VS_NC * NB * 4);

  float* dout = (float*)d_out;

  hipMemsetAsync(d_ws, 0, zero_bytes, stream);
  k_detect<<<1, 64, 0, stream>>>(x, ei, flags);
  k_deg<<<(NE + 255) / 256, 256, 0, stream>>>(ei, aew, flags, deg, cnt);
  k_dis<<<(3 * NN + 255) / 256, 256, 0, stream>>>(deg, cnt, dis2);
  k_sc1<<<NSCB, 256, 0, stream>>>(cnt, bsum);
  k_sc2<<<1, 256, 0, stream>>>(bsum, boff, row_ptr);
  k_sc3<<<NSCB, 256, 0, stream>>>(cnt, boff, row_ptr);
  k_fill<<<(NE + 255) / 256, 256, 0, stream>>>(ei, flags, row_ptr, deg, dis2, aew,
                                               fill, csr_s, csr_w);
  k_h1v<<<(NN + 3) / 4, 256, 0, stream>>>(x, W1, flags, h1);
  k_hidden<<<(NN + 3) / 4, 256, 0, stream>>>(h1, csr_s, csr_w, row_ptr, deg,
                                             Wf, bfv, qf, b1, flags, dout);
  k_agg2<<<(NN + 3) / 4, 256, 0, stream>>>(csr_s, csr_w, row_ptr, dis2, dout, agg);
  k_emb2<<<(NN + 3) / 4, 256, 0, stream>>>(agg, W2, b2, flags, dout);
  {
    dim3 gdim(VS_NC, 32);
    k_vsum<<<gdim, 256, 0, stream>>>(gn, dout, flags, part, rspart);
  }
  k_gfinal<<<NB, 64, 0, stream>>>(part, rspart, dout);
}

// Round 9
// 877.946 us; speedup vs baseline: 3.2643x; 1.0473x over previous
//
#include <hip/hip_runtime.h>
#include <hip/hip_bf16.h>

#define NN 50000
#define NE 800000
#define NG 3
#define NB 256
#define NSCB 196  // ceil(NN/256)

#define OFF_FUSED ((size_t)0)
#define OFF_EMB   ((size_t)NN * 64)
#define OFF_G     (OFF_EMB + (size_t)NN * 256)
#define OFF_HID   (OFF_G + (size_t)NB * 64)
#define OFF_ATTN  (OFF_HID + (size_t)3 * NN * 64)

// k_vsum geometry: 49 n-chunks of 1024; 32 b-groups of 8 rows; slice = ks*4+wave
#define VS_NC 49
#define VS_SL (VS_NC * 4)

typedef unsigned short u16;

__device__ __forceinline__ float bf2f(u16 u) {
  union { unsigned int i; float f; } v; v.i = ((unsigned int)u) << 16; return v.f;
}
__device__ __forceinline__ u16 f2bf(float f) {
  unsigned int x = __float_as_uint(f);
  unsigned int r = (x + 0x7FFFu + ((x >> 16) & 1u)) >> 16;
  return (u16)r;
}
__device__ __forceinline__ float ldf(const void* p, size_t i, int f32) {
  return f32 ? ((const float*)p)[i] : bf2f(((const u16*)p)[i]);
}
__device__ __forceinline__ int ld_src(const void* ei, int e, int i64) {
  return i64 ? (int)((const long long*)ei)[e] : ((const int*)ei)[e];
}
__device__ __forceinline__ int ld_dst(const void* ei, int e, int i64) {
  return i64 ? (int)((const long long*)ei)[(size_t)NE + e] : ((const int*)ei)[(size_t)NE + e];
}

// ---- dtype detection ----
__global__ void k_detect(const void* x, const void* ei, int* flags) {
  if (threadIdx.x != 0 || blockIdx.x != 0) return;
  const u16* xw = (const u16*)x;
  int sane = 0;
  for (int i = 0; i < 64; ++i) {
    unsigned ex = (xw[2 * i] >> 7) & 0xFF;
    sane += (ex >= 96 && ex <= 141);
  }
  flags[0] = (sane < 48) ? 1 : 0;  // 1 => inputs are float32
  const int* e32 = (const int*)ei;
  int zeros = 0;
  for (int t = 1; t < 32; t += 2) zeros += (e32[t] == 0);
  flags[1] = (zeros >= 12) ? 1 : 0;  // 1 => edge_index is int64
}

// ---- degree accumulation ----
__global__ void k_deg(const void* ei, const void* aew, const int* __restrict__ flags,
                      float* __restrict__ deg, unsigned* __restrict__ cnt) {
  int e = blockIdx.x * 256 + threadIdx.x;
  if (e >= NE) return;
  int f32 = flags[0], i64 = flags[1];
  int d = ld_dst(ei, e, i64);
  atomicAdd(&cnt[d], 1u);
  atomicAdd(&deg[d],          ldf(aew, e, f32));
  atomicAdd(&deg[NN + d],     ldf(aew, (size_t)NE + e, f32));
  atomicAdd(&deg[2 * NN + d], ldf(aew, (size_t)2 * NE + e, f32));
}

__global__ void k_dis(float* __restrict__ deg, const unsigned* __restrict__ cnt,
                      float* __restrict__ dis2) {
  int i = blockIdx.x * 256 + threadIdx.x;
  if (i < 3 * NN) deg[i] = rsqrtf(deg[i] + 1.0f);
  if (i < NN) dis2[i] = rsqrtf((float)cnt[i] + 1.0f);
}

// ---- 3-phase exclusive scan of cnt -> row_ptr ----
__global__ __launch_bounds__(256) void k_sc1(const unsigned* __restrict__ cnt,
                                             unsigned* __restrict__ bsum) {
  int b = blockIdx.x, tid = threadIdx.x, i = b * 256 + tid;
  unsigned v = (i < NN) ? cnt[i] : 0u;
  #pragma unroll
  for (int off = 32; off > 0; off >>= 1) v += __shfl_down(v, off);
  __shared__ unsigned w4[4];
  if ((tid & 63) == 0) w4[tid >> 6] = v;
  __syncthreads();
  if (tid == 0) bsum[b] = w4[0] + w4[1] + w4[2] + w4[3];
}
__global__ __launch_bounds__(256) void k_sc2(const unsigned* __restrict__ bsum,
                                             unsigned* __restrict__ boff,
                                             unsigned* __restrict__ row_ptr) {
  int tid = threadIdx.x, lane = tid & 63, w = tid >> 6;
  unsigned v = (tid < NSCB) ? bsum[tid] : 0u;
  unsigned x = v;
  #pragma unroll
  for (int off = 1; off < 64; off <<= 1) {
    unsigned y = __shfl_up(x, off);
    if (lane >= off) x += y;
  }
  __shared__ unsigned w4[4];
  if (lane == 63) w4[w] = x;
  __syncthreads();
  unsigned woff = 0;
  #pragma unroll
  for (int k = 0; k < 4; ++k) woff += (k < w) ? w4[k] : 0u;
  if (tid < NSCB) boff[tid] = woff + x - v;
  if (tid == 255) row_ptr[NN] = woff + x;
}
__global__ __launch_bounds__(256) void k_sc3(const unsigned* __restrict__ cnt,
                                             const unsigned* __restrict__ boff,
                                             unsigned* __restrict__ row_ptr) {
  int b = blockIdx.x, tid = threadIdx.x, lane = tid & 63, w = tid >> 6;
  int i = b * 256 + tid;
  unsigned v = (i < NN) ? cnt[i] : 0u;
  unsigned x = v;
  #pragma unroll
  for (int off = 1; off < 64; off <<= 1) {
    unsigned y = __shfl_up(x, off);
    if (lane >= off) x += y;
  }
  __shared__ unsigned w4[4];
  if (lane == 63) w4[w] = x;
  __syncthreads();
  unsigned woff = 0;
  #pragma unroll
  for (int k = 0; k < 4; ++k) woff += (k < w) ? w4[k] : 0u;
  if (i < NN) row_ptr[i] = boff[b] + woff + x - v;
}

// ---- CSR fill with packed, pre-normalized edge data ----
__global__ void k_fill(const void* ei, const int* __restrict__ flags,
                       const unsigned* __restrict__ row_ptr,
                       const float* __restrict__ dis, const float* __restrict__ dis2,
                       const void* aew, unsigned* __restrict__ fill,
                       int* __restrict__ csr_s, float4* __restrict__ csr_w) {
  int e = blockIdx.x * 256 + threadIdx.x;
  if (e >= NE) return;
  int f32 = flags[0], i64 = flags[1];
  int s = ld_src(ei, e, i64);
  int d = ld_dst(ei, e, i64);
  unsigned pos = row_ptr[d] + atomicAdd(&fill[d], 1u);
  float w0 = dis[s]          * ldf(aew, e, f32);
  float w1 = dis[NN + s]     * ldf(aew, (size_t)NE + e, f32);
  float w2 = dis[2 * NN + s] * ldf(aew, (size_t)2 * NE + e, f32);
  csr_s[pos] = s;
  csr_w[pos] = make_float4(w0, w1, w2, dis2[s]);
}

// ---- h1 = x @ W1 (vectorized: 4 k-quarters in parallel, LDS broadcast) ----
__global__ __launch_bounds__(256) void k_h1v(const void* x, const void* W1,
                                             const int* __restrict__ flags,
                                             float* __restrict__ h1) {
  __shared__ u16 W1L[256 * 64];
  __shared__ float xL[4][256];
  int tid = threadIdx.x, f32 = flags[0];
  for (int i = tid; i < 256 * 64; i += 256)
    W1L[i] = f32 ? f2bf(((const float*)W1)[i]) : ((const u16*)W1)[i];
  #pragma unroll
  for (int r = 0; r < 4; ++r) {
    int row = blockIdx.x * 4 + r;
    xL[r][tid] = (row < NN) ? ldf(x, (size_t)row * 256 + tid, f32) : 0.f;
  }
  __syncthreads();
  int wid = tid >> 6, lane = tid & 63;
  int n = blockIdx.x * 4 + wid;
  if (n >= NN) return;
  int g = lane >> 4, dq = lane & 15;
  float acc[4] = {0.f, 0.f, 0.f, 0.f};
  #pragma unroll 8
  for (int kk = 0; kk < 64; ++kk) {
    int k = g * 64 + kk;
    float a = xL[wid][k];
    ushort4 wv = *(const ushort4*)&W1L[k * 64 + dq * 4];
    acc[0] += a * bf2f(wv.x); acc[1] += a * bf2f(wv.y);
    acc[2] += a * bf2f(wv.z); acc[3] += a * bf2f(wv.w);
  }
  #pragma unroll
  for (int c = 0; c < 4; ++c) {
    acc[c] += __shfl_xor(acc[c], 16);
    acc[c] += __shfl_xor(acc[c], 32);
  }
  if (lane < 16)
    *(float4*)&h1[(size_t)n * 64 + lane * 4] = make_float4(acc[0], acc[1], acc[2], acc[3]);
}

// ---- gather layer1 only (3 graphs), max occupancy ----
__global__ __launch_bounds__(256) void k_gath1(
    const float* __restrict__ h1, const int* __restrict__ csr_s,
    const float4* __restrict__ csr_w, const unsigned* __restrict__ row_ptr,
    const float* __restrict__ deg_dis, const void* b1,
    const int* __restrict__ flags, float* __restrict__ dout) {
  __shared__ float4 eWL[4][64];  // 4 KB per-wave edge staging
  __shared__ float b1L[64];
  int tid = threadIdx.x, f32 = flags[0];
  if (tid < 64) b1L[tid] = ldf(b1, tid, f32);
  __syncthreads();
  int wid = tid >> 6, lane = tid & 63;
  int n = blockIdx.x * 4 + wid;
  if (n >= NN) return;

  float dd0 = deg_dis[n], dd1 = deg_dis[NN + n], dd2 = deg_dis[2 * NN + n];
  float a0[4] = {0,0,0,0}, a1[4] = {0,0,0,0}, a2[4] = {0,0,0,0};
  int g = lane >> 4, dq = lane & 15;
  unsigned beg = row_ptr[n], end = row_ptr[n + 1];
  for (unsigned base = beg; base < end; base += 64) {
    unsigned rem = end - base;
    int m = (rem > 64u) ? 64 : (int)rem;
    float4 st = make_float4(0.f, 0.f, 0.f, __int_as_float(0));
    if (lane < m) {
      float4 cw = csr_w[base + lane];
      int s = csr_s[base + lane];
      st = make_float4(cw.x * dd0, cw.y * dd1, cw.z * dd2, __int_as_float(s));
    }
    eWL[wid][lane] = st;   // wave-private row; same-wave LDS ops are in-order
    int jmax = (m + 3) >> 2;
    for (int j = 0; j < jmax; ++j) {
      float4 e = eWL[wid][j * 4 + g];
      int sj = __float_as_int(e.w);
      float4 hr = *(const float4*)&h1[(size_t)sj * 64 + dq * 4];
      a0[0] += e.x * hr.x; a0[1] += e.x * hr.y; a0[2] += e.x * hr.z; a0[3] += e.x * hr.w;
      a1[0] += e.y * hr.x; a1[1] += e.y * hr.y; a1[2] += e.y * hr.z; a1[3] += e.y * hr.w;
      a2[0] += e.z * hr.x; a2[1] += e.z * hr.y; a2[2] += e.z * hr.z; a2[3] += e.z * hr.w;
    }
  }
  #pragma unroll
  for (int c = 0; c < 4; ++c) {
    a0[c] += __shfl_xor(a0[c], 16); a0[c] += __shfl_xor(a0[c], 32);
    a1[c] += __shfl_xor(a1[c], 16); a1[c] += __shfl_xor(a1[c], 32);
    a2[c] += __shfl_xor(a2[c], 16); a2[c] += __shfl_xor(a2[c], 32);
  }
  // redistribute to lane=dim layout
  int srcl = lane >> 2, cc = lane & 3;
  float t0, t1, t2, t3, r0, r1, r2;
  t0 = __shfl(a0[0], srcl); t1 = __shfl(a0[1], srcl);
  t2 = __shfl(a0[2], srcl); t3 = __shfl(a0[3], srcl);
  r0 = cc == 0 ? t0 : cc == 1 ? t1 : cc == 2 ? t2 : t3;
  t0 = __shfl(a1[0], srcl); t1 = __shfl(a1[1], srcl);
  t2 = __shfl(a1[2], srcl); t3 = __shfl(a1[3], srcl);
  r1 = cc == 0 ? t0 : cc == 1 ? t1 : cc == 2 ? t2 : t3;
  t0 = __shfl(a2[0], srcl); t1 = __shfl(a2[1], srcl);
  t2 = __shfl(a2[2], srcl); t3 = __shfl(a2[3], srcl);
  r2 = cc == 0 ? t0 : cc == 1 ? t1 : cc == 2 ? t2 : t3;

  float selfv = h1[(size_t)n * 64 + lane];
  float b1v = b1L[lane];
  dout[OFF_HID + ((size_t)0 * NN + n) * 64 + lane] = fmaxf(r0 + dd0 * dd0 * selfv + b1v, 0.f);
  dout[OFF_HID + ((size_t)1 * NN + n) * 64 + lane] = fmaxf(r1 + dd1 * dd1 * selfv + b1v, 0.f);
  dout[OFF_HID + ((size_t)2 * NN + n) * 64 + lane] = fmaxf(r2 + dd2 * dd2 * selfv + b1v, 0.f);
}

// ---- dense attention: t=tanh(hid@Wf+bf), scores, softmax, fused ----
#define WFS 66  // Wf LDS row stride in shorts: 2-way bank aliasing only
__global__ __launch_bounds__(256) void k_attn(
    const void* Wf, const void* bfv, const void* qf,
    const int* __restrict__ flags, float* __restrict__ dout) {
  __shared__ u16 WfL[3 * 64 * WFS];
  __shared__ float qfL[192], bfL[192];
  int tid = threadIdx.x, f32 = flags[0];
  for (int i = tid; i < 3 * 64 * 64; i += 256) {
    int gi = i >> 12, rem = i & 4095, k = rem >> 6, j = rem & 63;
    WfL[gi * 64 * WFS + k * WFS + j] =
        f32 ? f2bf(((const float*)Wf)[i]) : ((const u16*)Wf)[i];
  }
  if (tid < 192) { qfL[tid] = ldf(qf, tid, f32); bfL[tid] = ldf(bfv, tid, f32); }
  __syncthreads();
  int wid = tid >> 6, lane = tid & 63;
  int n = blockIdx.x * 4 + wid;
  if (n >= NN) return;

  float hid0 = dout[OFF_HID + ((size_t)0 * NN + n) * 64 + lane];
  float hid1 = dout[OFF_HID + ((size_t)1 * NN + n) * 64 + lane];
  float hid2 = dout[OFF_HID + ((size_t)2 * NN + n) * 64 + lane];

  int g = lane >> 4, dq = lane & 15;
  float u0[4] = {0,0,0,0}, u1[4] = {0,0,0,0}, u2[4] = {0,0,0,0};
  #pragma unroll 4
  for (int kk = 0; kk < 16; ++kk) {
    int k = g * 16 + kk;
    float h0 = __shfl(hid0, k), h1b = __shfl(hid1, k), h2b = __shfl(hid2, k);
    ushort4 w0v = *(const ushort4*)&WfL[k * WFS + dq * 4];
    ushort4 w1v = *(const ushort4*)&WfL[64 * WFS + k * WFS + dq * 4];
    ushort4 w2v = *(const ushort4*)&WfL[128 * WFS + k * WFS + dq * 4];
    u0[0] += h0 * bf2f(w0v.x); u0[1] += h0 * bf2f(w0v.y);
    u0[2] += h0 * bf2f(w0v.z); u0[3] += h0 * bf2f(w0v.w);
    u1[0] += h1b * bf2f(w1v.x); u1[1] += h1b * bf2f(w1v.y);
    u1[2] += h1b * bf2f(w1v.z); u1[3] += h1b * bf2f(w1v.w);
    u2[0] += h2b * bf2f(w2v.x); u2[1] += h2b * bf2f(w2v.y);
    u2[2] += h2b * bf2f(w2v.z); u2[3] += h2b * bf2f(w2v.w);
  }
  #pragma unroll
  for (int c = 0; c < 4; ++c) {
    u0[c] += __shfl_xor(u0[c], 16); u0[c] += __shfl_xor(u0[c], 32);
    u1[c] += __shfl_xor(u1[c], 16); u1[c] += __shfl_xor(u1[c], 32);
    u2[c] += __shfl_xor(u2[c], 16); u2[c] += __shfl_xor(u2[c], 32);
  }
  // redistribute to lane=dim, then only 3 tanh per lane
  int srcl = lane >> 2, cc = lane & 3;
  float t0, t1, t2, t3, v0, v1, v2;
  t0 = __shfl(u0[0], srcl); t1 = __shfl(u0[1], srcl);
  t2 = __shfl(u0[2], srcl); t3 = __shfl(u0[3], srcl);
  v0 = cc == 0 ? t0 : cc == 1 ? t1 : cc == 2 ? t2 : t3;
  t0 = __shfl(u1[0], srcl); t1 = __shfl(u1[1], srcl);
  t2 = __shfl(u1[2], srcl); t3 = __shfl(u1[3], srcl);
  v1 = cc == 0 ? t0 : cc == 1 ? t1 : cc == 2 ? t2 : t3;
  t0 = __shfl(u2[0], srcl); t1 = __shfl(u2[1], srcl);
  t2 = __shfl(u2[2], srcl); t3 = __shfl(u2[3], srcl);
  v2 = cc == 0 ? t0 : cc == 1 ? t1 : cc == 2 ? t2 : t3;

  float p0 = tanhf(v0 + bfL[lane])       * qfL[lane];
  float p1 = tanhf(v1 + bfL[64 + lane])  * qfL[64 + lane];
  float p2 = tanhf(v2 + bfL[128 + lane]) * qfL[128 + lane];
  #pragma unroll
  for (int off = 32; off > 0; off >>= 1) {
    p0 += __shfl_xor(p0, off);
    p1 += __shfl_xor(p1, off);
    p2 += __shfl_xor(p2, off);
  }
  float mx = fmaxf(p0, fmaxf(p1, p2));
  float e0 = expf(p0 - mx), e1 = expf(p1 - mx), e2 = expf(p2 - mx);
  float inv = 1.0f / (e0 + e1 + e2);
  float aw0 = e0 * inv, aw1 = e1 * inv, aw2 = e2 * inv;
  float fv = aw0 * hid0 + aw1 * hid1 + aw2 * hid2;
  dout[OFF_FUSED + (size_t)n * 64 + lane] = fv;
  if (lane < 3) dout[OFF_ATTN + (size_t)n * 3 + lane] =
                    (lane == 0 ? aw0 : (lane == 1 ? aw1 : aw2));
}

// ---- layer2 gather (packed LDS staging): agg = sym-aggregate(fused) ----
__global__ __launch_bounds__(256) void k_agg2(
    const int* __restrict__ csr_s, const float4* __restrict__ csr_w,
    const unsigned* __restrict__ row_ptr, const float* __restrict__ dis2,
    const float* __restrict__ dout, float* __restrict__ agg) {
  __shared__ uint2 eL[4][64];
  const float* fused = dout + OFF_FUSED;
  int tid = threadIdx.x, wid = tid >> 6, lane = tid & 63;
  int n = blockIdx.x * 4 + wid;
  if (n >= NN) return;
  float dd = dis2[n];
  float acc[4] = {0.f, 0.f, 0.f, 0.f};
  int g = lane >> 4, dq = lane & 15;
  unsigned beg = row_ptr[n], end = row_ptr[n + 1];
  for (unsigned base = beg; base < end; base += 64) {
    unsigned rem = end - base;
    int m = (rem > 64u) ? 64 : (int)rem;
    uint2 st = make_uint2(0u, 0u);
    if (lane < m)
      st = make_uint2((unsigned)csr_s[base + lane],
                      __float_as_uint(csr_w[base + lane].w * dd));
    eL[wid][lane] = st;
    int jmax = (m + 3) >> 2;
    for (int j = 0; j < jmax; ++j) {
      uint2 e = eL[wid][j * 4 + g];
      int sj = (int)e.x;
      float wj = __uint_as_float(e.y);
      float4 fr = *(const float4*)&fused[(size_t)sj * 64 + dq * 4];
      acc[0] += wj * fr.x; acc[1] += wj * fr.y;
      acc[2] += wj * fr.z; acc[3] += wj * fr.w;
    }
  }
  #pragma unroll
  for (int c = 0; c < 4; ++c) {
    acc[c] += __shfl_xor(acc[c], 16);
    acc[c] += __shfl_xor(acc[c], 32);
  }
  if (lane < 16) {
    float4 sf = *(const float4*)&fused[(size_t)n * 64 + lane * 4];
    float sw = dd * dd;
    *(float4*)&agg[(size_t)n * 64 + lane * 4] =
        make_float4(acc[0] + sw * sf.x, acc[1] + sw * sf.y,
                    acc[2] + sw * sf.z, acc[3] + sw * sf.w);
  }
}

// ---- emb = relu(agg @ W2 + b2) (LDS broadcast matvec, float4 out) ----
__global__ __launch_bounds__(256) void k_emb2(const float* __restrict__ agg,
                                              const void* W2, const void* b2,
                                              const int* __restrict__ flags,
                                              float* __restrict__ dout) {
  __shared__ u16 W2L[64 * 256];
  __shared__ float agL[4][64];
  __shared__ float b2L[256];
  int tid = threadIdx.x, f32 = flags[0];
  for (int i = tid; i < 64 * 256; i += 256)
    W2L[i] = f32 ? f2bf(((const float*)W2)[i]) : ((const u16*)W2)[i];
  b2L[tid] = ldf(b2, tid, f32);
  {
    int r = tid >> 6, c = tid & 63;
    int row = blockIdx.x * 4 + r;
    agL[r][c] = (row < NN) ? agg[(size_t)row * 64 + c] : 0.f;
  }
  __syncthreads();
  int wid = tid >> 6, lane = tid & 63;
  int n = blockIdx.x * 4 + wid;
  if (n >= NN) return;
  float acc0 = b2L[lane * 4], acc1 = b2L[lane * 4 + 1];
  float acc2 = b2L[lane * 4 + 2], acc3 = b2L[lane * 4 + 3];
  #pragma unroll 8
  for (int k = 0; k < 64; ++k) {
    float a = agL[wid][k];
    ushort4 wv = *(const ushort4*)&W2L[k * 256 + lane * 4];
    acc0 += a * bf2f(wv.x); acc1 += a * bf2f(wv.y);
    acc2 += a * bf2f(wv.z); acc3 += a * bf2f(wv.w);
  }
  *(float4*)&dout[OFF_EMB + (size_t)n * 256 + lane * 4] =
      make_float4(fmaxf(acc0, 0.f), fmaxf(acc1, 0.f),
                  fmaxf(acc2, 0.f), fmaxf(acc3, 0.f));
}

// ---- vsum = graph_neigh @ fused (LDS gn tiles) + fused row sums ----
__global__ __launch_bounds__(256) void k_vsum(const void* gn,
                                              const float* __restrict__ dout,
                                              const int* __restrict__ flags,
                                              float* __restrict__ part,
                                              float* __restrict__ rspart) {
  __shared__ float gnL[8][1024];
  const float* fused = dout + OFF_FUSED;
  int tid = threadIdx.x, wid = tid >> 6, lane = tid & 63;
  int f32 = flags[0];
  int ks = blockIdx.x, bg = blockIdx.y;
  int nbase = ks * 1024;
  #pragma unroll
  for (int r = 0; r < 8; ++r) {
    #pragma unroll
    for (int i = 0; i < 4; ++i) {
      int colv = i * 256 + tid;
      int nn = nbase + colv;
      gnL[r][colv] = (nn < NN) ? ldf(gn, (size_t)(bg * 8 + r) * NN + nn, f32) : 0.f;
    }
  }
  __syncthreads();
  #pragma unroll
  for (int rr = 0; rr < 2; ++rr) {
    int r = wid * 2 + rr;
    float s = 0.f;
    #pragma unroll
    for (int i = 0; i < 16; ++i) s += gnL[r][i * 64 + lane];
    #pragma unroll
    for (int off = 32; off > 0; off >>= 1) s += __shfl_down(s, off);
    if (lane == 0) rspart[(size_t)ks * 256 + bg * 8 + r] = s;
  }
  int g = lane >> 4, dq = lane & 15;
  float acc[8][4];
  #pragma unroll
  for (int r = 0; r < 8; ++r)
    #pragma unroll
    for (int c = 0; c < 4; ++c) acc[r][c] = 0.f;
  for (int i = 0; i < 64; ++i) {
    int nloc = wid * 256 + i * 4 + g;
    int nn = nbase + nloc;
    float4 fr = (nn < NN) ? *(const float4*)&fused[(size_t)nn * 64 + dq * 4]
                          : make_float4(0.f, 0.f, 0.f, 0.f);
    #pragma unroll
    for (int r = 0; r < 8; ++r) {
      float gv = gnL[r][nloc];
      acc[r][0] += gv * fr.x; acc[r][1] += gv * fr.y;
      acc[r][2] += gv * fr.z; acc[r][3] += gv * fr.w;
    }
  }
  #pragma unroll
  for (int r = 0; r < 8; ++r)
    #pragma unroll
    for (int c = 0; c < 4; ++c) {
      acc[r][c] += __shfl_xor(acc[r][c], 16);
      acc[r][c] += __shfl_xor(acc[r][c], 32);
    }
  if (lane < 16) {
    int slice = ks * 4 + wid;
    #pragma unroll
    for (int r = 0; r < 8; ++r)
      *(float4*)&part[((size_t)slice * 256 + bg * 8 + r) * 64 + lane * 4] =
          make_float4(acc[r][0], acc[r][1], acc[r][2], acc[r][3]);
  }
}

// ---- g finalize: reduce partials, divide by row_sum, L2 normalize ----
__global__ __launch_bounds__(64) void k_gfinal(const float* __restrict__ part,
                                               const float* __restrict__ rspart,
                                               float* __restrict__ dout) {
  int b = blockIdx.x, j = threadIdx.x;
  float acc = 0.f;
  for (int k = 0; k < VS_SL; ++k) acc += part[((size_t)k * 256 + b) * 64 + j];
  float rs = 0.f;
  for (int k = 0; k < VS_NC; ++k) rs += rspart[(size_t)k * 256 + b];
  float v = acc / rs;
  float sq = v * v;
  #pragma unroll
  for (int off = 32; off > 0; off >>= 1) sq += __shfl_xor(sq, off);
  float nrm = sqrtf(sq);
  dout[OFF_G + (size_t)b * 64 + j] = v / fmaxf(nrm, 1e-12f);
}

extern "C" void kernel_launch(void* const* d_in, const int* in_sizes, int n_in,
                              void* d_out, int out_size, void* d_ws, size_t ws_size,
                              hipStream_t stream) {
  const void* x   = d_in[0];
  const void* ei  = d_in[1];
  const void* gn  = d_in[2];
  const void* aew = d_in[3];
  const void* W1  = d_in[4];
  const void* b1  = d_in[5];
  const void* W2  = d_in[6];
  const void* b2  = d_in[7];
  const void* Wf  = d_in[8];
  const void* bfv = d_in[9];
  const void* qf  = d_in[10];

  char* ws = (char*)d_ws;
  size_t off = 0;
  auto alloc = [&](size_t bytes) -> void* {
    void* p = ws + off;
    off += (bytes + 255) & ~(size_t)255;
    return p;
  };
  // zero-init region (atomically accumulated buffers only)
  float*    deg     = (float*)alloc((size_t)3 * NN * 4);
  unsigned* cnt     = (unsigned*)alloc((size_t)NN * 4);
  unsigned* fill    = (unsigned*)alloc((size_t)NN * 4);
  size_t zero_bytes = off;
  int*      flags   = (int*)alloc(64);
  float*    dis2    = (float*)alloc((size_t)NN * 4);
  unsigned* row_ptr = (unsigned*)alloc((size_t)(NN + 1) * 4);
  unsigned* bsum    = (unsigned*)alloc((size_t)NSCB * 4);
  unsigned* boff    = (unsigned*)alloc((size_t)NSCB * 4);
  int*      csr_s   = (int*)alloc((size_t)NE * 4);
  float4*   csr_w   = (float4*)alloc((size_t)NE * 16);
  // time-shared region: h1 (k_h1v->k_gath1), agg (k_agg2->k_emb2), part (k_vsum->k_gfinal)
  size_t regA_bytes = (size_t)VS_SL * NB * 64 * 4;
  char*  regA       = (char*)alloc(regA_bytes);
  float* h1   = (float*)regA;
  float* agg  = (float*)regA;
  float* part = (float*)regA;
  float* rspart = (float*)alloc((size_t)VS_NC * NB * 4);

  float* dout = (float*)d_out;

  hipMemsetAsync(d_ws, 0, zero_bytes, stream);
  k_detect<<<1, 64, 0, stream>>>(x, ei, flags);
  k_deg<<<(NE + 255) / 256, 256, 0, stream>>>(ei, aew, flags, deg, cnt);
  k_dis<<<(3 * NN + 255) / 256, 256, 0, stream>>>(deg, cnt, dis2);
  k_sc1<<<NSCB, 256, 0, stream>>>(cnt, bsum);
  k_sc2<<<1, 256, 0, stream>>>(bsum, boff, row_ptr);
  k_sc3<<<NSCB, 256, 0, stream>>>(cnt, boff, row_ptr);
  k_fill<<<(NE + 255) / 256, 256, 0, stream>>>(ei, flags, row_ptr, deg, dis2, aew,
                                               fill, csr_s, csr_w);
  k_h1v<<<(NN + 3) / 4, 256, 0, stream>>>(x, W1, flags, h1);
  k_gath1<<<(NN + 3) / 4, 256, 0, stream>>>(h1, csr_s, csr_w, row_ptr, deg, b1,
                                            flags, dout);
  k_attn<<<(NN + 3) / 4, 256, 0, stream>>>(Wf, bfv, qf, flags, dout);
  k_agg2<<<(NN + 3) / 4, 256, 0, stream>>>(csr_s, csr_w, row_ptr, dis2, dout, agg);
  k_emb2<<<(NN + 3) / 4, 256, 0, stream>>>(agg, W2, b2, flags, dout);
  {
    dim3 gdim(VS_NC, 32);
    k_vsum<<<gdim, 256, 0, stream>>>(gn, dout, flags, part, rspart);
  }
  k_gfinal<<<NB, 64, 0, stream>>>(part, rspart, dout);
}

// Round 10
// 772.479 us; speedup vs baseline: 3.7100x; 1.1365x over previous
//
#include <hip/hip_runtime.h>
#include <hip/hip_bf16.h>

#define NN 50000
#define NE 800000
#define NG 3
#define NB 256
#define NSCB 196  // ceil(NN/256)

#define OFF_FUSED ((size_t)0)
#define OFF_EMB   ((size_t)NN * 64)
#define OFF_G     (OFF_EMB + (size_t)NN * 256)
#define OFF_HID   (OFF_G + (size_t)NB * 64)
#define OFF_ATTN  (OFF_HID + (size_t)3 * NN * 64)

// k_vsum geometry: 49 n-chunks of 1024; 32 b-groups of 8 rows; slice = ks*4+wave
#define VS_NC 49
#define VS_SL (VS_NC * 4)

typedef unsigned short u16;

__device__ __forceinline__ float bf2f(u16 u) {
  union { unsigned int i; float f; } v; v.i = ((unsigned int)u) << 16; return v.f;
}
__device__ __forceinline__ u16 f2bf(float f) {
  unsigned int x = __float_as_uint(f);
  unsigned int r = (x + 0x7FFFu + ((x >> 16) & 1u)) >> 16;
  return (u16)r;
}
__device__ __forceinline__ float ldf(const void* p, size_t i, int f32) {
  return f32 ? ((const float*)p)[i] : bf2f(((const u16*)p)[i]);
}
__device__ __forceinline__ int ld_src(const void* ei, int e, int i64) {
  return i64 ? (int)((const long long*)ei)[e] : ((const int*)ei)[e];
}
__device__ __forceinline__ int ld_dst(const void* ei, int e, int i64) {
  return i64 ? (int)((const long long*)ei)[(size_t)NE + e] : ((const int*)ei)[(size_t)NE + e];
}

// ---- dtype detection ----
__global__ void k_detect(const void* x, const void* ei, int* flags) {
  if (threadIdx.x != 0 || blockIdx.x != 0) return;
  const u16* xw = (const u16*)x;
  int sane = 0;
  for (int i = 0; i < 64; ++i) {
    unsigned ex = (xw[2 * i] >> 7) & 0xFF;
    sane += (ex >= 96 && ex <= 141);
  }
  flags[0] = (sane < 48) ? 1 : 0;  // 1 => inputs are float32
  const int* e32 = (const int*)ei;
  int zeros = 0;
  for (int t = 1; t < 32; t += 2) zeros += (e32[t] == 0);
  flags[1] = (zeros >= 12) ? 1 : 0;  // 1 => edge_index is int64
}

// ---- degree accumulation ----
__global__ void k_deg(const void* ei, const void* aew, const int* __restrict__ flags,
                      float* __restrict__ deg, unsigned* __restrict__ cnt) {
  int e = blockIdx.x * 256 + threadIdx.x;
  if (e >= NE) return;
  int f32 = flags[0], i64 = flags[1];
  int d = ld_dst(ei, e, i64);
  atomicAdd(&cnt[d], 1u);
  atomicAdd(&deg[d],          ldf(aew, e, f32));
  atomicAdd(&deg[NN + d],     ldf(aew, (size_t)NE + e, f32));
  atomicAdd(&deg[2 * NN + d], ldf(aew, (size_t)2 * NE + e, f32));
}

__global__ void k_dis(float* __restrict__ deg, const unsigned* __restrict__ cnt,
                      float* __restrict__ dis2) {
  int i = blockIdx.x * 256 + threadIdx.x;
  if (i < 3 * NN) deg[i] = rsqrtf(deg[i] + 1.0f);
  if (i < NN) dis2[i] = rsqrtf((float)cnt[i] + 1.0f);
}

// ---- 3-phase exclusive scan of cnt -> row_ptr ----
__global__ __launch_bounds__(256) void k_sc1(const unsigned* __restrict__ cnt,
                                             unsigned* __restrict__ bsum) {
  int b = blockIdx.x, tid = threadIdx.x, i = b * 256 + tid;
  unsigned v = (i < NN) ? cnt[i] : 0u;
  #pragma unroll
  for (int off = 32; off > 0; off >>= 1) v += __shfl_down(v, off);
  __shared__ unsigned w4[4];
  if ((tid & 63) == 0) w4[tid >> 6] = v;
  __syncthreads();
  if (tid == 0) bsum[b] = w4[0] + w4[1] + w4[2] + w4[3];
}
__global__ __launch_bounds__(256) void k_sc2(const unsigned* __restrict__ bsum,
                                             unsigned* __restrict__ boff,
                                             unsigned* __restrict__ row_ptr) {
  int tid = threadIdx.x, lane = tid & 63, w = tid >> 6;
  unsigned v = (tid < NSCB) ? bsum[tid] : 0u;
  unsigned x = v;
  #pragma unroll
  for (int off = 1; off < 64; off <<= 1) {
    unsigned y = __shfl_up(x, off);
    if (lane >= off) x += y;
  }
  __shared__ unsigned w4[4];
  if (lane == 63) w4[w] = x;
  __syncthreads();
  unsigned woff = 0;
  #pragma unroll
  for (int k = 0; k < 4; ++k) woff += (k < w) ? w4[k] : 0u;
  if (tid < NSCB) boff[tid] = woff + x - v;
  if (tid == 255) row_ptr[NN] = woff + x;
}
__global__ __launch_bounds__(256) void k_sc3(const unsigned* __restrict__ cnt,
                                             const unsigned* __restrict__ boff,
                                             unsigned* __restrict__ row_ptr) {
  int b = blockIdx.x, tid = threadIdx.x, lane = tid & 63, w = tid >> 6;
  int i = b * 256 + tid;
  unsigned v = (i < NN) ? cnt[i] : 0u;
  unsigned x = v;
  #pragma unroll
  for (int off = 1; off < 64; off <<= 1) {
    unsigned y = __shfl_up(x, off);
    if (lane >= off) x += y;
  }
  __shared__ unsigned w4[4];
  if (lane == 63) w4[w] = x;
  __syncthreads();
  unsigned woff = 0;
  #pragma unroll
  for (int k = 0; k < 4; ++k) woff += (k < w) ? w4[k] : 0u;
  if (i < NN) row_ptr[i] = boff[b] + woff + x - v;
}

// ---- CSR fill with packed, pre-normalized edge data ----
__global__ void k_fill(const void* ei, const int* __restrict__ flags,
                       const unsigned* __restrict__ row_ptr,
                       const float* __restrict__ dis, const float* __restrict__ dis2,
                       const void* aew, unsigned* __restrict__ fill,
                       int* __restrict__ csr_s, float4* __restrict__ csr_w) {
  int e = blockIdx.x * 256 + threadIdx.x;
  if (e >= NE) return;
  int f32 = flags[0], i64 = flags[1];
  int s = ld_src(ei, e, i64);
  int d = ld_dst(ei, e, i64);
  unsigned pos = row_ptr[d] + atomicAdd(&fill[d], 1u);
  float w0 = dis[s]          * ldf(aew, e, f32);
  float w1 = dis[NN + s]     * ldf(aew, (size_t)NE + e, f32);
  float w2 = dis[2 * NN + s] * ldf(aew, (size_t)2 * NE + e, f32);
  csr_s[pos] = s;
  csr_w[pos] = make_float4(w0, w1, w2, dis2[s]);
}

// ---- h1 = x @ W1: 16 rows/block, k-interleaved 4-way, W1 staged once ----
#define H1_ROWS 16
__global__ __launch_bounds__(256) void k_h1v(const void* x, const void* W1,
                                             const int* __restrict__ flags,
                                             float* __restrict__ h1) {
  __shared__ u16 W1L[256 * 68];   // [k][j], stride 68 shorts
  __shared__ float xL[4][256];    // one row per wave (wave-private)
  int tid = threadIdx.x, f32 = flags[0];
  for (int i = tid; i < 256 * 64; i += 256) {
    int k = i >> 6, j = i & 63;
    W1L[k * 68 + j] = f32 ? f2bf(((const float*)W1)[i]) : ((const u16*)W1)[i];
  }
  __syncthreads();
  int wid = tid >> 6, lane = tid & 63;
  int rg = lane >> 4, dq = lane & 15;
  int rowbase = blockIdx.x * H1_ROWS;
  #pragma unroll 1
  for (int rr = 0; rr < H1_ROWS / 4; ++rr) {
    int n = rowbase + rr * 4 + wid;
    // stage x row (wave-private; same-wave LDS ordering, no barrier)
    if (n < NN) {
      if (f32) {
        float4 xv = *(const float4*)((const float*)x + (size_t)n * 256 + lane * 4);
        *(float4*)&xL[wid][lane * 4] = xv;
      } else {
        ushort4 xv = *(const ushort4*)((const u16*)x + (size_t)n * 256 + lane * 4);
        *(float4*)&xL[wid][lane * 4] =
            make_float4(bf2f(xv.x), bf2f(xv.y), bf2f(xv.z), bf2f(xv.w));
      }
    } else {
      *(float4*)&xL[wid][lane * 4] = make_float4(0.f, 0.f, 0.f, 0.f);
    }
    float acc0 = 0.f, acc1 = 0.f, acc2 = 0.f, acc3 = 0.f;
    #pragma unroll 8
    for (int kk = 0; kk < 64; ++kk) {
      int k = kk * 4 + rg;
      float xk = xL[wid][k];
      ushort4 wv = *(const ushort4*)&W1L[k * 68 + dq * 4];
      acc0 += xk * bf2f(wv.x); acc1 += xk * bf2f(wv.y);
      acc2 += xk * bf2f(wv.z); acc3 += xk * bf2f(wv.w);
    }
    acc0 += __shfl_xor(acc0, 16); acc0 += __shfl_xor(acc0, 32);
    acc1 += __shfl_xor(acc1, 16); acc1 += __shfl_xor(acc1, 32);
    acc2 += __shfl_xor(acc2, 16); acc2 += __shfl_xor(acc2, 32);
    acc3 += __shfl_xor(acc3, 16); acc3 += __shfl_xor(acc3, 32);
    if (rg == 0 && n < NN)
      *(float4*)&h1[(size_t)n * 64 + dq * 4] = make_float4(acc0, acc1, acc2, acc3);
  }
}

// ---- gather layer1 only (3 graphs), max occupancy ----
__global__ __launch_bounds__(256) void k_gath1(
    const float* __restrict__ h1, const int* __restrict__ csr_s,
    const float4* __restrict__ csr_w, const unsigned* __restrict__ row_ptr,
    const float* __restrict__ deg_dis, const void* b1,
    const int* __restrict__ flags, float* __restrict__ dout) {
  __shared__ float4 eWL[4][64];  // 4 KB per-wave edge staging
  __shared__ float b1L[64];
  int tid = threadIdx.x, f32 = flags[0];
  if (tid < 64) b1L[tid] = ldf(b1, tid, f32);
  __syncthreads();
  int wid = tid >> 6, lane = tid & 63;
  int n = blockIdx.x * 4 + wid;
  if (n >= NN) return;

  float dd0 = deg_dis[n], dd1 = deg_dis[NN + n], dd2 = deg_dis[2 * NN + n];
  float a0[4] = {0,0,0,0}, a1[4] = {0,0,0,0}, a2[4] = {0,0,0,0};
  int g = lane >> 4, dq = lane & 15;
  unsigned beg = row_ptr[n], end = row_ptr[n + 1];
  for (unsigned base = beg; base < end; base += 64) {
    unsigned rem = end - base;
    int m = (rem > 64u) ? 64 : (int)rem;
    float4 st = make_float4(0.f, 0.f, 0.f, __int_as_float(0));
    if (lane < m) {
      float4 cw = csr_w[base + lane];
      int s = csr_s[base + lane];
      st = make_float4(cw.x * dd0, cw.y * dd1, cw.z * dd2, __int_as_float(s));
    }
    eWL[wid][lane] = st;   // wave-private row; same-wave LDS ops are in-order
    int jmax = (m + 3) >> 2;
    for (int j = 0; j < jmax; ++j) {
      float4 e = eWL[wid][j * 4 + g];
      int sj = __float_as_int(e.w);
      float4 hr = *(const float4*)&h1[(size_t)sj * 64 + dq * 4];
      a0[0] += e.x * hr.x; a0[1] += e.x * hr.y; a0[2] += e.x * hr.z; a0[3] += e.x * hr.w;
      a1[0] += e.y * hr.x; a1[1] += e.y * hr.y; a1[2] += e.y * hr.z; a1[3] += e.y * hr.w;
      a2[0] += e.z * hr.x; a2[1] += e.z * hr.y; a2[2] += e.z * hr.z; a2[3] += e.z * hr.w;
    }
  }
  #pragma unroll
  for (int c = 0; c < 4; ++c) {
    a0[c] += __shfl_xor(a0[c], 16); a0[c] += __shfl_xor(a0[c], 32);
    a1[c] += __shfl_xor(a1[c], 16); a1[c] += __shfl_xor(a1[c], 32);
    a2[c] += __shfl_xor(a2[c], 16); a2[c] += __shfl_xor(a2[c], 32);
  }
  // redistribute to lane=dim layout
  int srcl = lane >> 2, cc = lane & 3;
  float t0, t1, t2, t3, r0, r1, r2;
  t0 = __shfl(a0[0], srcl); t1 = __shfl(a0[1], srcl);
  t2 = __shfl(a0[2], srcl); t3 = __shfl(a0[3], srcl);
  r0 = cc == 0 ? t0 : cc == 1 ? t1 : cc == 2 ? t2 : t3;
  t0 = __shfl(a1[0], srcl); t1 = __shfl(a1[1], srcl);
  t2 = __shfl(a1[2], srcl); t3 = __shfl(a1[3], srcl);
  r1 = cc == 0 ? t0 : cc == 1 ? t1 : cc == 2 ? t2 : t3;
  t0 = __shfl(a2[0], srcl); t1 = __shfl(a2[1], srcl);
  t2 = __shfl(a2[2], srcl); t3 = __shfl(a2[3], srcl);
  r2 = cc == 0 ? t0 : cc == 1 ? t1 : cc == 2 ? t2 : t3;

  float selfv = h1[(size_t)n * 64 + lane];
  float b1v = b1L[lane];
  dout[OFF_HID + ((size_t)0 * NN + n) * 64 + lane] = fmaxf(r0 + dd0 * dd0 * selfv + b1v, 0.f);
  dout[OFF_HID + ((size_t)1 * NN + n) * 64 + lane] = fmaxf(r1 + dd1 * dd1 * selfv + b1v, 0.f);
  dout[OFF_HID + ((size_t)2 * NN + n) * 64 + lane] = fmaxf(r2 + dd2 * dd2 * selfv + b1v, 0.f);
}

// ---- dense attention: t=tanh(hid@Wf+bf), scores, softmax, fused ----
#define WFS 66  // Wf LDS row stride in shorts: 2-way bank aliasing only
__global__ __launch_bounds__(256) void k_attn(
    const void* Wf, const void* bfv, const void* qf,
    const int* __restrict__ flags, float* __restrict__ dout) {
  __shared__ u16 WfL[3 * 64 * WFS];
  __shared__ float qfL[192], bfL[192];
  int tid = threadIdx.x, f32 = flags[0];
  for (int i = tid; i < 3 * 64 * 64; i += 256) {
    int gi = i >> 12, rem = i & 4095, k = rem >> 6, j = rem & 63;
    WfL[gi * 64 * WFS + k * WFS + j] =
        f32 ? f2bf(((const float*)Wf)[i]) : ((const u16*)Wf)[i];
  }
  if (tid < 192) { qfL[tid] = ldf(qf, tid, f32); bfL[tid] = ldf(bfv, tid, f32); }
  __syncthreads();
  int wid = tid >> 6, lane = tid & 63;
  int n = blockIdx.x * 4 + wid;
  if (n >= NN) return;

  float hid0 = dout[OFF_HID + ((size_t)0 * NN + n) * 64 + lane];
  float hid1 = dout[OFF_HID + ((size_t)1 * NN + n) * 64 + lane];
  float hid2 = dout[OFF_HID + ((size_t)2 * NN + n) * 64 + lane];

  int g = lane >> 4, dq = lane & 15;
  float u0[4] = {0,0,0,0}, u1[4] = {0,0,0,0}, u2[4] = {0,0,0,0};
  #pragma unroll 4
  for (int kk = 0; kk < 16; ++kk) {
    int k = g * 16 + kk;
    float h0 = __shfl(hid0, k), h1b = __shfl(hid1, k), h2b = __shfl(hid2, k);
    ushort4 w0v = *(const ushort4*)&WfL[k * WFS + dq * 4];
    ushort4 w1v = *(const ushort4*)&WfL[64 * WFS + k * WFS + dq * 4];
    ushort4 w2v = *(const ushort4*)&WfL[128 * WFS + k * WFS + dq * 4];
    u0[0] += h0 * bf2f(w0v.x); u0[1] += h0 * bf2f(w0v.y);
    u0[2] += h0 * bf2f(w0v.z); u0[3] += h0 * bf2f(w0v.w);
    u1[0] += h1b * bf2f(w1v.x); u1[1] += h1b * bf2f(w1v.y);
    u1[2] += h1b * bf2f(w1v.z); u1[3] += h1b * bf2f(w1v.w);
    u2[0] += h2b * bf2f(w2v.x); u2[1] += h2b * bf2f(w2v.y);
    u2[2] += h2b * bf2f(w2v.z); u2[3] += h2b * bf2f(w2v.w);
  }
  #pragma unroll
  for (int c = 0; c < 4; ++c) {
    u0[c] += __shfl_xor(u0[c], 16); u0[c] += __shfl_xor(u0[c], 32);
    u1[c] += __shfl_xor(u1[c], 16); u1[c] += __shfl_xor(u1[c], 32);
    u2[c] += __shfl_xor(u2[c], 16); u2[c] += __shfl_xor(u2[c], 32);
  }
  // redistribute to lane=dim, then only 3 tanh per lane
  int srcl = lane >> 2, cc = lane & 3;
  float t0, t1, t2, t3, v0, v1, v2;
  t0 = __shfl(u0[0], srcl); t1 = __shfl(u0[1], srcl);
  t2 = __shfl(u0[2], srcl); t3 = __shfl(u0[3], srcl);
  v0 = cc == 0 ? t0 : cc == 1 ? t1 : cc == 2 ? t2 : t3;
  t0 = __shfl(u1[0], srcl); t1 = __shfl(u1[1], srcl);
  t2 = __shfl(u1[2], srcl); t3 = __shfl(u1[3], srcl);
  v1 = cc == 0 ? t0 : cc == 1 ? t1 : cc == 2 ? t2 : t3;
  t0 = __shfl(u2[0], srcl); t1 = __shfl(u2[1], srcl);
  t2 = __shfl(u2[2], srcl); t3 = __shfl(u2[3], srcl);
  v2 = cc == 0 ? t0 : cc == 1 ? t1 : cc == 2 ? t2 : t3;

  float p0 = tanhf(v0 + bfL[lane])       * qfL[lane];
  float p1 = tanhf(v1 + bfL[64 + lane])  * qfL[64 + lane];
  float p2 = tanhf(v2 + bfL[128 + lane]) * qfL[128 + lane];
  #pragma unroll
  for (int off = 32; off > 0; off >>= 1) {
    p0 += __shfl_xor(p0, off);
    p1 += __shfl_xor(p1, off);
    p2 += __shfl_xor(p2, off);
  }
  float mx = fmaxf(p0, fmaxf(p1, p2));
  float e0 = expf(p0 - mx), e1 = expf(p1 - mx), e2 = expf(p2 - mx);
  float inv = 1.0f / (e0 + e1 + e2);
  float aw0 = e0 * inv, aw1 = e1 * inv, aw2 = e2 * inv;
  float fv = aw0 * hid0 + aw1 * hid1 + aw2 * hid2;
  dout[OFF_FUSED + (size_t)n * 64 + lane] = fv;
  if (lane < 3) dout[OFF_ATTN + (size_t)n * 3 + lane] =
                    (lane == 0 ? aw0 : (lane == 1 ? aw1 : aw2));
}

// ---- layer2 gather (packed LDS staging): agg = sym-aggregate(fused) ----
__global__ __launch_bounds__(256) void k_agg2(
    const int* __restrict__ csr_s, const float4* __restrict__ csr_w,
    const unsigned* __restrict__ row_ptr, const float* __restrict__ dis2,
    const float* __restrict__ dout, float* __restrict__ agg) {
  __shared__ uint2 eL[4][64];
  const float* fused = dout + OFF_FUSED;
  int tid = threadIdx.x, wid = tid >> 6, lane = tid & 63;
  int n = blockIdx.x * 4 + wid;
  if (n >= NN) return;
  float dd = dis2[n];
  float acc[4] = {0.f, 0.f, 0.f, 0.f};
  int g = lane >> 4, dq = lane & 15;
  unsigned beg = row_ptr[n], end = row_ptr[n + 1];
  for (unsigned base = beg; base < end; base += 64) {
    unsigned rem = end - base;
    int m = (rem > 64u) ? 64 : (int)rem;
    uint2 st = make_uint2(0u, 0u);
    if (lane < m)
      st = make_uint2((unsigned)csr_s[base + lane],
                      __float_as_uint(csr_w[base + lane].w * dd));
    eL[wid][lane] = st;
    int jmax = (m + 3) >> 2;
    for (int j = 0; j < jmax; ++j) {
      uint2 e = eL[wid][j * 4 + g];
      int sj = (int)e.x;
      float wj = __uint_as_float(e.y);
      float4 fr = *(const float4*)&fused[(size_t)sj * 64 + dq * 4];
      acc[0] += wj * fr.x; acc[1] += wj * fr.y;
      acc[2] += wj * fr.z; acc[3] += wj * fr.w;
    }
  }
  #pragma unroll
  for (int c = 0; c < 4; ++c) {
    acc[c] += __shfl_xor(acc[c], 16);
    acc[c] += __shfl_xor(acc[c], 32);
  }
  if (lane < 16) {
    float4 sf = *(const float4*)&fused[(size_t)n * 64 + lane * 4];
    float sw = dd * dd;
    *(float4*)&agg[(size_t)n * 64 + lane * 4] =
        make_float4(acc[0] + sw * sf.x, acc[1] + sw * sf.y,
                    acc[2] + sw * sf.z, acc[3] + sw * sf.w);
  }
}

// ---- emb = relu(agg @ W2 + b2) (LDS broadcast matvec, float4 out) ----
__global__ __launch_bounds__(256) void k_emb2(const float* __restrict__ agg,
                                              const void* W2, const void* b2,
                                              const int* __restrict__ flags,
                                              float* __restrict__ dout) {
  __shared__ u16 W2L[64 * 256];
  __shared__ float agL[4][64];
  __shared__ float b2L[256];
  int tid = threadIdx.x, f32 = flags[0];
  for (int i = tid; i < 64 * 256; i += 256)
    W2L[i] = f32 ? f2bf(((const float*)W2)[i]) : ((const u16*)W2)[i];
  b2L[tid] = ldf(b2, tid, f32);
  {
    int r = tid >> 6, c = tid & 63;
    int row = blockIdx.x * 4 + r;
    agL[r][c] = (row < NN) ? agg[(size_t)row * 64 + c] : 0.f;
  }
  __syncthreads();
  int wid = tid >> 6, lane = tid & 63;
  int n = blockIdx.x * 4 + wid;
  if (n >= NN) return;
  float acc0 = b2L[lane * 4], acc1 = b2L[lane * 4 + 1];
  float acc2 = b2L[lane * 4 + 2], acc3 = b2L[lane * 4 + 3];
  #pragma unroll 8
  for (int k = 0; k < 64; ++k) {
    float a = agL[wid][k];
    ushort4 wv = *(const ushort4*)&W2L[k * 256 + lane * 4];
    acc0 += a * bf2f(wv.x); acc1 += a * bf2f(wv.y);
    acc2 += a * bf2f(wv.z); acc3 += a * bf2f(wv.w);
  }
  *(float4*)&dout[OFF_EMB + (size_t)n * 256 + lane * 4] =
      make_float4(fmaxf(acc0, 0.f), fmaxf(acc1, 0.f),
                  fmaxf(acc2, 0.f), fmaxf(acc3, 0.f));
}

// ---- vsum = graph_neigh @ fused (LDS gn tiles) + fused row sums ----
__global__ __launch_bounds__(256) void k_vsum(const void* gn,
                                              const float* __restrict__ dout,
                                              const int* __restrict__ flags,
                                              float* __restrict__ part,
                                              float* __restrict__ rspart) {
  __shared__ float gnL[8][1024];
  const float* fused = dout + OFF_FUSED;
  int tid = threadIdx.x, wid = tid >> 6, lane = tid & 63;
  int f32 = flags[0];
  int ks = blockIdx.x, bg = blockIdx.y;
  int nbase = ks * 1024;
  #pragma unroll
  for (int r = 0; r < 8; ++r) {
    #pragma unroll
    for (int i = 0; i < 4; ++i) {
      int colv = i * 256 + tid;
      int nn = nbase + colv;
      gnL[r][colv] = (nn < NN) ? ldf(gn, (size_t)(bg * 8 + r) * NN + nn, f32) : 0.f;
    }
  }
  __syncthreads();
  #pragma unroll
  for (int rr = 0; rr < 2; ++rr) {
    int r = wid * 2 + rr;
    float s = 0.f;
    #pragma unroll
    for (int i = 0; i < 16; ++i) s += gnL[r][i * 64 + lane];
    #pragma unroll
    for (int off = 32; off > 0; off >>= 1) s += __shfl_down(s, off);
    if (lane == 0) rspart[(size_t)ks * 256 + bg * 8 + r] = s;
  }
  int g = lane >> 4, dq = lane & 15;
  float acc[8][4];
  #pragma unroll
  for (int r = 0; r < 8; ++r)
    #pragma unroll
    for (int c = 0; c < 4; ++c) acc[r][c] = 0.f;
  for (int i = 0; i < 64; ++i) {
    int nloc = wid * 256 + i * 4 + g;
    int nn = nbase + nloc;
    float4 fr = (nn < NN) ? *(const float4*)&fused[(size_t)nn * 64 + dq * 4]
                          : make_float4(0.f, 0.f, 0.f, 0.f);
    #pragma unroll
    for (int r = 0; r < 8; ++r) {
      float gv = gnL[r][nloc];
      acc[r][0] += gv * fr.x; acc[r][1] += gv * fr.y;
      acc[r][2] += gv * fr.z; acc[r][3] += gv * fr.w;
    }
  }
  #pragma unroll
  for (int r = 0; r < 8; ++r)
    #pragma unroll
    for (int c = 0; c < 4; ++c) {
      acc[r][c] += __shfl_xor(acc[r][c], 16);
      acc[r][c] += __shfl_xor(acc[r][c], 32);
    }
  if (lane < 16) {
    int slice = ks * 4 + wid;
    #pragma unroll
    for (int r = 0; r < 8; ++r)
      *(float4*)&part[((size_t)slice * 256 + bg * 8 + r) * 64 + lane * 4] =
          make_float4(acc[r][0], acc[r][1], acc[r][2], acc[r][3]);
  }
}

// ---- g finalize: reduce partials, divide by row_sum, L2 normalize ----
__global__ __launch_bounds__(64) void k_gfinal(const float* __restrict__ part,
                                               const float* __restrict__ rspart,
                                               float* __restrict__ dout) {
  int b = blockIdx.x, j = threadIdx.x;
  float acc = 0.f;
  for (int k = 0; k < VS_SL; ++k) acc += part[((size_t)k * 256 + b) * 64 + j];
  float rs = 0.f;
  for (int k = 0; k < VS_NC; ++k) rs += rspart[(size_t)k * 256 + b];
  float v = acc / rs;
  float sq = v * v;
  #pragma unroll
  for (int off = 32; off > 0; off >>= 1) sq += __shfl_xor(sq, off);
  float nrm = sqrtf(sq);
  dout[OFF_G + (size_t)b * 64 + j] = v / fmaxf(nrm, 1e-12f);
}

extern "C" void kernel_launch(void* const* d_in, const int* in_sizes, int n_in,
                              void* d_out, int out_size, void* d_ws, size_t ws_size,
                              hipStream_t stream) {
  const void* x   = d_in[0];
  const void* ei  = d_in[1];
  const void* gn  = d_in[2];
  const void* aew = d_in[3];
  const void* W1  = d_in[4];
  const void* b1  = d_in[5];
  const void* W2  = d_in[6];
  const void* b2  = d_in[7];
  const void* Wf  = d_in[8];
  const void* bfv = d_in[9];
  const void* qf  = d_in[10];

  char* ws = (char*)d_ws;
  size_t off = 0;
  auto alloc = [&](size_t bytes) -> void* {
    void* p = ws + off;
    off += (bytes + 255) & ~(size_t)255;
    return p;
  };
  // zero-init region (atomically accumulated buffers only)
  float*    deg     = (float*)alloc((size_t)3 * NN * 4);
  unsigned* cnt     = (unsigned*)alloc((size_t)NN * 4);
  unsigned* fill    = (unsigned*)alloc((size_t)NN * 4);
  size_t zero_bytes = off;
  int*      flags   = (int*)alloc(64);
  float*    dis2    = (float*)alloc((size_t)NN * 4);
  unsigned* row_ptr = (unsigned*)alloc((size_t)(NN + 1) * 4);
  unsigned* bsum    = (unsigned*)alloc((size_t)NSCB * 4);
  unsigned* boff    = (unsigned*)alloc((size_t)NSCB * 4);
  int*      csr_s   = (int*)alloc((size_t)NE * 4);
  float4*   csr_w   = (float4*)alloc((size_t)NE * 16);
  // time-shared region: h1 (k_h1v->k_gath1), agg (k_agg2->k_emb2), part (k_vsum->k_gfinal)
  size_t regA_bytes = (size_t)VS_SL * NB * 64 * 4;
  char*  regA       = (char*)alloc(regA_bytes);
  float* h1   = (float*)regA;
  float* agg  = (float*)regA;
  float* part = (float*)regA;
  float* rspart = (float*)alloc((size_t)VS_NC * NB * 4);

  float* dout = (float*)d_out;

  hipMemsetAsync(d_ws, 0, zero_bytes, stream);
  k_detect<<<1, 64, 0, stream>>>(x, ei, flags);
  k_deg<<<(NE + 255) / 256, 256, 0, stream>>>(ei, aew, flags, deg, cnt);
  k_dis<<<(3 * NN + 255) / 256, 256, 0, stream>>>(deg, cnt, dis2);
  k_sc1<<<NSCB, 256, 0, stream>>>(cnt, bsum);
  k_sc2<<<1, 256, 0, stream>>>(bsum, boff, row_ptr);
  k_sc3<<<NSCB, 256, 0, stream>>>(cnt, boff, row_ptr);
  k_fill<<<(NE + 255) / 256, 256, 0, stream>>>(ei, flags, row_ptr, deg, dis2, aew,
                                               fill, csr_s, csr_w);
  k_h1v<<<(NN + H1_ROWS - 1) / H1_ROWS, 256, 0, stream>>>(x, W1, flags, h1);
  k_gath1<<<(NN + 3) / 4, 256, 0, stream>>>(h1, csr_s, csr_w, row_ptr, deg, b1,
                                            flags, dout);
  k_attn<<<(NN + 3) / 4, 256, 0, stream>>>(Wf, bfv, qf, flags, dout);
  k_agg2<<<(NN + 3) / 4, 256, 0, stream>>>(csr_s, csr_w, row_ptr, dis2, dout, agg);
  k_emb2<<<(NN + 3) / 4, 256, 0, stream>>>(agg, W2, b2, flags, dout);
  {
    dim3 gdim(VS_NC, 32);
    k_vsum<<<gdim, 256, 0, stream>>>(gn, dout, flags, part, rspart);
  }
  k_gfinal<<<NB, 64, 0, stream>>>(part, rspart, dout);
}

// Round 11
// 655.590 us; speedup vs baseline: 4.3715x; 1.1783x over previous
//
#include <hip/hip_runtime.h>
#include <hip/hip_bf16.h>

#define NN 50000
#define NE 800000
#define NG 3
#define NB 256
#define NSCB 196  // ceil(NN/256)

#define OFF_FUSED ((size_t)0)
#define OFF_EMB   ((size_t)NN * 64)
#define OFF_G     (OFF_EMB + (size_t)NN * 256)
#define OFF_HID   (OFF_G + (size_t)NB * 64)
#define OFF_ATTN  (OFF_HID + (size_t)3 * NN * 64)

// k_vsum geometry: 49 n-chunks of 1024; 32 b-groups of 8 rows; slice = ks*4+wave
#define VS_NC 49
#define VS_SL (VS_NC * 4)

typedef unsigned short u16;

__device__ __forceinline__ float bf2f(u16 u) {
  union { unsigned int i; float f; } v; v.i = ((unsigned int)u) << 16; return v.f;
}
__device__ __forceinline__ u16 f2bf(float f) {
  unsigned int x = __float_as_uint(f);
  unsigned int r = (x + 0x7FFFu + ((x >> 16) & 1u)) >> 16;
  return (u16)r;
}
__device__ __forceinline__ float ldf(const void* p, size_t i, int f32) {
  return f32 ? ((const float*)p)[i] : bf2f(((const u16*)p)[i]);
}
__device__ __forceinline__ int ld_src(const void* ei, int e, int i64) {
  return i64 ? (int)((const long long*)ei)[e] : ((const int*)ei)[e];
}
__device__ __forceinline__ int ld_dst(const void* ei, int e, int i64) {
  return i64 ? (int)((const long long*)ei)[(size_t)NE + e] : ((const int*)ei)[(size_t)NE + e];
}

// ---- dtype detection ----
__global__ void k_detect(const void* x, const void* ei, int* flags) {
  if (threadIdx.x != 0 || blockIdx.x != 0) return;
  const u16* xw = (const u16*)x;
  int sane = 0;
  for (int i = 0; i < 64; ++i) {
    unsigned ex = (xw[2 * i] >> 7) & 0xFF;
    sane += (ex >= 96 && ex <= 141);
  }
  flags[0] = (sane < 48) ? 1 : 0;  // 1 => inputs are float32
  const int* e32 = (const int*)ei;
  int zeros = 0;
  for (int t = 1; t < 32; t += 2) zeros += (e32[t] == 0);
  flags[1] = (zeros >= 12) ? 1 : 0;  // 1 => edge_index is int64
}

// ---- degree accumulation ----
__global__ void k_deg(const void* ei, const void* aew, const int* __restrict__ flags,
                      float* __restrict__ deg, unsigned* __restrict__ cnt) {
  int e = blockIdx.x * 256 + threadIdx.x;
  if (e >= NE) return;
  int f32 = flags[0], i64 = flags[1];
  int d = ld_dst(ei, e, i64);
  atomicAdd(&cnt[d], 1u);
  atomicAdd(&deg[d],          ldf(aew, e, f32));
  atomicAdd(&deg[NN + d],     ldf(aew, (size_t)NE + e, f32));
  atomicAdd(&deg[2 * NN + d], ldf(aew, (size_t)2 * NE + e, f32));
}

__global__ void k_dis(float* __restrict__ deg, const unsigned* __restrict__ cnt,
                      float* __restrict__ dis2) {
  int i = blockIdx.x * 256 + threadIdx.x;
  if (i < 3 * NN) deg[i] = rsqrtf(deg[i] + 1.0f);
  if (i < NN) dis2[i] = rsqrtf((float)cnt[i] + 1.0f);
}

// ---- 3-phase exclusive scan of cnt -> row_ptr ----
__global__ __launch_bounds__(256) void k_sc1(const unsigned* __restrict__ cnt,
                                             unsigned* __restrict__ bsum) {
  int b = blockIdx.x, tid = threadIdx.x, i = b * 256 + tid;
  unsigned v = (i < NN) ? cnt[i] : 0u;
  #pragma unroll
  for (int off = 32; off > 0; off >>= 1) v += __shfl_down(v, off);
  __shared__ unsigned w4[4];
  if ((tid & 63) == 0) w4[tid >> 6] = v;
  __syncthreads();
  if (tid == 0) bsum[b] = w4[0] + w4[1] + w4[2] + w4[3];
}
__global__ __launch_bounds__(256) void k_sc2(const unsigned* __restrict__ bsum,
                                             unsigned* __restrict__ boff,
                                             unsigned* __restrict__ row_ptr) {
  int tid = threadIdx.x, lane = tid & 63, w = tid >> 6;
  unsigned v = (tid < NSCB) ? bsum[tid] : 0u;
  unsigned x = v;
  #pragma unroll
  for (int off = 1; off < 64; off <<= 1) {
    unsigned y = __shfl_up(x, off);
    if (lane >= off) x += y;
  }
  __shared__ unsigned w4[4];
  if (lane == 63) w4[w] = x;
  __syncthreads();
  unsigned woff = 0;
  #pragma unroll
  for (int k = 0; k < 4; ++k) woff += (k < w) ? w4[k] : 0u;
  if (tid < NSCB) boff[tid] = woff + x - v;
  if (tid == 255) row_ptr[NN] = woff + x;
}
__global__ __launch_bounds__(256) void k_sc3(const unsigned* __restrict__ cnt,
                                             const unsigned* __restrict__ boff,
                                             unsigned* __restrict__ row_ptr) {
  int b = blockIdx.x, tid = threadIdx.x, lane = tid & 63, w = tid >> 6;
  int i = b * 256 + tid;
  unsigned v = (i < NN) ? cnt[i] : 0u;
  unsigned x = v;
  #pragma unroll
  for (int off = 1; off < 64; off <<= 1) {
    unsigned y = __shfl_up(x, off);
    if (lane >= off) x += y;
  }
  __shared__ unsigned w4[4];
  if (lane == 63) w4[w] = x;
  __syncthreads();
  unsigned woff = 0;
  #pragma unroll
  for (int k = 0; k < 4; ++k) woff += (k < w) ? w4[k] : 0u;
  if (i < NN) row_ptr[i] = boff[b] + woff + x - v;
}

// ---- CSR fill with packed, pre-normalized edge data ----
__global__ void k_fill(const void* ei, const int* __restrict__ flags,
                       const unsigned* __restrict__ row_ptr,
                       const float* __restrict__ dis, const float* __restrict__ dis2,
                       const void* aew, unsigned* __restrict__ fill,
                       int* __restrict__ csr_s, float4* __restrict__ csr_w) {
  int e = blockIdx.x * 256 + threadIdx.x;
  if (e >= NE) return;
  int f32 = flags[0], i64 = flags[1];
  int s = ld_src(ei, e, i64);
  int d = ld_dst(ei, e, i64);
  unsigned pos = row_ptr[d] + atomicAdd(&fill[d], 1u);
  float w0 = dis[s]          * ldf(aew, e, f32);
  float w1 = dis[NN + s]     * ldf(aew, (size_t)NE + e, f32);
  float w2 = dis[2 * NN + s] * ldf(aew, (size_t)2 * NE + e, f32);
  csr_s[pos] = s;
  csr_w[pos] = make_float4(w0, w1, w2, dis2[s]);
}

// ---- h1 = x @ W1: 16 rows/block, k-interleaved 4-way, W1 staged once ----
#define H1_ROWS 16
__global__ __launch_bounds__(256) void k_h1v(const void* x, const void* W1,
                                             const int* __restrict__ flags,
                                             float* __restrict__ h1) {
  __shared__ u16 W1L[256 * 68];   // [k][j], stride 68 shorts
  __shared__ float xL[4][256];    // one row per wave (wave-private)
  int tid = threadIdx.x, f32 = flags[0];
  for (int i = tid; i < 256 * 64; i += 256) {
    int k = i >> 6, j = i & 63;
    W1L[k * 68 + j] = f32 ? f2bf(((const float*)W1)[i]) : ((const u16*)W1)[i];
  }
  __syncthreads();
  int wid = tid >> 6, lane = tid & 63;
  int rg = lane >> 4, dq = lane & 15;
  int rowbase = blockIdx.x * H1_ROWS;
  #pragma unroll 1
  for (int rr = 0; rr < H1_ROWS / 4; ++rr) {
    int n = rowbase + rr * 4 + wid;
    if (n < NN) {
      if (f32) {
        float4 xv = *(const float4*)((const float*)x + (size_t)n * 256 + lane * 4);
        *(float4*)&xL[wid][lane * 4] = xv;
      } else {
        ushort4 xv = *(const ushort4*)((const u16*)x + (size_t)n * 256 + lane * 4);
        *(float4*)&xL[wid][lane * 4] =
            make_float4(bf2f(xv.x), bf2f(xv.y), bf2f(xv.z), bf2f(xv.w));
      }
    } else {
      *(float4*)&xL[wid][lane * 4] = make_float4(0.f, 0.f, 0.f, 0.f);
    }
    float acc0 = 0.f, acc1 = 0.f, acc2 = 0.f, acc3 = 0.f;
    #pragma unroll 8
    for (int kk = 0; kk < 64; ++kk) {
      int k = kk * 4 + rg;
      float xk = xL[wid][k];
      ushort4 wv = *(const ushort4*)&W1L[k * 68 + dq * 4];
      acc0 += xk * bf2f(wv.x); acc1 += xk * bf2f(wv.y);
      acc2 += xk * bf2f(wv.z); acc3 += xk * bf2f(wv.w);
    }
    acc0 += __shfl_xor(acc0, 16); acc0 += __shfl_xor(acc0, 32);
    acc1 += __shfl_xor(acc1, 16); acc1 += __shfl_xor(acc1, 32);
    acc2 += __shfl_xor(acc2, 16); acc2 += __shfl_xor(acc2, 32);
    acc3 += __shfl_xor(acc3, 16); acc3 += __shfl_xor(acc3, 32);
    if (rg == 0 && n < NN)
      *(float4*)&h1[(size_t)n * 64 + dq * 4] = make_float4(acc0, acc1, acc2, acc3);
  }
}

// ---- gather layer1 only (3 graphs), max occupancy ----
__global__ __launch_bounds__(256) void k_gath1(
    const float* __restrict__ h1, const int* __restrict__ csr_s,
    const float4* __restrict__ csr_w, const unsigned* __restrict__ row_ptr,
    const float* __restrict__ deg_dis, const void* b1,
    const int* __restrict__ flags, float* __restrict__ dout) {
  __shared__ float4 eWL[4][64];  // 4 KB per-wave edge staging
  __shared__ float b1L[64];
  int tid = threadIdx.x, f32 = flags[0];
  if (tid < 64) b1L[tid] = ldf(b1, tid, f32);
  __syncthreads();
  int wid = tid >> 6, lane = tid & 63;
  int n = blockIdx.x * 4 + wid;
  if (n >= NN) return;

  float dd0 = deg_dis[n], dd1 = deg_dis[NN + n], dd2 = deg_dis[2 * NN + n];
  float a0[4] = {0,0,0,0}, a1[4] = {0,0,0,0}, a2[4] = {0,0,0,0};
  int g = lane >> 4, dq = lane & 15;
  unsigned beg = row_ptr[n], end = row_ptr[n + 1];
  for (unsigned base = beg; base < end; base += 64) {
    unsigned rem = end - base;
    int m = (rem > 64u) ? 64 : (int)rem;
    float4 st = make_float4(0.f, 0.f, 0.f, __int_as_float(0));
    if (lane < m) {
      float4 cw = csr_w[base + lane];
      int s = csr_s[base + lane];
      st = make_float4(cw.x * dd0, cw.y * dd1, cw.z * dd2, __int_as_float(s));
    }
    eWL[wid][lane] = st;   // wave-private row; same-wave LDS ops are in-order
    int jmax = (m + 3) >> 2;
    for (int j = 0; j < jmax; ++j) {
      float4 e = eWL[wid][j * 4 + g];
      int sj = __float_as_int(e.w);
      float4 hr = *(const float4*)&h1[(size_t)sj * 64 + dq * 4];
      a0[0] += e.x * hr.x; a0[1] += e.x * hr.y; a0[2] += e.x * hr.z; a0[3] += e.x * hr.w;
      a1[0] += e.y * hr.x; a1[1] += e.y * hr.y; a1[2] += e.y * hr.z; a1[3] += e.y * hr.w;
      a2[0] += e.z * hr.x; a2[1] += e.z * hr.y; a2[2] += e.z * hr.z; a2[3] += e.z * hr.w;
    }
  }
  #pragma unroll
  for (int c = 0; c < 4; ++c) {
    a0[c] += __shfl_xor(a0[c], 16); a0[c] += __shfl_xor(a0[c], 32);
    a1[c] += __shfl_xor(a1[c], 16); a1[c] += __shfl_xor(a1[c], 32);
    a2[c] += __shfl_xor(a2[c], 16); a2[c] += __shfl_xor(a2[c], 32);
  }
  // redistribute to lane=dim layout
  int srcl = lane >> 2, cc = lane & 3;
  float t0, t1, t2, t3, r0, r1, r2;
  t0 = __shfl(a0[0], srcl); t1 = __shfl(a0[1], srcl);
  t2 = __shfl(a0[2], srcl); t3 = __shfl(a0[3], srcl);
  r0 = cc == 0 ? t0 : cc == 1 ? t1 : cc == 2 ? t2 : t3;
  t0 = __shfl(a1[0], srcl); t1 = __shfl(a1[1], srcl);
  t2 = __shfl(a1[2], srcl); t3 = __shfl(a1[3], srcl);
  r1 = cc == 0 ? t0 : cc == 1 ? t1 : cc == 2 ? t2 : t3;
  t0 = __shfl(a2[0], srcl); t1 = __shfl(a2[1], srcl);
  t2 = __shfl(a2[2], srcl); t3 = __shfl(a2[3], srcl);
  r2 = cc == 0 ? t0 : cc == 1 ? t1 : cc == 2 ? t2 : t3;

  float selfv = h1[(size_t)n * 64 + lane];
  float b1v = b1L[lane];
  dout[OFF_HID + ((size_t)0 * NN + n) * 64 + lane] = fmaxf(r0 + dd0 * dd0 * selfv + b1v, 0.f);
  dout[OFF_HID + ((size_t)1 * NN + n) * 64 + lane] = fmaxf(r1 + dd1 * dd1 * selfv + b1v, 0.f);
  dout[OFF_HID + ((size_t)2 * NN + n) * 64 + lane] = fmaxf(r2 + dd2 * dd2 * selfv + b1v, 0.f);
}

// ---- dense attention: t=tanh(hid@Wf+bf), scores, softmax, fused ----
#define WFS 66  // Wf LDS row stride in shorts: 2-way bank aliasing only
__global__ __launch_bounds__(256) void k_attn(
    const void* Wf, const void* bfv, const void* qf,
    const int* __restrict__ flags, float* __restrict__ dout) {
  __shared__ u16 WfL[3 * 64 * WFS];
  __shared__ float qfL[192], bfL[192];
  int tid = threadIdx.x, f32 = flags[0];
  for (int i = tid; i < 3 * 64 * 64; i += 256) {
    int gi = i >> 12, rem = i & 4095, k = rem >> 6, j = rem & 63;
    WfL[gi * 64 * WFS + k * WFS + j] =
        f32 ? f2bf(((const float*)Wf)[i]) : ((const u16*)Wf)[i];
  }
  if (tid < 192) { qfL[tid] = ldf(qf, tid, f32); bfL[tid] = ldf(bfv, tid, f32); }
  __syncthreads();
  int wid = tid >> 6, lane = tid & 63;
  int n = blockIdx.x * 4 + wid;
  if (n >= NN) return;

  float hid0 = dout[OFF_HID + ((size_t)0 * NN + n) * 64 + lane];
  float hid1 = dout[OFF_HID + ((size_t)1 * NN + n) * 64 + lane];
  float hid2 = dout[OFF_HID + ((size_t)2 * NN + n) * 64 + lane];

  int g = lane >> 4, dq = lane & 15;
  float u0[4] = {0,0,0,0}, u1[4] = {0,0,0,0}, u2[4] = {0,0,0,0};
  #pragma unroll 4
  for (int kk = 0; kk < 16; ++kk) {
    int k = g * 16 + kk;
    float h0 = __shfl(hid0, k), h1b = __shfl(hid1, k), h2b = __shfl(hid2, k);
    ushort4 w0v = *(const ushort4*)&WfL[k * WFS + dq * 4];
    ushort4 w1v = *(const ushort4*)&WfL[64 * WFS + k * WFS + dq * 4];
    ushort4 w2v = *(const ushort4*)&WfL[128 * WFS + k * WFS + dq * 4];
    u0[0] += h0 * bf2f(w0v.x); u0[1] += h0 * bf2f(w0v.y);
    u0[2] += h0 * bf2f(w0v.z); u0[3] += h0 * bf2f(w0v.w);
    u1[0] += h1b * bf2f(w1v.x); u1[1] += h1b * bf2f(w1v.y);
    u1[2] += h1b * bf2f(w1v.z); u1[3] += h1b * bf2f(w1v.w);
    u2[0] += h2b * bf2f(w2v.x); u2[1] += h2b * bf2f(w2v.y);
    u2[2] += h2b * bf2f(w2v.z); u2[3] += h2b * bf2f(w2v.w);
  }
  #pragma unroll
  for (int c = 0; c < 4; ++c) {
    u0[c] += __shfl_xor(u0[c], 16); u0[c] += __shfl_xor(u0[c], 32);
    u1[c] += __shfl_xor(u1[c], 16); u1[c] += __shfl_xor(u1[c], 32);
    u2[c] += __shfl_xor(u2[c], 16); u2[c] += __shfl_xor(u2[c], 32);
  }
  // redistribute to lane=dim, then only 3 tanh per lane
  int srcl = lane >> 2, cc = lane & 3;
  float t0, t1, t2, t3, v0, v1, v2;
  t0 = __shfl(u0[0], srcl); t1 = __shfl(u0[1], srcl);
  t2 = __shfl(u0[2], srcl); t3 = __shfl(u0[3], srcl);
  v0 = cc == 0 ? t0 : cc == 1 ? t1 : cc == 2 ? t2 : t3;
  t0 = __shfl(u1[0], srcl); t1 = __shfl(u1[1], srcl);
  t2 = __shfl(u1[2], srcl); t3 = __shfl(u1[3], srcl);
  v1 = cc == 0 ? t0 : cc == 1 ? t1 : cc == 2 ? t2 : t3;
  t0 = __shfl(u2[0], srcl); t1 = __shfl(u2[1], srcl);
  t2 = __shfl(u2[2], srcl); t3 = __shfl(u2[3], srcl);
  v2 = cc == 0 ? t0 : cc == 1 ? t1 : cc == 2 ? t2 : t3;

  float p0 = tanhf(v0 + bfL[lane])       * qfL[lane];
  float p1 = tanhf(v1 + bfL[64 + lane])  * qfL[64 + lane];
  float p2 = tanhf(v2 + bfL[128 + lane]) * qfL[128 + lane];
  #pragma unroll
  for (int off = 32; off > 0; off >>= 1) {
    p0 += __shfl_xor(p0, off);
    p1 += __shfl_xor(p1, off);
    p2 += __shfl_xor(p2, off);
  }
  float mx = fmaxf(p0, fmaxf(p1, p2));
  float e0 = expf(p0 - mx), e1 = expf(p1 - mx), e2 = expf(p2 - mx);
  float inv = 1.0f / (e0 + e1 + e2);
  float aw0 = e0 * inv, aw1 = e1 * inv, aw2 = e2 * inv;
  float fv = aw0 * hid0 + aw1 * hid1 + aw2 * hid2;
  dout[OFF_FUSED + (size_t)n * 64 + lane] = fv;
  if (lane < 3) dout[OFF_ATTN + (size_t)n * 3 + lane] =
                    (lane == 0 ? aw0 : (lane == 1 ? aw1 : aw2));
}

// ---- layer2 gather (packed LDS staging): agg = sym-aggregate(fused) ----
__global__ __launch_bounds__(256) void k_agg2(
    const int* __restrict__ csr_s, const float4* __restrict__ csr_w,
    const unsigned* __restrict__ row_ptr, const float* __restrict__ dis2,
    const float* __restrict__ dout, float* __restrict__ agg) {
  __shared__ uint2 eL[4][64];
  const float* fused = dout + OFF_FUSED;
  int tid = threadIdx.x, wid = tid >> 6, lane = tid & 63;
  int n = blockIdx.x * 4 + wid;
  if (n >= NN) return;
  float dd = dis2[n];
  float acc[4] = {0.f, 0.f, 0.f, 0.f};
  int g = lane >> 4, dq = lane & 15;
  unsigned beg = row_ptr[n], end = row_ptr[n + 1];
  for (unsigned base = beg; base < end; base += 64) {
    unsigned rem = end - base;
    int m = (rem > 64u) ? 64 : (int)rem;
    uint2 st = make_uint2(0u, 0u);
    if (lane < m)
      st = make_uint2((unsigned)csr_s[base + lane],
                      __float_as_uint(csr_w[base + lane].w * dd));
    eL[wid][lane] = st;
    int jmax = (m + 3) >> 2;
    for (int j = 0; j < jmax; ++j) {
      uint2 e = eL[wid][j * 4 + g];
      int sj = (int)e.x;
      float wj = __uint_as_float(e.y);
      float4 fr = *(const float4*)&fused[(size_t)sj * 64 + dq * 4];
      acc[0] += wj * fr.x; acc[1] += wj * fr.y;
      acc[2] += wj * fr.z; acc[3] += wj * fr.w;
    }
  }
  #pragma unroll
  for (int c = 0; c < 4; ++c) {
    acc[c] += __shfl_xor(acc[c], 16);
    acc[c] += __shfl_xor(acc[c], 32);
  }
  if (lane < 16) {
    float4 sf = *(const float4*)&fused[(size_t)n * 64 + lane * 4];
    float sw = dd * dd;
    *(float4*)&agg[(size_t)n * 64 + lane * 4] =
        make_float4(acc[0] + sw * sf.x, acc[1] + sw * sf.y,
                    acc[2] + sw * sf.z, acc[3] + sw * sf.w);
  }
}

// ---- emb = relu(agg @ W2 + b2): 16 rows/block, 4 rows/wave in-flight ----
#define E2_ROWS 16
__global__ __launch_bounds__(256) void k_emb2(const float* __restrict__ agg,
                                              const void* W2, const void* b2,
                                              const int* __restrict__ flags,
                                              float* __restrict__ dout) {
  __shared__ u16 W2L[64 * 256];
  __shared__ float agL[E2_ROWS * 64];
  __shared__ float b2L[256];
  int tid = threadIdx.x, f32 = flags[0];
  for (int i = tid; i < 64 * 256; i += 256)
    W2L[i] = f32 ? f2bf(((const float*)W2)[i]) : ((const u16*)W2)[i];
  b2L[tid] = ldf(b2, tid, f32);
  {
    // 16 rows × 64 = 1024 floats, contiguous from agg[n0*64]
    int n0 = blockIdx.x * E2_ROWS;
    *(float4*)&agL[tid * 4] = *(const float4*)&agg[(size_t)n0 * 64 + tid * 4];
  }
  __syncthreads();
  int wid = tid >> 6, lane = tid & 63;
  int n0 = blockIdx.x * E2_ROWS + wid * 4;  // wave handles rows n0..n0+3
  const float* ag = &agL[wid * 4 * 64];
  float b0 = b2L[lane * 4], b1v = b2L[lane * 4 + 1];
  float b2v = b2L[lane * 4 + 2], b3 = b2L[lane * 4 + 3];
  float A0 = b0, A1 = b1v, A2 = b2v, A3 = b3;   // row 0
  float B0 = b0, B1 = b1v, B2 = b2v, B3 = b3;   // row 1
  float C0 = b0, C1 = b1v, C2 = b2v, C3 = b3;   // row 2
  float D0 = b0, D1 = b1v, D2 = b2v, D3 = b3;   // row 3
  #pragma unroll 8
  for (int k = 0; k < 64; ++k) {
    ushort4 wv = *(const ushort4*)&W2L[k * 256 + lane * 4];
    float w0 = bf2f(wv.x), w1 = bf2f(wv.y), w2 = bf2f(wv.z), w3 = bf2f(wv.w);
    float a = ag[k], b = ag[64 + k], c = ag[128 + k], d = ag[192 + k];
    A0 += a * w0; A1 += a * w1; A2 += a * w2; A3 += a * w3;
    B0 += b * w0; B1 += b * w1; B2 += b * w2; B3 += b * w3;
    C0 += c * w0; C1 += c * w1; C2 += c * w2; C3 += c * w3;
    D0 += d * w0; D1 += d * w1; D2 += d * w2; D3 += d * w3;
  }
  *(float4*)&dout[OFF_EMB + (size_t)(n0 + 0) * 256 + lane * 4] =
      make_float4(fmaxf(A0, 0.f), fmaxf(A1, 0.f), fmaxf(A2, 0.f), fmaxf(A3, 0.f));
  *(float4*)&dout[OFF_EMB + (size_t)(n0 + 1) * 256 + lane * 4] =
      make_float4(fmaxf(B0, 0.f), fmaxf(B1, 0.f), fmaxf(B2, 0.f), fmaxf(B3, 0.f));
  *(float4*)&dout[OFF_EMB + (size_t)(n0 + 2) * 256 + lane * 4] =
      make_float4(fmaxf(C0, 0.f), fmaxf(C1, 0.f), fmaxf(C2, 0.f), fmaxf(C3, 0.f));
  *(float4*)&dout[OFF_EMB + (size_t)(n0 + 3) * 256 + lane * 4] =
      make_float4(fmaxf(D0, 0.f), fmaxf(D1, 0.f), fmaxf(D2, 0.f), fmaxf(D3, 0.f));
}

// ---- vsum = graph_neigh @ fused (LDS gn tiles) + fused row sums ----
__global__ __launch_bounds__(256) void k_vsum(const void* gn,
                                              const float* __restrict__ dout,
                                              const int* __restrict__ flags,
                                              float* __restrict__ part,
                                              float* __restrict__ rspart) {
  __shared__ float gnL[8][1024];
  const float* fused = dout + OFF_FUSED;
  int tid = threadIdx.x, wid = tid >> 6, lane = tid & 63;
  int f32 = flags[0];
  int ks = blockIdx.x, bg = blockIdx.y;
  int nbase = ks * 1024;
  #pragma unroll
  for (int r = 0; r < 8; ++r) {
    #pragma unroll
    for (int i = 0; i < 4; ++i) {
      int colv = i * 256 + tid;
      int nn = nbase + colv;
      gnL[r][colv] = (nn < NN) ? ldf(gn, (size_t)(bg * 8 + r) * NN + nn, f32) : 0.f;
    }
  }
  __syncthreads();
  #pragma unroll
  for (int rr = 0; rr < 2; ++rr) {
    int r = wid * 2 + rr;
    float s = 0.f;
    #pragma unroll
    for (int i = 0; i < 16; ++i) s += gnL[r][i * 64 + lane];
    #pragma unroll
    for (int off = 32; off > 0; off >>= 1) s += __shfl_down(s, off);
    if (lane == 0) rspart[(size_t)ks * 256 + bg * 8 + r] = s;
  }
  int g = lane >> 4, dq = lane & 15;
  float acc[8][4];
  #pragma unroll
  for (int r = 0; r < 8; ++r)
    #pragma unroll
    for (int c = 0; c < 4; ++c) acc[r][c] = 0.f;
  for (int i = 0; i < 64; ++i) {
    int nloc = wid * 256 + i * 4 + g;
    int nn = nbase + nloc;
    float4 fr = (nn < NN) ? *(const float4*)&fused[(size_t)nn * 64 + dq * 4]
                          : make_float4(0.f, 0.f, 0.f, 0.f);
    #pragma unroll
    for (int r = 0; r < 8; ++r) {
      float gv = gnL[r][nloc];
      acc[r][0] += gv * fr.x; acc[r][1] += gv * fr.y;
      acc[r][2] += gv * fr.z; acc[r][3] += gv * fr.w;
    }
  }
  #pragma unroll
  for (int r = 0; r < 8; ++r)
    #pragma unroll
    for (int c = 0; c < 4; ++c) {
      acc[r][c] += __shfl_xor(acc[r][c], 16);
      acc[r][c] += __shfl_xor(acc[r][c], 32);
    }
  if (lane < 16) {
    int slice = ks * 4 + wid;
    #pragma unroll
    for (int r = 0; r < 8; ++r)
      *(float4*)&part[((size_t)slice * 256 + bg * 8 + r) * 64 + lane * 4] =
          make_float4(acc[r][0], acc[r][1], acc[r][2], acc[r][3]);
  }
}

// ---- g finalize: reduce partials, divide by row_sum, L2 normalize ----
__global__ __launch_bounds__(64) void k_gfinal(const float* __restrict__ part,
                                               const float* __restrict__ rspart,
                                               float* __restrict__ dout) {
  int b = blockIdx.x, j = threadIdx.x;
  float acc = 0.f;
  for (int k = 0; k < VS_SL; ++k) acc += part[((size_t)k * 256 + b) * 64 + j];
  float rs = 0.f;
  for (int k = 0; k < VS_NC; ++k) rs += rspart[(size_t)k * 256 + b];
  float v = acc / rs;
  float sq = v * v;
  #pragma unroll
  for (int off = 32; off > 0; off >>= 1) sq += __shfl_xor(sq, off);
  float nrm = sqrtf(sq);
  dout[OFF_G + (size_t)b * 64 + j] = v / fmaxf(nrm, 1e-12f);
}

extern "C" void kernel_launch(void* const* d_in, const int* in_sizes, int n_in,
                              void* d_out, int out_size, void* d_ws, size_t ws_size,
                              hipStream_t stream) {
  const void* x   = d_in[0];
  const void* ei  = d_in[1];
  const void* gn  = d_in[2];
  const void* aew = d_in[3];
  const void* W1  = d_in[4];
  const void* b1  = d_in[5];
  const void* W2  = d_in[6];
  const void* b2  = d_in[7];
  const void* Wf  = d_in[8];
  const void* bfv = d_in[9];
  const void* qf  = d_in[10];

  char* ws = (char*)d_ws;
  size_t off = 0;
  auto alloc = [&](size_t bytes) -> void* {
    void* p = ws + off;
    off += (bytes + 255) & ~(size_t)255;
    return p;
  };
  // zero-init region (atomically accumulated buffers only)
  float*    deg     = (float*)alloc((size_t)3 * NN * 4);
  unsigned* cnt     = (unsigned*)alloc((size_t)NN * 4);
  unsigned* fill    = (unsigned*)alloc((size_t)NN * 4);
  size_t zero_bytes = off;
  int*      flags   = (int*)alloc(64);
  float*    dis2    = (float*)alloc((size_t)NN * 4);
  unsigned* row_ptr = (unsigned*)alloc((size_t)(NN + 1) * 4);
  unsigned* bsum    = (unsigned*)alloc((size_t)NSCB * 4);
  unsigned* boff    = (unsigned*)alloc((size_t)NSCB * 4);
  int*      csr_s   = (int*)alloc((size_t)NE * 4);
  float4*   csr_w   = (float4*)alloc((size_t)NE * 16);
  // time-shared region: h1 (k_h1v->k_gath1), agg (k_agg2->k_emb2), part (k_vsum->k_gfinal)
  size_t regA_bytes = (size_t)VS_SL * NB * 64 * 4;
  char*  regA       = (char*)alloc(regA_bytes);
  float* h1   = (float*)regA;
  float* agg  = (float*)regA;
  float* part = (float*)regA;
  float* rspart = (float*)alloc((size_t)VS_NC * NB * 4);

  float* dout = (float*)d_out;

  hipMemsetAsync(d_ws, 0, zero_bytes, stream);
  k_detect<<<1, 64, 0, stream>>>(x, ei, flags);
  k_deg<<<(NE + 255) / 256, 256, 0, stream>>>(ei, aew, flags, deg, cnt);
  k_dis<<<(3 * NN + 255) / 256, 256, 0, stream>>>(deg, cnt, dis2);
  k_sc1<<<NSCB, 256, 0, stream>>>(cnt, bsum);
  k_sc2<<<1, 256, 0, stream>>>(bsum, boff, row_ptr);
  k_sc3<<<NSCB, 256, 0, stream>>>(cnt, boff, row_ptr);
  k_fill<<<(NE + 255) / 256, 256, 0, stream>>>(ei, flags, row_ptr, deg, dis2, aew,
                                               fill, csr_s, csr_w);
  k_h1v<<<(NN + H1_ROWS - 1) / H1_ROWS, 256, 0, stream>>>(x, W1, flags, h1);
  k_gath1<<<(NN + 3) / 4, 256, 0, stream>>>(h1, csr_s, csr_w, row_ptr, deg, b1,
                                            flags, dout);
  k_attn<<<(NN + 3) / 4, 256, 0, stream>>>(Wf, bfv, qf, flags, dout);
  k_agg2<<<(NN + 3) / 4, 256, 0, stream>>>(csr_s, csr_w, row_ptr, dis2, dout, agg);
  k_emb2<<<NN / E2_ROWS, 256, 0, stream>>>(agg, W2, b2, flags, dout);
  {
    dim3 gdim(VS_NC, 32);
    k_vsum<<<gdim, 256, 0, stream>>>(gn, dout, flags, part, rspart);
  }
  k_gfinal<<<NB, 64, 0, stream>>>(part, rspart, dout);
}

// Round 12
// 622.531 us; speedup vs baseline: 4.6036x; 1.0531x over previous
//
#include <hip/hip_runtime.h>
#include <hip/hip_bf16.h>

#define NN 50000
#define NE 800000
#define NG 3
#define NB 256
#define NSCB 196  // ceil(NN/256)

#define OFF_FUSED ((size_t)0)
#define OFF_EMB   ((size_t)NN * 64)
#define OFF_G     (OFF_EMB + (size_t)NN * 256)
#define OFF_HID   (OFF_G + (size_t)NB * 64)
#define OFF_ATTN  (OFF_HID + (size_t)3 * NN * 64)

// k_vsum geometry: 49 n-chunks of 1024; 32 b-groups of 8 rows; slice = ks*4+wave
#define VS_NC 49
#define VS_SL (VS_NC * 4)

typedef unsigned short u16;

__device__ __forceinline__ float bf2f(u16 u) {
  union { unsigned int i; float f; } v; v.i = ((unsigned int)u) << 16; return v.f;
}
__device__ __forceinline__ u16 f2bf(float f) {
  unsigned int x = __float_as_uint(f);
  unsigned int r = (x + 0x7FFFu + ((x >> 16) & 1u)) >> 16;
  return (u16)r;
}
__device__ __forceinline__ float ldf(const void* p, size_t i, int f32) {
  return f32 ? ((const float*)p)[i] : bf2f(((const u16*)p)[i]);
}
__device__ __forceinline__ int ld_src(const void* ei, int e, int i64) {
  return i64 ? (int)((const long long*)ei)[e] : ((const int*)ei)[e];
}
__device__ __forceinline__ int ld_dst(const void* ei, int e, int i64) {
  return i64 ? (int)((const long long*)ei)[(size_t)NE + e] : ((const int*)ei)[(size_t)NE + e];
}

// ---- dtype detection ----
__global__ void k_detect(const void* x, const void* ei, int* flags) {
  if (threadIdx.x != 0 || blockIdx.x != 0) return;
  const u16* xw = (const u16*)x;
  int sane = 0;
  for (int i = 0; i < 64; ++i) {
    unsigned ex = (xw[2 * i] >> 7) & 0xFF;
    sane += (ex >= 96 && ex <= 141);
  }
  flags[0] = (sane < 48) ? 1 : 0;  // 1 => inputs are float32
  const int* e32 = (const int*)ei;
  int zeros = 0;
  for (int t = 1; t < 32; t += 2) zeros += (e32[t] == 0);
  flags[1] = (zeros >= 12) ? 1 : 0;  // 1 => edge_index is int64
}

// ---- degree accumulation ----
__global__ void k_deg(const void* ei, const void* aew, const int* __restrict__ flags,
                      float* __restrict__ deg, unsigned* __restrict__ cnt) {
  int e = blockIdx.x * 256 + threadIdx.x;
  if (e >= NE) return;
  int f32 = flags[0], i64 = flags[1];
  int d = ld_dst(ei, e, i64);
  atomicAdd(&cnt[d], 1u);
  atomicAdd(&deg[d],          ldf(aew, e, f32));
  atomicAdd(&deg[NN + d],     ldf(aew, (size_t)NE + e, f32));
  atomicAdd(&deg[2 * NN + d], ldf(aew, (size_t)2 * NE + e, f32));
}

__global__ void k_dis(float* __restrict__ deg, const unsigned* __restrict__ cnt,
                      float* __restrict__ dis2) {
  int i = blockIdx.x * 256 + threadIdx.x;
  if (i < 3 * NN) deg[i] = rsqrtf(deg[i] + 1.0f);
  if (i < NN) dis2[i] = rsqrtf((float)cnt[i] + 1.0f);
}

// ---- 3-phase exclusive scan of cnt -> row_ptr ----
__global__ __launch_bounds__(256) void k_sc1(const unsigned* __restrict__ cnt,
                                             unsigned* __restrict__ bsum) {
  int b = blockIdx.x, tid = threadIdx.x, i = b * 256 + tid;
  unsigned v = (i < NN) ? cnt[i] : 0u;
  #pragma unroll
  for (int off = 32; off > 0; off >>= 1) v += __shfl_down(v, off);
  __shared__ unsigned w4[4];
  if ((tid & 63) == 0) w4[tid >> 6] = v;
  __syncthreads();
  if (tid == 0) bsum[b] = w4[0] + w4[1] + w4[2] + w4[3];
}
__global__ __launch_bounds__(256) void k_sc2(const unsigned* __restrict__ bsum,
                                             unsigned* __restrict__ boff,
                                             unsigned* __restrict__ row_ptr) {
  int tid = threadIdx.x, lane = tid & 63, w = tid >> 6;
  unsigned v = (tid < NSCB) ? bsum[tid] : 0u;
  unsigned x = v;
  #pragma unroll
  for (int off = 1; off < 64; off <<= 1) {
    unsigned y = __shfl_up(x, off);
    if (lane >= off) x += y;
  }
  __shared__ unsigned w4[4];
  if (lane == 63) w4[w] = x;
  __syncthreads();
  unsigned woff = 0;
  #pragma unroll
  for (int k = 0; k < 4; ++k) woff += (k < w) ? w4[k] : 0u;
  if (tid < NSCB) boff[tid] = woff + x - v;
  if (tid == 255) row_ptr[NN] = woff + x;
}
__global__ __launch_bounds__(256) void k_sc3(const unsigned* __restrict__ cnt,
                                             const unsigned* __restrict__ boff,
                                             unsigned* __restrict__ row_ptr) {
  int b = blockIdx.x, tid = threadIdx.x, lane = tid & 63, w = tid >> 6;
  int i = b * 256 + tid;
  unsigned v = (i < NN) ? cnt[i] : 0u;
  unsigned x = v;
  #pragma unroll
  for (int off = 1; off < 64; off <<= 1) {
    unsigned y = __shfl_up(x, off);
    if (lane >= off) x += y;
  }
  __shared__ unsigned w4[4];
  if (lane == 63) w4[w] = x;
  __syncthreads();
  unsigned woff = 0;
  #pragma unroll
  for (int k = 0; k < 4; ++k) woff += (k < w) ? w4[k] : 0u;
  if (i < NN) row_ptr[i] = boff[b] + woff + x - v;
}

// ---- CSR fill with packed, pre-normalized edge data ----
__global__ void k_fill(const void* ei, const int* __restrict__ flags,
                       const unsigned* __restrict__ row_ptr,
                       const float* __restrict__ dis, const float* __restrict__ dis2,
                       const void* aew, unsigned* __restrict__ fill,
                       int* __restrict__ csr_s, float4* __restrict__ csr_w) {
  int e = blockIdx.x * 256 + threadIdx.x;
  if (e >= NE) return;
  int f32 = flags[0], i64 = flags[1];
  int s = ld_src(ei, e, i64);
  int d = ld_dst(ei, e, i64);
  unsigned pos = row_ptr[d] + atomicAdd(&fill[d], 1u);
  float w0 = dis[s]          * ldf(aew, e, f32);
  float w1 = dis[NN + s]     * ldf(aew, (size_t)NE + e, f32);
  float w2 = dis[2 * NN + s] * ldf(aew, (size_t)2 * NE + e, f32);
  csr_s[pos] = s;
  csr_w[pos] = make_float4(w0, w1, w2, dis2[s]);
}

// ---- h1 = x @ W1: 16 rows/block, k-interleaved 4-way, W1 staged once ----
#define H1_ROWS 16
__global__ __launch_bounds__(256) void k_h1v(const void* x, const void* W1,
                                             const int* __restrict__ flags,
                                             float* __restrict__ h1) {
  __shared__ u16 W1L[256 * 68];   // [k][j], stride 68 shorts
  __shared__ float xL[4][256];    // one row per wave (wave-private)
  int tid = threadIdx.x, f32 = flags[0];
  for (int i = tid; i < 256 * 64; i += 256) {
    int k = i >> 6, j = i & 63;
    W1L[k * 68 + j] = f32 ? f2bf(((const float*)W1)[i]) : ((const u16*)W1)[i];
  }
  __syncthreads();
  int wid = tid >> 6, lane = tid & 63;
  int rg = lane >> 4, dq = lane & 15;
  int rowbase = blockIdx.x * H1_ROWS;
  #pragma unroll 1
  for (int rr = 0; rr < H1_ROWS / 4; ++rr) {
    int n = rowbase + rr * 4 + wid;
    if (n < NN) {
      if (f32) {
        float4 xv = *(const float4*)((const float*)x + (size_t)n * 256 + lane * 4);
        *(float4*)&xL[wid][lane * 4] = xv;
      } else {
        ushort4 xv = *(const ushort4*)((const u16*)x + (size_t)n * 256 + lane * 4);
        *(float4*)&xL[wid][lane * 4] =
            make_float4(bf2f(xv.x), bf2f(xv.y), bf2f(xv.z), bf2f(xv.w));
      }
    } else {
      *(float4*)&xL[wid][lane * 4] = make_float4(0.f, 0.f, 0.f, 0.f);
    }
    float acc0 = 0.f, acc1 = 0.f, acc2 = 0.f, acc3 = 0.f;
    #pragma unroll 8
    for (int kk = 0; kk < 64; ++kk) {
      int k = kk * 4 + rg;
      float xk = xL[wid][k];
      ushort4 wv = *(const ushort4*)&W1L[k * 68 + dq * 4];
      acc0 += xk * bf2f(wv.x); acc1 += xk * bf2f(wv.y);
      acc2 += xk * bf2f(wv.z); acc3 += xk * bf2f(wv.w);
    }
    acc0 += __shfl_xor(acc0, 16); acc0 += __shfl_xor(acc0, 32);
    acc1 += __shfl_xor(acc1, 16); acc1 += __shfl_xor(acc1, 32);
    acc2 += __shfl_xor(acc2, 16); acc2 += __shfl_xor(acc2, 32);
    acc3 += __shfl_xor(acc3, 16); acc3 += __shfl_xor(acc3, 32);
    if (rg == 0 && n < NN)
      *(float4*)&h1[(size_t)n * 64 + dq * 4] = make_float4(acc0, acc1, acc2, acc3);
  }
}

// ---- gather layer1 only (3 graphs), max occupancy ----
__global__ __launch_bounds__(256) void k_gath1(
    const float* __restrict__ h1, const int* __restrict__ csr_s,
    const float4* __restrict__ csr_w, const unsigned* __restrict__ row_ptr,
    const float* __restrict__ deg_dis, const void* b1,
    const int* __restrict__ flags, float* __restrict__ dout) {
  __shared__ float4 eWL[4][64];  // 4 KB per-wave edge staging
  __shared__ float b1L[64];
  int tid = threadIdx.x, f32 = flags[0];
  if (tid < 64) b1L[tid] = ldf(b1, tid, f32);
  __syncthreads();
  int wid = tid >> 6, lane = tid & 63;
  int n = blockIdx.x * 4 + wid;
  if (n >= NN) return;

  float dd0 = deg_dis[n], dd1 = deg_dis[NN + n], dd2 = deg_dis[2 * NN + n];
  float a0[4] = {0,0,0,0}, a1[4] = {0,0,0,0}, a2[4] = {0,0,0,0};
  int g = lane >> 4, dq = lane & 15;
  unsigned beg = row_ptr[n], end = row_ptr[n + 1];
  for (unsigned base = beg; base < end; base += 64) {
    unsigned rem = end - base;
    int m = (rem > 64u) ? 64 : (int)rem;
    float4 st = make_float4(0.f, 0.f, 0.f, __int_as_float(0));
    if (lane < m) {
      float4 cw = csr_w[base + lane];
      int s = csr_s[base + lane];
      st = make_float4(cw.x * dd0, cw.y * dd1, cw.z * dd2, __int_as_float(s));
    }
    eWL[wid][lane] = st;   // wave-private row; same-wave LDS ops are in-order
    int jmax = (m + 3) >> 2;
    for (int j = 0; j < jmax; ++j) {
      float4 e = eWL[wid][j * 4 + g];
      int sj = __float_as_int(e.w);
      float4 hr = *(const float4*)&h1[(size_t)sj * 64 + dq * 4];
      a0[0] += e.x * hr.x; a0[1] += e.x * hr.y; a0[2] += e.x * hr.z; a0[3] += e.x * hr.w;
      a1[0] += e.y * hr.x; a1[1] += e.y * hr.y; a1[2] += e.y * hr.z; a1[3] += e.y * hr.w;
      a2[0] += e.z * hr.x; a2[1] += e.z * hr.y; a2[2] += e.z * hr.z; a2[3] += e.z * hr.w;
    }
  }
  #pragma unroll
  for (int c = 0; c < 4; ++c) {
    a0[c] += __shfl_xor(a0[c], 16); a0[c] += __shfl_xor(a0[c], 32);
    a1[c] += __shfl_xor(a1[c], 16); a1[c] += __shfl_xor(a1[c], 32);
    a2[c] += __shfl_xor(a2[c], 16); a2[c] += __shfl_xor(a2[c], 32);
  }
  // redistribute to lane=dim layout
  int srcl = lane >> 2, cc = lane & 3;
  float t0, t1, t2, t3, r0, r1, r2;
  t0 = __shfl(a0[0], srcl); t1 = __shfl(a0[1], srcl);
  t2 = __shfl(a0[2], srcl); t3 = __shfl(a0[3], srcl);
  r0 = cc == 0 ? t0 : cc == 1 ? t1 : cc == 2 ? t2 : t3;
  t0 = __shfl(a1[0], srcl); t1 = __shfl(a1[1], srcl);
  t2 = __shfl(a1[2], srcl); t3 = __shfl(a1[3], srcl);
  r1 = cc == 0 ? t0 : cc == 1 ? t1 : cc == 2 ? t2 : t3;
  t0 = __shfl(a2[0], srcl); t1 = __shfl(a2[1], srcl);
  t2 = __shfl(a2[2], srcl); t3 = __shfl(a2[3], srcl);
  r2 = cc == 0 ? t0 : cc == 1 ? t1 : cc == 2 ? t2 : t3;

  float selfv = h1[(size_t)n * 64 + lane];
  float b1v = b1L[lane];
  dout[OFF_HID + ((size_t)0 * NN + n) * 64 + lane] = fmaxf(r0 + dd0 * dd0 * selfv + b1v, 0.f);
  dout[OFF_HID + ((size_t)1 * NN + n) * 64 + lane] = fmaxf(r1 + dd1 * dd1 * selfv + b1v, 0.f);
  dout[OFF_HID + ((size_t)2 * NN + n) * 64 + lane] = fmaxf(r2 + dd2 * dd2 * selfv + b1v, 0.f);
}

// ---- dense attention: 16 nodes/block, node-per-lane-group, no reductions ----
#define WFS 66   // Wf LDS row stride in shorts
#define AT_ROWS 16
#define HS 68    // hid LDS row stride in floats (16B aligned, nodes 4 banks apart)
__global__ __launch_bounds__(256) void k_attn(
    const void* Wf, const void* bfv, const void* qf,
    const int* __restrict__ flags, float* __restrict__ dout) {
  __shared__ u16 WfL[3 * 64 * WFS];          // 25.3 KB
  __shared__ float hidL[3][AT_ROWS][HS];     // 13.1 KB
  __shared__ float qfL[192], bfL[192];
  int tid = threadIdx.x, f32 = flags[0];
  int n0 = blockIdx.x * AT_ROWS;             // NN % 16 == 0: no tail anywhere
  for (int i = tid; i < 3 * 64 * 64; i += 256) {
    int gi = i >> 12, rem = i & 4095, k = rem >> 6, j = rem & 63;
    WfL[gi * 64 * WFS + k * WFS + j] =
        f32 ? f2bf(((const float*)Wf)[i]) : ((const u16*)Wf)[i];
  }
  for (int i = tid; i < 3 * AT_ROWS * 64; i += 256) {
    int gi = i >> 10, rem = i & 1023, node = rem >> 6, k = rem & 63;
    hidL[gi][node][k] = dout[OFF_HID + ((size_t)gi * NN + (n0 + node)) * 64 + k];
  }
  if (tid < 192) { qfL[tid] = ldf(qf, tid, f32); bfL[tid] = ldf(bfv, tid, f32); }
  __syncthreads();
  int wid = tid >> 6, lane = tid & 63;
  int ng = lane >> 4, dq = lane & 15;   // node-group, j-quad
  int node = wid * 4 + ng;              // local node 0..15
  int n = n0 + node;

  float u0[4] = {0,0,0,0}, u1[4] = {0,0,0,0}, u2[4] = {0,0,0,0};
  #pragma unroll 8
  for (int k = 0; k < 64; ++k) {
    // same addr across 4 node-groups -> broadcast; dq tiles 128B -> conflict-free
    ushort4 w0v = *(const ushort4*)&WfL[k * WFS + dq * 4];
    ushort4 w1v = *(const ushort4*)&WfL[64 * WFS + k * WFS + dq * 4];
    ushort4 w2v = *(const ushort4*)&WfL[128 * WFS + k * WFS + dq * 4];
    float h0 = hidL[0][node][k], h1b = hidL[1][node][k], h2b = hidL[2][node][k];
    u0[0] += h0 * bf2f(w0v.x); u0[1] += h0 * bf2f(w0v.y);
    u0[2] += h0 * bf2f(w0v.z); u0[3] += h0 * bf2f(w0v.w);
    u1[0] += h1b * bf2f(w1v.x); u1[1] += h1b * bf2f(w1v.y);
    u1[2] += h1b * bf2f(w1v.z); u1[3] += h1b * bf2f(w1v.w);
    u2[0] += h2b * bf2f(w2v.x); u2[1] += h2b * bf2f(w2v.y);
    u2[2] += h2b * bf2f(w2v.z); u2[3] += h2b * bf2f(w2v.w);
  }
  // scores: tanh + qf dot, then 4-step reduce within the 16-lane group
  float p0 = 0.f, p1 = 0.f, p2 = 0.f;
  #pragma unroll
  for (int c = 0; c < 4; ++c) {
    int j = dq * 4 + c;
    p0 += tanhf(u0[c] + bfL[j])       * qfL[j];
    p1 += tanhf(u1[c] + bfL[64 + j])  * qfL[64 + j];
    p2 += tanhf(u2[c] + bfL[128 + j]) * qfL[128 + j];
  }
  #pragma unroll
  for (int off = 1; off < 16; off <<= 1) {
    p0 += __shfl_xor(p0, off);
    p1 += __shfl_xor(p1, off);
    p2 += __shfl_xor(p2, off);
  }
  float mx = fmaxf(p0, fmaxf(p1, p2));
  float e0 = expf(p0 - mx), e1 = expf(p1 - mx), e2 = expf(p2 - mx);
  float inv = 1.0f / (e0 + e1 + e2);
  float aw0 = e0 * inv, aw1 = e1 * inv, aw2 = e2 * inv;
  float4 h0v = *(const float4*)&hidL[0][node][dq * 4];
  float4 h1v = *(const float4*)&hidL[1][node][dq * 4];
  float4 h2v = *(const float4*)&hidL[2][node][dq * 4];
  *(float4*)&dout[OFF_FUSED + (size_t)n * 64 + dq * 4] =
      make_float4(aw0 * h0v.x + aw1 * h1v.x + aw2 * h2v.x,
                  aw0 * h0v.y + aw1 * h1v.y + aw2 * h2v.y,
                  aw0 * h0v.z + aw1 * h1v.z + aw2 * h2v.z,
                  aw0 * h0v.w + aw1 * h1v.w + aw2 * h2v.w);
  if (dq < 3) dout[OFF_ATTN + (size_t)n * 3 + dq] =
                  (dq == 0 ? aw0 : (dq == 1 ? aw1 : aw2));
}

// ---- layer2 gather (packed LDS staging): agg = sym-aggregate(fused) ----
__global__ __launch_bounds__(256) void k_agg2(
    const int* __restrict__ csr_s, const float4* __restrict__ csr_w,
    const unsigned* __restrict__ row_ptr, const float* __restrict__ dis2,
    const float* __restrict__ dout, float* __restrict__ agg) {
  __shared__ uint2 eL[4][64];
  const float* fused = dout + OFF_FUSED;
  int tid = threadIdx.x, wid = tid >> 6, lane = tid & 63;
  int n = blockIdx.x * 4 + wid;
  if (n >= NN) return;
  float dd = dis2[n];
  float acc[4] = {0.f, 0.f, 0.f, 0.f};
  int g = lane >> 4, dq = lane & 15;
  unsigned beg = row_ptr[n], end = row_ptr[n + 1];
  for (unsigned base = beg; base < end; base += 64) {
    unsigned rem = end - base;
    int m = (rem > 64u) ? 64 : (int)rem;
    uint2 st = make_uint2(0u, 0u);
    if (lane < m)
      st = make_uint2((unsigned)csr_s[base + lane],
                      __float_as_uint(csr_w[base + lane].w * dd));
    eL[wid][lane] = st;
    int jmax = (m + 3) >> 2;
    for (int j = 0; j < jmax; ++j) {
      uint2 e = eL[wid][j * 4 + g];
      int sj = (int)e.x;
      float wj = __uint_as_float(e.y);
      float4 fr = *(const float4*)&fused[(size_t)sj * 64 + dq * 4];
      acc[0] += wj * fr.x; acc[1] += wj * fr.y;
      acc[2] += wj * fr.z; acc[3] += wj * fr.w;
    }
  }
  #pragma unroll
  for (int c = 0; c < 4; ++c) {
    acc[c] += __shfl_xor(acc[c], 16);
    acc[c] += __shfl_xor(acc[c], 32);
  }
  if (lane < 16) {
    float4 sf = *(const float4*)&fused[(size_t)n * 64 + lane * 4];
    float sw = dd * dd;
    *(float4*)&agg[(size_t)n * 64 + lane * 4] =
        make_float4(acc[0] + sw * sf.x, acc[1] + sw * sf.y,
                    acc[2] + sw * sf.z, acc[3] + sw * sf.w);
  }
}

// ---- emb = relu(agg @ W2 + b2): 16 rows/block, 4 rows/wave in-flight ----
#define E2_ROWS 16
__global__ __launch_bounds__(256) void k_emb2(const float* __restrict__ agg,
                                              const void* W2, const void* b2,
                                              const int* __restrict__ flags,
                                              float* __restrict__ dout) {
  __shared__ u16 W2L[64 * 256];
  __shared__ float agL[E2_ROWS * 64];
  __shared__ float b2L[256];
  int tid = threadIdx.x, f32 = flags[0];
  for (int i = tid; i < 64 * 256; i += 256)
    W2L[i] = f32 ? f2bf(((const float*)W2)[i]) : ((const u16*)W2)[i];
  b2L[tid] = ldf(b2, tid, f32);
  {
    int n0 = blockIdx.x * E2_ROWS;
    *(float4*)&agL[tid * 4] = *(const float4*)&agg[(size_t)n0 * 64 + tid * 4];
  }
  __syncthreads();
  int wid = tid >> 6, lane = tid & 63;
  int n0 = blockIdx.x * E2_ROWS + wid * 4;  // wave handles rows n0..n0+3
  const float* ag = &agL[wid * 4 * 64];
  float b0 = b2L[lane * 4], b1v = b2L[lane * 4 + 1];
  float b2v = b2L[lane * 4 + 2], b3 = b2L[lane * 4 + 3];
  float A0 = b0, A1 = b1v, A2 = b2v, A3 = b3;
  float B0 = b0, B1 = b1v, B2 = b2v, B3 = b3;
  float C0 = b0, C1 = b1v, C2 = b2v, C3 = b3;
  float D0 = b0, D1 = b1v, D2 = b2v, D3 = b3;
  #pragma unroll 8
  for (int k = 0; k < 64; ++k) {
    ushort4 wv = *(const ushort4*)&W2L[k * 256 + lane * 4];
    float w0 = bf2f(wv.x), w1 = bf2f(wv.y), w2 = bf2f(wv.z), w3 = bf2f(wv.w);
    float a = ag[k], b = ag[64 + k], c = ag[128 + k], d = ag[192 + k];
    A0 += a * w0; A1 += a * w1; A2 += a * w2; A3 += a * w3;
    B0 += b * w0; B1 += b * w1; B2 += b * w2; B3 += b * w3;
    C0 += c * w0; C1 += c * w1; C2 += c * w2; C3 += c * w3;
    D0 += d * w0; D1 += d * w1; D2 += d * w2; D3 += d * w3;
  }
  *(float4*)&dout[OFF_EMB + (size_t)(n0 + 0) * 256 + lane * 4] =
      make_float4(fmaxf(A0, 0.f), fmaxf(A1, 0.f), fmaxf(A2, 0.f), fmaxf(A3, 0.f));
  *(float4*)&dout[OFF_EMB + (size_t)(n0 + 1) * 256 + lane * 4] =
      make_float4(fmaxf(B0, 0.f), fmaxf(B1, 0.f), fmaxf(B2, 0.f), fmaxf(B3, 0.f));
  *(float4*)&dout[OFF_EMB + (size_t)(n0 + 2) * 256 + lane * 4] =
      make_float4(fmaxf(C0, 0.f), fmaxf(C1, 0.f), fmaxf(C2, 0.f), fmaxf(C3, 0.f));
  *(float4*)&dout[OFF_EMB + (size_t)(n0 + 3) * 256 + lane * 4] =
      make_float4(fmaxf(D0, 0.f), fmaxf(D1, 0.f), fmaxf(D2, 0.f), fmaxf(D3, 0.f));
}

// ---- vsum = graph_neigh @ fused (LDS gn tiles) + fused row sums ----
__global__ __launch_bounds__(256) void k_vsum(const void* gn,
                                              const float* __restrict__ dout,
                                              const int* __restrict__ flags,
                                              float* __restrict__ part,
                                              float* __restrict__ rspart) {
  __shared__ float gnL[8][1024];
  const float* fused = dout + OFF_FUSED;
  int tid = threadIdx.x, wid = tid >> 6, lane = tid & 63;
  int f32 = flags[0];
  int ks = blockIdx.x, bg = blockIdx.y;
  int nbase = ks * 1024;
  #pragma unroll
  for (int r = 0; r < 8; ++r) {
    #pragma unroll
    for (int i = 0; i < 4; ++i) {
      int colv = i * 256 + tid;
      int nn = nbase + colv;
      gnL[r][colv] = (nn < NN) ? ldf(gn, (size_t)(bg * 8 + r) * NN + nn, f32) : 0.f;
    }
  }
  __syncthreads();
  #pragma unroll
  for (int rr = 0; rr < 2; ++rr) {
    int r = wid * 2 + rr;
    float s = 0.f;
    #pragma unroll
    for (int i = 0; i < 16; ++i) s += gnL[r][i * 64 + lane];
    #pragma unroll
    for (int off = 32; off > 0; off >>= 1) s += __shfl_down(s, off);
    if (lane == 0) rspart[(size_t)ks * 256 + bg * 8 + r] = s;
  }
  int g = lane >> 4, dq = lane & 15;
  float acc[8][4];
  #pragma unroll
  for (int r = 0; r < 8; ++r)
    #pragma unroll
    for (int c = 0; c < 4; ++c) acc[r][c] = 0.f;
  for (int i = 0; i < 64; ++i) {
    int nloc = wid * 256 + i * 4 + g;
    int nn = nbase + nloc;
    float4 fr = (nn < NN) ? *(const float4*)&fused[(size_t)nn * 64 + dq * 4]
                          : make_float4(0.f, 0.f, 0.f, 0.f);
    #pragma unroll
    for (int r = 0; r < 8; ++r) {
      float gv = gnL[r][nloc];
      acc[r][0] += gv * fr.x; acc[r][1] += gv * fr.y;
      acc[r][2] += gv * fr.z; acc[r][3] += gv * fr.w;
    }
  }
  #pragma unroll
  for (int r = 0; r < 8; ++r)
    #pragma unroll
    for (int c = 0; c < 4; ++c) {
      acc[r][c] += __shfl_xor(acc[r][c], 16);
      acc[r][c] += __shfl_xor(acc[r][c], 32);
    }
  if (lane < 16) {
    int slice = ks * 4 + wid;
    #pragma unroll
    for (int r = 0; r < 8; ++r)
      *(float4*)&part[((size_t)slice * 256 + bg * 8 + r) * 64 + lane * 4] =
          make_float4(acc[r][0], acc[r][1], acc[r][2], acc[r][3]);
  }
}

// ---- g finalize: reduce partials, divide by row_sum, L2 normalize ----
__global__ __launch_bounds__(64) void k_gfinal(const float* __restrict__ part,
                                               const float* __restrict__ rspart,
                                               float* __restrict__ dout) {
  int b = blockIdx.x, j = threadIdx.x;
  float acc = 0.f;
  for (int k = 0; k < VS_SL; ++k) acc += part[((size_t)k * 256 + b) * 64 + j];
  float rs = 0.f;
  for (int k = 0; k < VS_NC; ++k) rs += rspart[(size_t)k * 256 + b];
  float v = acc / rs;
  float sq = v * v;
  #pragma unroll
  for (int off = 32; off > 0; off >>= 1) sq += __shfl_xor(sq, off);
  float nrm = sqrtf(sq);
  dout[OFF_G + (size_t)b * 64 + j] = v / fmaxf(nrm, 1e-12f);
}

extern "C" void kernel_launch(void* const* d_in, const int* in_sizes, int n_in,
                              void* d_out, int out_size, void* d_ws, size_t ws_size,
                              hipStream_t stream) {
  const void* x   = d_in[0];
  const void* ei  = d_in[1];
  const void* gn  = d_in[2];
  const void* aew = d_in[3];
  const void* W1  = d_in[4];
  const void* b1  = d_in[5];
  const void* W2  = d_in[6];
  const void* b2  = d_in[7];
  const void* Wf  = d_in[8];
  const void* bfv = d_in[9];
  const void* qf  = d_in[10];

  char* ws = (char*)d_ws;
  size_t off = 0;
  auto alloc = [&](size_t bytes) -> void* {
    void* p = ws + off;
    off += (bytes + 255) & ~(size_t)255;
    return p;
  };
  // zero-init region (atomically accumulated buffers only)
  float*    deg     = (float*)alloc((size_t)3 * NN * 4);
  unsigned* cnt     = (unsigned*)alloc((size_t)NN * 4);
  unsigned* fill    = (unsigned*)alloc((size_t)NN * 4);
  size_t zero_bytes = off;
  int*      flags   = (int*)alloc(64);
  float*    dis2    = (float*)alloc((size_t)NN * 4);
  unsigned* row_ptr = (unsigned*)alloc((size_t)(NN + 1) * 4);
  unsigned* bsum    = (unsigned*)alloc((size_t)NSCB * 4);
  unsigned* boff    = (unsigned*)alloc((size_t)NSCB * 4);
  int*      csr_s   = (int*)alloc((size_t)NE * 4);
  float4*   csr_w   = (float4*)alloc((size_t)NE * 16);
  // time-shared region: h1 (k_h1v->k_gath1), agg (k_agg2->k_emb2), part (k_vsum->k_gfinal)
  size_t regA_bytes = (size_t)VS_SL * NB * 64 * 4;
  char*  regA       = (char*)alloc(regA_bytes);
  float* h1   = (float*)regA;
  float* agg  = (float*)regA;
  float* part = (float*)regA;
  float* rspart = (float*)alloc((size_t)VS_NC * NB * 4);

  float* dout = (float*)d_out;

  hipMemsetAsync(d_ws, 0, zero_bytes, stream);
  k_detect<<<1, 64, 0, stream>>>(x, ei, flags);
  k_deg<<<(NE + 255) / 256, 256, 0, stream>>>(ei, aew, flags, deg, cnt);
  k_dis<<<(3 * NN + 255) / 256, 256, 0, stream>>>(deg, cnt, dis2);
  k_sc1<<<NSCB, 256, 0, stream>>>(cnt, bsum);
  k_sc2<<<1, 256, 0, stream>>>(bsum, boff, row_ptr);
  k_sc3<<<NSCB, 256, 0, stream>>>(cnt, boff, row_ptr);
  k_fill<<<(NE + 255) / 256, 256, 0, stream>>>(ei, flags, row_ptr, deg, dis2, aew,
                                               fill, csr_s, csr_w);
  k_h1v<<<(NN + H1_ROWS - 1) / H1_ROWS, 256, 0, stream>>>(x, W1, flags, h1);
  k_gath1<<<(NN + 3) / 4, 256, 0, stream>>>(h1, csr_s, csr_w, row_ptr, deg, b1,
                                            flags, dout);
  k_attn<<<NN / AT_ROWS, 256, 0, stream>>>(Wf, bfv, qf, flags, dout);
  k_agg2<<<(NN + 3) / 4, 256, 0, stream>>>(csr_s, csr_w, row_ptr, dis2, dout, agg);
  k_emb2<<<NN / E2_ROWS, 256, 0, stream>>>(agg, W2, b2, flags, dout);
  {
    dim3 gdim(VS_NC, 32);
    k_vsum<<<gdim, 256, 0, stream>>>(gn, dout, flags, part, rspart);
  }
  k_gfinal<<<NB, 64, 0, stream>>>(part, rspart, dout);
}

// Round 13
// 527.204 us; speedup vs baseline: 5.4360x; 1.1808x over previous
//
#include <hip/hip_runtime.h>
#include <hip/hip_bf16.h>

#define NN 50000
#define NE 800000
#define NG 3
#define NB 256
#define NSCB 196  // ceil(NN/256)

#define OFF_FUSED ((size_t)0)
#define OFF_EMB   ((size_t)NN * 64)
#define OFF_G     (OFF_EMB + (size_t)NN * 256)
#define OFF_HID   (OFF_G + (size_t)NB * 64)
#define OFF_ATTN  (OFF_HID + (size_t)3 * NN * 64)

// k_vsum geometry: 49 n-chunks of 1024; 32 b-groups of 8 rows; slice = ks*4+wave
#define VS_NC 49
#define VS_SL (VS_NC * 4)

typedef unsigned short u16;

__device__ __forceinline__ float bf2f(u16 u) {
  union { unsigned int i; float f; } v; v.i = ((unsigned int)u) << 16; return v.f;
}
__device__ __forceinline__ u16 f2bf(float f) {
  unsigned int x = __float_as_uint(f);
  unsigned int r = (x + 0x7FFFu + ((x >> 16) & 1u)) >> 16;
  return (u16)r;
}
__device__ __forceinline__ float ldf(const void* p, size_t i, int f32) {
  return f32 ? ((const float*)p)[i] : bf2f(((const u16*)p)[i]);
}
__device__ __forceinline__ int ld_src(const void* ei, int e, int i64) {
  return i64 ? (int)((const long long*)ei)[e] : ((const int*)ei)[e];
}
__device__ __forceinline__ int ld_dst(const void* ei, int e, int i64) {
  return i64 ? (int)((const long long*)ei)[(size_t)NE + e] : ((const int*)ei)[(size_t)NE + e];
}

// ---- dtype detection ----
__global__ void k_detect(const void* x, const void* ei, int* flags) {
  if (threadIdx.x != 0 || blockIdx.x != 0) return;
  const u16* xw = (const u16*)x;
  int sane = 0;
  for (int i = 0; i < 64; ++i) {
    unsigned ex = (xw[2 * i] >> 7) & 0xFF;
    sane += (ex >= 96 && ex <= 141);
  }
  flags[0] = (sane < 48) ? 1 : 0;  // 1 => inputs are float32
  const int* e32 = (const int*)ei;
  int zeros = 0;
  for (int t = 1; t < 32; t += 2) zeros += (e32[t] == 0);
  flags[1] = (zeros >= 12) ? 1 : 0;  // 1 => edge_index is int64
}

// ---- edge count histogram (the only per-edge atomic besides fill) ----
__global__ void k_cnt(const void* ei, const int* __restrict__ flags,
                      unsigned* __restrict__ cnt) {
  int e = blockIdx.x * 256 + threadIdx.x;
  if (e >= NE) return;
  atomicAdd(&cnt[ld_dst(ei, e, flags[1])], 1u);
}

// ---- 3-phase exclusive scan of cnt -> row_ptr ----
__global__ __launch_bounds__(256) void k_sc1(const unsigned* __restrict__ cnt,
                                             unsigned* __restrict__ bsum) {
  int b = blockIdx.x, tid = threadIdx.x, i = b * 256 + tid;
  unsigned v = (i < NN) ? cnt[i] : 0u;
  #pragma unroll
  for (int off = 32; off > 0; off >>= 1) v += __shfl_down(v, off);
  __shared__ unsigned w4[4];
  if ((tid & 63) == 0) w4[tid >> 6] = v;
  __syncthreads();
  if (tid == 0) bsum[b] = w4[0] + w4[1] + w4[2] + w4[3];
}
__global__ __launch_bounds__(256) void k_sc2(const unsigned* __restrict__ bsum,
                                             unsigned* __restrict__ boff,
                                             unsigned* __restrict__ row_ptr) {
  int tid = threadIdx.x, lane = tid & 63, w = tid >> 6;
  unsigned v = (tid < NSCB) ? bsum[tid] : 0u;
  unsigned x = v;
  #pragma unroll
  for (int off = 1; off < 64; off <<= 1) {
    unsigned y = __shfl_up(x, off);
    if (lane >= off) x += y;
  }
  __shared__ unsigned w4[4];
  if (lane == 63) w4[w] = x;
  __syncthreads();
  unsigned woff = 0;
  #pragma unroll
  for (int k = 0; k < 4; ++k) woff += (k < w) ? w4[k] : 0u;
  if (tid < NSCB) boff[tid] = woff + x - v;
  if (tid == 255) row_ptr[NN] = woff + x;
}
__global__ __launch_bounds__(256) void k_sc3(const unsigned* __restrict__ cnt,
                                             const unsigned* __restrict__ boff,
                                             unsigned* __restrict__ row_ptr) {
  int b = blockIdx.x, tid = threadIdx.x, lane = tid & 63, w = tid >> 6;
  int i = b * 256 + tid;
  unsigned v = (i < NN) ? cnt[i] : 0u;
  unsigned x = v;
  #pragma unroll
  for (int off = 1; off < 64; off <<= 1) {
    unsigned y = __shfl_up(x, off);
    if (lane >= off) x += y;
  }
  __shared__ unsigned w4[4];
  if (lane == 63) w4[w] = x;
  __syncthreads();
  unsigned woff = 0;
  #pragma unroll
  for (int k = 0; k < 4; ++k) woff += (k < w) ? w4[k] : 0u;
  if (i < NN) row_ptr[i] = boff[b] + woff + x - v;
}

// ---- CSR fill: place {src, raw ew0..2}; normalization deferred ----
__global__ void k_fill(const void* ei, const int* __restrict__ flags,
                       const unsigned* __restrict__ row_ptr, const void* aew,
                       unsigned* __restrict__ fill,
                       int* __restrict__ csr_s, float4* __restrict__ csr_w) {
  int e = blockIdx.x * 256 + threadIdx.x;
  if (e >= NE) return;
  int f32 = flags[0], i64 = flags[1];
  int s = ld_src(ei, e, i64);
  int d = ld_dst(ei, e, i64);
  unsigned pos = row_ptr[d] + atomicAdd(&fill[d], 1u);
  csr_s[pos] = s;
  csr_w[pos] = make_float4(ldf(aew, e, f32),
                           ldf(aew, (size_t)NE + e, f32),
                           ldf(aew, (size_t)2 * NE + e, f32), 0.f);
}

// ---- per-node degree sums from CSR rows (atomic-free, coalesced) ----
__global__ __launch_bounds__(256) void k_degsum(const unsigned* __restrict__ row_ptr,
                                                const float4* __restrict__ csr_w,
                                                float* __restrict__ deg) {
  int tid = threadIdx.x, wid = tid >> 6, lane = tid & 63;
  int node = blockIdx.x * 16 + wid * 4 + (lane >> 4);  // NN%16==0
  int sl = lane & 15;
  unsigned beg = row_ptr[node], end = row_ptr[node + 1];
  float s0 = 0.f, s1 = 0.f, s2 = 0.f;
  for (unsigned p = beg + sl; p < end; p += 16) {
    float4 w = csr_w[p];
    s0 += w.x; s1 += w.y; s2 += w.z;
  }
  #pragma unroll
  for (int off = 1; off < 16; off <<= 1) {
    s0 += __shfl_xor(s0, off);
    s1 += __shfl_xor(s1, off);
    s2 += __shfl_xor(s2, off);
  }
  if (sl == 0) {
    deg[node] = s0; deg[NN + node] = s1; deg[2 * NN + node] = s2;
  }
}

__global__ void k_dis(float* __restrict__ deg, const unsigned* __restrict__ cnt,
                      float* __restrict__ dis2) {
  int i = blockIdx.x * 256 + threadIdx.x;
  if (i < 3 * NN) deg[i] = rsqrtf(deg[i] + 1.0f);
  if (i < NN) dis2[i] = rsqrtf((float)cnt[i] + 1.0f);
}

// ---- normalize CSR weights in place: w_g *= dis_g[src]; .w = dis2[src] ----
__global__ void k_norm(const int* __restrict__ csr_s, const float* __restrict__ dis,
                       const float* __restrict__ dis2, float4* __restrict__ csr_w) {
  int p = blockIdx.x * 256 + threadIdx.x;
  if (p >= NE) return;
  int s = csr_s[p];
  float4 f = csr_w[p];
  csr_w[p] = make_float4(f.x * dis[s], f.y * dis[NN + s],
                         f.z * dis[2 * NN + s], dis2[s]);
}

// ---- h1 = x @ W1: 16 rows/block, k-interleaved 4-way, W1 staged once ----
#define H1_ROWS 16
__global__ __launch_bounds__(256) void k_h1v(const void* x, const void* W1,
                                             const int* __restrict__ flags,
                                             float* __restrict__ h1) {
  __shared__ u16 W1L[256 * 68];   // [k][j], stride 68 shorts
  __shared__ float xL[4][256];    // one row per wave (wave-private)
  int tid = threadIdx.x, f32 = flags[0];
  for (int i = tid; i < 256 * 64; i += 256) {
    int k = i >> 6, j = i & 63;
    W1L[k * 68 + j] = f32 ? f2bf(((const float*)W1)[i]) : ((const u16*)W1)[i];
  }
  __syncthreads();
  int wid = tid >> 6, lane = tid & 63;
  int rg = lane >> 4, dq = lane & 15;
  int rowbase = blockIdx.x * H1_ROWS;
  #pragma unroll 1
  for (int rr = 0; rr < H1_ROWS / 4; ++rr) {
    int n = rowbase + rr * 4 + wid;
    if (n < NN) {
      if (f32) {
        float4 xv = *(const float4*)((const float*)x + (size_t)n * 256 + lane * 4);
        *(float4*)&xL[wid][lane * 4] = xv;
      } else {
        ushort4 xv = *(const ushort4*)((const u16*)x + (size_t)n * 256 + lane * 4);
        *(float4*)&xL[wid][lane * 4] =
            make_float4(bf2f(xv.x), bf2f(xv.y), bf2f(xv.z), bf2f(xv.w));
      }
    } else {
      *(float4*)&xL[wid][lane * 4] = make_float4(0.f, 0.f, 0.f, 0.f);
    }
    float acc0 = 0.f, acc1 = 0.f, acc2 = 0.f, acc3 = 0.f;
    #pragma unroll 8
    for (int kk = 0; kk < 64; ++kk) {
      int k = kk * 4 + rg;
      float xk = xL[wid][k];
      ushort4 wv = *(const ushort4*)&W1L[k * 68 + dq * 4];
      acc0 += xk * bf2f(wv.x); acc1 += xk * bf2f(wv.y);
      acc2 += xk * bf2f(wv.z); acc3 += xk * bf2f(wv.w);
    }
    acc0 += __shfl_xor(acc0, 16); acc0 += __shfl_xor(acc0, 32);
    acc1 += __shfl_xor(acc1, 16); acc1 += __shfl_xor(acc1, 32);
    acc2 += __shfl_xor(acc2, 16); acc2 += __shfl_xor(acc2, 32);
    acc3 += __shfl_xor(acc3, 16); acc3 += __shfl_xor(acc3, 32);
    if (rg == 0 && n < NN)
      *(float4*)&h1[(size_t)n * 64 + dq * 4] = make_float4(acc0, acc1, acc2, acc3);
  }
}

// ---- gather layer1 only (3 graphs), max occupancy ----
__global__ __launch_bounds__(256) void k_gath1(
    const float* __restrict__ h1, const int* __restrict__ csr_s,
    const float4* __restrict__ csr_w, const unsigned* __restrict__ row_ptr,
    const float* __restrict__ deg_dis, const void* b1,
    const int* __restrict__ flags, float* __restrict__ dout) {
  __shared__ float4 eWL[4][64];  // 4 KB per-wave edge staging
  __shared__ float b1L[64];
  int tid = threadIdx.x, f32 = flags[0];
  if (tid < 64) b1L[tid] = ldf(b1, tid, f32);
  __syncthreads();
  int wid = tid >> 6, lane = tid & 63;
  int n = blockIdx.x * 4 + wid;
  if (n >= NN) return;

  float dd0 = deg_dis[n], dd1 = deg_dis[NN + n], dd2 = deg_dis[2 * NN + n];
  float a0[4] = {0,0,0,0}, a1[4] = {0,0,0,0}, a2[4] = {0,0,0,0};
  int g = lane >> 4, dq = lane & 15;
  unsigned beg = row_ptr[n], end = row_ptr[n + 1];
  for (unsigned base = beg; base < end; base += 64) {
    unsigned rem = end - base;
    int m = (rem > 64u) ? 64 : (int)rem;
    float4 st = make_float4(0.f, 0.f, 0.f, __int_as_float(0));
    if (lane < m) {
      float4 cw = csr_w[base + lane];
      int s = csr_s[base + lane];
      st = make_float4(cw.x * dd0, cw.y * dd1, cw.z * dd2, __int_as_float(s));
    }
    eWL[wid][lane] = st;   // wave-private row; same-wave LDS ops are in-order
    int jmax = (m + 3) >> 2;
    for (int j = 0; j < jmax; ++j) {
      float4 e = eWL[wid][j * 4 + g];
      int sj = __float_as_int(e.w);
      float4 hr = *(const float4*)&h1[(size_t)sj * 64 + dq * 4];
      a0[0] += e.x * hr.x; a0[1] += e.x * hr.y; a0[2] += e.x * hr.z; a0[3] += e.x * hr.w;
      a1[0] += e.y * hr.x; a1[1] += e.y * hr.y; a1[2] += e.y * hr.z; a1[3] += e.y * hr.w;
      a2[0] += e.z * hr.x; a2[1] += e.z * hr.y; a2[2] += e.z * hr.z; a2[3] += e.z * hr.w;
    }
  }
  #pragma unroll
  for (int c = 0; c < 4; ++c) {
    a0[c] += __shfl_xor(a0[c], 16); a0[c] += __shfl_xor(a0[c], 32);
    a1[c] += __shfl_xor(a1[c], 16); a1[c] += __shfl_xor(a1[c], 32);
    a2[c] += __shfl_xor(a2[c], 16); a2[c] += __shfl_xor(a2[c], 32);
  }
  // redistribute to lane=dim layout
  int srcl = lane >> 2, cc = lane & 3;
  float t0, t1, t2, t3, r0, r1, r2;
  t0 = __shfl(a0[0], srcl); t1 = __shfl(a0[1], srcl);
  t2 = __shfl(a0[2], srcl); t3 = __shfl(a0[3], srcl);
  r0 = cc == 0 ? t0 : cc == 1 ? t1 : cc == 2 ? t2 : t3;
  t0 = __shfl(a1[0], srcl); t1 = __shfl(a1[1], srcl);
  t2 = __shfl(a1[2], srcl); t3 = __shfl(a1[3], srcl);
  r1 = cc == 0 ? t0 : cc == 1 ? t1 : cc == 2 ? t2 : t3;
  t0 = __shfl(a2[0], srcl); t1 = __shfl(a2[1], srcl);
  t2 = __shfl(a2[2], srcl); t3 = __shfl(a2[3], srcl);
  r2 = cc == 0 ? t0 : cc == 1 ? t1 : cc == 2 ? t2 : t3;

  float selfv = h1[(size_t)n * 64 + lane];
  float b1v = b1L[lane];
  dout[OFF_HID + ((size_t)0 * NN + n) * 64 + lane] = fmaxf(r0 + dd0 * dd0 * selfv + b1v, 0.f);
  dout[OFF_HID + ((size_t)1 * NN + n) * 64 + lane] = fmaxf(r1 + dd1 * dd1 * selfv + b1v, 0.f);
  dout[OFF_HID + ((size_t)2 * NN + n) * 64 + lane] = fmaxf(r2 + dd2 * dd2 * selfv + b1v, 0.f);
}

// ---- dense attention: 16 nodes/block, node-per-lane-group, no reductions ----
#define WFS 66   // Wf LDS row stride in shorts
#define AT_ROWS 16
#define HS 68    // hid LDS row stride in floats
__global__ __launch_bounds__(256) void k_attn(
    const void* Wf, const void* bfv, const void* qf,
    const int* __restrict__ flags, float* __restrict__ dout) {
  __shared__ u16 WfL[3 * 64 * WFS];
  __shared__ float hidL[3][AT_ROWS][HS];
  __shared__ float qfL[192], bfL[192];
  int tid = threadIdx.x, f32 = flags[0];
  int n0 = blockIdx.x * AT_ROWS;
  for (int i = tid; i < 3 * 64 * 64; i += 256) {
    int gi = i >> 12, rem = i & 4095, k = rem >> 6, j = rem & 63;
    WfL[gi * 64 * WFS + k * WFS + j] =
        f32 ? f2bf(((const float*)Wf)[i]) : ((const u16*)Wf)[i];
  }
  for (int i = tid; i < 3 * AT_ROWS * 64; i += 256) {
    int gi = i >> 10, rem = i & 1023, node = rem >> 6, k = rem & 63;
    hidL[gi][node][k] = dout[OFF_HID + ((size_t)gi * NN + (n0 + node)) * 64 + k];
  }
  if (tid < 192) { qfL[tid] = ldf(qf, tid, f32); bfL[tid] = ldf(bfv, tid, f32); }
  __syncthreads();
  int wid = tid >> 6, lane = tid & 63;
  int ng = lane >> 4, dq = lane & 15;
  int node = wid * 4 + ng;
  int n = n0 + node;

  float u0[4] = {0,0,0,0}, u1[4] = {0,0,0,0}, u2[4] = {0,0,0,0};
  #pragma unroll 8
  for (int k = 0; k < 64; ++k) {
    ushort4 w0v = *(const ushort4*)&WfL[k * WFS + dq * 4];
    ushort4 w1v = *(const ushort4*)&WfL[64 * WFS + k * WFS + dq * 4];
    ushort4 w2v = *(const ushort4*)&WfL[128 * WFS + k * WFS + dq * 4];
    float h0 = hidL[0][node][k], h1b = hidL[1][node][k], h2b = hidL[2][node][k];
    u0[0] += h0 * bf2f(w0v.x); u0[1] += h0 * bf2f(w0v.y);
    u0[2] += h0 * bf2f(w0v.z); u0[3] += h0 * bf2f(w0v.w);
    u1[0] += h1b * bf2f(w1v.x); u1[1] += h1b * bf2f(w1v.y);
    u1[2] += h1b * bf2f(w1v.z); u1[3] += h1b * bf2f(w1v.w);
    u2[0] += h2b * bf2f(w2v.x); u2[1] += h2b * bf2f(w2v.y);
    u2[2] += h2b * bf2f(w2v.z); u2[3] += h2b * bf2f(w2v.w);
  }
  float p0 = 0.f, p1 = 0.f, p2 = 0.f;
  #pragma unroll
  for (int c = 0; c < 4; ++c) {
    int j = dq * 4 + c;
    p0 += tanhf(u0[c] + bfL[j])       * qfL[j];
    p1 += tanhf(u1[c] + bfL[64 + j])  * qfL[64 + j];
    p2 += tanhf(u2[c] + bfL[128 + j]) * qfL[128 + j];
  }
  #pragma unroll
  for (int off = 1; off < 16; off <<= 1) {
    p0 += __shfl_xor(p0, off);
    p1 += __shfl_xor(p1, off);
    p2 += __shfl_xor(p2, off);
  }
  float mx = fmaxf(p0, fmaxf(p1, p2));
  float e0 = expf(p0 - mx), e1 = expf(p1 - mx), e2 = expf(p2 - mx);
  float inv = 1.0f / (e0 + e1 + e2);
  float aw0 = e0 * inv, aw1 = e1 * inv, aw2 = e2 * inv;
  float4 h0v = *(const float4*)&hidL[0][node][dq * 4];
  float4 h1v = *(const float4*)&hidL[1][node][dq * 4];
  float4 h2v = *(const float4*)&hidL[2][node][dq * 4];
  *(float4*)&dout[OFF_FUSED + (size_t)n * 64 + dq * 4] =
      make_float4(aw0 * h0v.x + aw1 * h1v.x + aw2 * h2v.x,
                  aw0 * h0v.y + aw1 * h1v.y + aw2 * h2v.y,
                  aw0 * h0v.z + aw1 * h1v.z + aw2 * h2v.z,
                  aw0 * h0v.w + aw1 * h1v.w + aw2 * h2v.w);
  if (dq < 3) dout[OFF_ATTN + (size_t)n * 3 + dq] =
                  (dq == 0 ? aw0 : (dq == 1 ? aw1 : aw2));
}

// ---- layer2 gather (packed LDS staging): agg = sym-aggregate(fused) ----
__global__ __launch_bounds__(256) void k_agg2(
    const int* __restrict__ csr_s, const float4* __restrict__ csr_w,
    const unsigned* __restrict__ row_ptr, const float* __restrict__ dis2,
    const float* __restrict__ dout, float* __restrict__ agg) {
  __shared__ uint2 eL[4][64];
  const float* fused = dout + OFF_FUSED;
  int tid = threadIdx.x, wid = tid >> 6, lane = tid & 63;
  int n = blockIdx.x * 4 + wid;
  if (n >= NN) return;
  float dd = dis2[n];
  float acc[4] = {0.f, 0.f, 0.f, 0.f};
  int g = lane >> 4, dq = lane & 15;
  unsigned beg = row_ptr[n], end = row_ptr[n + 1];
  for (unsigned base = beg; base < end; base += 64) {
    unsigned rem = end - base;
    int m = (rem > 64u) ? 64 : (int)rem;
    uint2 st = make_uint2(0u, 0u);
    if (lane < m)
      st = make_uint2((unsigned)csr_s[base + lane],
                      __float_as_uint(csr_w[base + lane].w * dd));
    eL[wid][lane] = st;
    int jmax = (m + 3) >> 2;
    for (int j = 0; j < jmax; ++j) {
      uint2 e = eL[wid][j * 4 + g];
      int sj = (int)e.x;
      float wj = __uint_as_float(e.y);
      float4 fr = *(const float4*)&fused[(size_t)sj * 64 + dq * 4];
      acc[0] += wj * fr.x; acc[1] += wj * fr.y;
      acc[2] += wj * fr.z; acc[3] += wj * fr.w;
    }
  }
  #pragma unroll
  for (int c = 0; c < 4; ++c) {
    acc[c] += __shfl_xor(acc[c], 16);
    acc[c] += __shfl_xor(acc[c], 32);
  }
  if (lane < 16) {
    float4 sf = *(const float4*)&fused[(size_t)n * 64 + lane * 4];
    float sw = dd * dd;
    *(float4*)&agg[(size_t)n * 64 + lane * 4] =
        make_float4(acc[0] + sw * sf.x, acc[1] + sw * sf.y,
                    acc[2] + sw * sf.z, acc[3] + sw * sf.w);
  }
}

// ---- emb = relu(agg @ W2 + b2): 16 rows/block, 4 rows/wave in-flight ----
#define E2_ROWS 16
__global__ __launch_bounds__(256) void k_emb2(const float* __restrict__ agg,
                                              const void* W2, const void* b2,
                                              const int* __restrict__ flags,
                                              float* __restrict__ dout) {
  __shared__ u16 W2L[64 * 256];
  __shared__ float agL[E2_ROWS * 64];
  __shared__ float b2L[256];
  int tid = threadIdx.x, f32 = flags[0];
  for (int i = tid; i < 64 * 256; i += 256)
    W2L[i] = f32 ? f2bf(((const float*)W2)[i]) : ((const u16*)W2)[i];
  b2L[tid] = ldf(b2, tid, f32);
  {
    int n0 = blockIdx.x * E2_ROWS;
    *(float4*)&agL[tid * 4] = *(const float4*)&agg[(size_t)n0 * 64 + tid * 4];
  }
  __syncthreads();
  int wid = tid >> 6, lane = tid & 63;
  int n0 = blockIdx.x * E2_ROWS + wid * 4;
  const float* ag = &agL[wid * 4 * 64];
  float b0 = b2L[lane * 4], b1v = b2L[lane * 4 + 1];
  float b2v = b2L[lane * 4 + 2], b3 = b2L[lane * 4 + 3];
  float A0 = b0, A1 = b1v, A2 = b2v, A3 = b3;
  float B0 = b0, B1 = b1v, B2 = b2v, B3 = b3;
  float C0 = b0, C1 = b1v, C2 = b2v, C3 = b3;
  float D0 = b0, D1 = b1v, D2 = b2v, D3 = b3;
  #pragma unroll 8
  for (int k = 0; k < 64; ++k) {
    ushort4 wv = *(const ushort4*)&W2L[k * 256 + lane * 4];
    float w0 = bf2f(wv.x), w1 = bf2f(wv.y), w2 = bf2f(wv.z), w3 = bf2f(wv.w);
    float a = ag[k], b = ag[64 + k], c = ag[128 + k], d = ag[192 + k];
    A0 += a * w0; A1 += a * w1; A2 += a * w2; A3 += a * w3;
    B0 += b * w0; B1 += b * w1; B2 += b * w2; B3 += b * w3;
    C0 += c * w0; C1 += c * w1; C2 += c * w2; C3 += c * w3;
    D0 += d * w0; D1 += d * w1; D2 += d * w2; D3 += d * w3;
  }
  *(float4*)&dout[OFF_EMB + (size_t)(n0 + 0) * 256 + lane * 4] =
      make_float4(fmaxf(A0, 0.f), fmaxf(A1, 0.f), fmaxf(A2, 0.f), fmaxf(A3, 0.f));
  *(float4*)&dout[OFF_EMB + (size_t)(n0 + 1) * 256 + lane * 4] =
      make_float4(fmaxf(B0, 0.f), fmaxf(B1, 0.f), fmaxf(B2, 0.f), fmaxf(B3, 0.f));
  *(float4*)&dout[OFF_EMB + (size_t)(n0 + 2) * 256 + lane * 4] =
      make_float4(fmaxf(C0, 0.f), fmaxf(C1, 0.f), fmaxf(C2, 0.f), fmaxf(C3, 0.f));
  *(float4*)&dout[OFF_EMB + (size_t)(n0 + 3) * 256 + lane * 4] =
      make_float4(fmaxf(D0, 0.f), fmaxf(D1, 0.f), fmaxf(D2, 0.f), fmaxf(D3, 0.f));
}

// ---- vsum = graph_neigh @ fused (LDS gn tiles) + fused row sums ----
__global__ __launch_bounds__(256) void k_vsum(const void* gn,
                                              const float* __restrict__ dout,
                                              const int* __restrict__ flags,
                                              float* __restrict__ part,
                                              float* __restrict__ rspart) {
  __shared__ float gnL[8][1024];
  const float* fused = dout + OFF_FUSED;
  int tid = threadIdx.x, wid = tid >> 6, lane = tid & 63;
  int f32 = flags[0];
  int ks = blockIdx.x, bg = blockIdx.y;
  int nbase = ks * 1024;
  #pragma unroll
  for (int r = 0; r < 8; ++r) {
    #pragma unroll
    for (int i = 0; i < 4; ++i) {
      int colv = i * 256 + tid;
      int nn = nbase + colv;
      gnL[r][colv] = (nn < NN) ? ldf(gn, (size_t)(bg * 8 + r) * NN + nn, f32) : 0.f;
    }
  }
  __syncthreads();
  #pragma unroll
  for (int rr = 0; rr < 2; ++rr) {
    int r = wid * 2 + rr;
    float s = 0.f;
    #pragma unroll
    for (int i = 0; i < 16; ++i) s += gnL[r][i * 64 + lane];
    #pragma unroll
    for (int off = 32; off > 0; off >>= 1) s += __shfl_down(s, off);
    if (lane == 0) rspart[(size_t)ks * 256 + bg * 8 + r] = s;
  }
  int g = lane >> 4, dq = lane & 15;
  float acc[8][4];
  #pragma unroll
  for (int r = 0; r < 8; ++r)
    #pragma unroll
    for (int c = 0; c < 4; ++c) acc[r][c] = 0.f;
  for (int i = 0; i < 64; ++i) {
    int nloc = wid * 256 + i * 4 + g;
    int nn = nbase + nloc;
    float4 fr = (nn < NN) ? *(const float4*)&fused[(size_t)nn * 64 + dq * 4]
                          : make_float4(0.f, 0.f, 0.f, 0.f);
    #pragma unroll
    for (int r = 0; r < 8; ++r) {
      float gv = gnL[r][nloc];
      acc[r][0] += gv * fr.x; acc[r][1] += gv * fr.y;
      acc[r][2] += gv * fr.z; acc[r][3] += gv * fr.w;
    }
  }
  #pragma unroll
  for (int r = 0; r < 8; ++r)
    #pragma unroll
    for (int c = 0; c < 4; ++c) {
      acc[r][c] += __shfl_xor(acc[r][c], 16);
      acc[r][c] += __shfl_xor(acc[r][c], 32);
    }
  if (lane < 16) {
    int slice = ks * 4 + wid;
    #pragma unroll
    for (int r = 0; r < 8; ++r)
      *(float4*)&part[((size_t)slice * 256 + bg * 8 + r) * 64 + lane * 4] =
          make_float4(acc[r][0], acc[r][1], acc[r][2], acc[r][3]);
  }
}

// ---- g finalize: reduce partials, divide by row_sum, L2 normalize ----
__global__ __launch_bounds__(64) void k_gfinal(const float* __restrict__ part,
                                               const float* __restrict__ rspart,
                                               float* __restrict__ dout) {
  int b = blockIdx.x, j = threadIdx.x;
  float acc = 0.f;
  for (int k = 0; k < VS_SL; ++k) acc += part[((size_t)k * 256 + b) * 64 + j];
  float rs = 0.f;
  for (int k = 0; k < VS_NC; ++k) rs += rspart[(size_t)k * 256 + b];
  float v = acc / rs;
  float sq = v * v;
  #pragma unroll
  for (int off = 32; off > 0; off >>= 1) sq += __shfl_xor(sq, off);
  float nrm = sqrtf(sq);
  dout[OFF_G + (size_t)b * 64 + j] = v / fmaxf(nrm, 1e-12f);
}

extern "C" void kernel_launch(void* const* d_in, const int* in_sizes, int n_in,
                              void* d_out, int out_size, void* d_ws, size_t ws_size,
                              hipStream_t stream) {
  const void* x   = d_in[0];
  const void* ei  = d_in[1];
  const void* gn  = d_in[2];
  const void* aew = d_in[3];
  const void* W1  = d_in[4];
  const void* b1  = d_in[5];
  const void* W2  = d_in[6];
  const void* b2  = d_in[7];
  const void* Wf  = d_in[8];
  const void* bfv = d_in[9];
  const void* qf  = d_in[10];

  char* ws = (char*)d_ws;
  size_t off = 0;
  auto alloc = [&](size_t bytes) -> void* {
    void* p = ws + off;
    off += (bytes + 255) & ~(size_t)255;
    return p;
  };
  // zero-init region (atomically accumulated buffers only)
  unsigned* cnt     = (unsigned*)alloc((size_t)NN * 4);
  unsigned* fill    = (unsigned*)alloc((size_t)NN * 4);
  size_t zero_bytes = off;
  float*    deg     = (float*)alloc((size_t)3 * NN * 4);
  int*      flags   = (int*)alloc(64);
  float*    dis2    = (float*)alloc((size_t)NN * 4);
  unsigned* row_ptr = (unsigned*)alloc((size_t)(NN + 1) * 4);
  unsigned* bsum    = (unsigned*)alloc((size_t)NSCB * 4);
  unsigned* boff    = (unsigned*)alloc((size_t)NSCB * 4);
  int*      csr_s   = (int*)alloc((size_t)NE * 4);
  float4*   csr_w   = (float4*)alloc((size_t)NE * 16);
  // time-shared region: h1 (k_h1v->k_gath1), agg (k_agg2->k_emb2), part (k_vsum->k_gfinal)
  size_t regA_bytes = (size_t)VS_SL * NB * 64 * 4;
  char*  regA       = (char*)alloc(regA_bytes);
  float* h1   = (float*)regA;
  float* agg  = (float*)regA;
  float* part = (float*)regA;
  float* rspart = (float*)alloc((size_t)VS_NC * NB * 4);

  float* dout = (float*)d_out;

  hipMemsetAsync(d_ws, 0, zero_bytes, stream);
  k_detect<<<1, 64, 0, stream>>>(x, ei, flags);
  k_cnt<<<(NE + 255) / 256, 256, 0, stream>>>(ei, flags, cnt);
  k_sc1<<<NSCB, 256, 0, stream>>>(cnt, bsum);
  k_sc2<<<1, 256, 0, stream>>>(bsum, boff, row_ptr);
  k_sc3<<<NSCB, 256, 0, stream>>>(cnt, boff, row_ptr);
  k_fill<<<(NE + 255) / 256, 256, 0, stream>>>(ei, flags, row_ptr, aew, fill,
                                               csr_s, csr_w);
  k_degsum<<<NN / 16, 256, 0, stream>>>(row_ptr, csr_w, deg);
  k_dis<<<(3 * NN + 255) / 256, 256, 0, stream>>>(deg, cnt, dis2);
  k_norm<<<(NE + 255) / 256, 256, 0, stream>>>(csr_s, deg, dis2, csr_w);
  k_h1v<<<(NN + H1_ROWS - 1) / H1_ROWS, 256, 0, stream>>>(x, W1, flags, h1);
  k_gath1<<<(NN + 3) / 4, 256, 0, stream>>>(h1, csr_s, csr_w, row_ptr, deg, b1,
                                            flags, dout);
  k_attn<<<NN / AT_ROWS, 256, 0, stream>>>(Wf, bfv, qf, flags, dout);
  k_agg2<<<(NN + 3) / 4, 256, 0, stream>>>(csr_s, csr_w, row_ptr, dis2, dout, agg);
  k_emb2<<<NN / E2_ROWS, 256, 0, stream>>>(agg, W2, b2, flags, dout);
  {
    dim3 gdim(VS_NC, 32);
    k_vsum<<<gdim, 256, 0, stream>>>(gn, dout, flags, part, rspart);
  }
  k_gfinal<<<NB, 64, 0, stream>>>(part, rspart, dout);
}

// Round 14
// 443.282 us; speedup vs baseline: 6.4652x; 1.1893x over previous
//
#include <hip/hip_runtime.h>
#include <hip/hip_bf16.h>

#define NN 50000
#define NE 800000
#define NG 3
#define NB 256
#define NSCB 196  // ceil(NN/256)

#define OFF_FUSED ((size_t)0)
#define OFF_EMB   ((size_t)NN * 64)
#define OFF_G     (OFF_EMB + (size_t)NN * 256)
#define OFF_HID   (OFF_G + (size_t)NB * 64)
#define OFF_ATTN  (OFF_HID + (size_t)3 * NN * 64)

// k_vsum geometry: 49 n-chunks of 1024; 32 b-groups of 8 rows; slice = ks*4+wave
#define VS_NC 49
#define VS_SL (VS_NC * 4)

typedef unsigned short u16;
typedef __attribute__((ext_vector_type(8))) short short8;
typedef __attribute__((ext_vector_type(4))) float floatx4;

__device__ __forceinline__ float bf2f(u16 u) {
  union { unsigned int i; float f; } v; v.i = ((unsigned int)u) << 16; return v.f;
}
__device__ __forceinline__ u16 f2bf(float f) {
  unsigned int x = __float_as_uint(f);
  unsigned int r = (x + 0x7FFFu + ((x >> 16) & 1u)) >> 16;
  return (u16)r;
}
__device__ __forceinline__ float ldf(const void* p, size_t i, int f32) {
  return f32 ? ((const float*)p)[i] : bf2f(((const u16*)p)[i]);
}
__device__ __forceinline__ int ld_src(const void* ei, int e, int i64) {
  return i64 ? (int)((const long long*)ei)[e] : ((const int*)ei)[e];
}
__device__ __forceinline__ int ld_dst(const void* ei, int e, int i64) {
  return i64 ? (int)((const long long*)ei)[(size_t)NE + e] : ((const int*)ei)[(size_t)NE + e];
}

// ---- dtype detection ----
__global__ void k_detect(const void* x, const void* ei, int* flags) {
  if (threadIdx.x != 0 || blockIdx.x != 0) return;
  const u16* xw = (const u16*)x;
  int sane = 0;
  for (int i = 0; i < 64; ++i) {
    unsigned ex = (xw[2 * i] >> 7) & 0xFF;
    sane += (ex >= 96 && ex <= 141);
  }
  flags[0] = (sane < 48) ? 1 : 0;  // 1 => inputs are float32
  const int* e32 = (const int*)ei;
  int zeros = 0;
  for (int t = 1; t < 32; t += 2) zeros += (e32[t] == 0);
  flags[1] = (zeros >= 12) ? 1 : 0;  // 1 => edge_index is int64
}

// ---- edge count histogram ----
__global__ void k_cnt(const void* ei, const int* __restrict__ flags,
                      unsigned* __restrict__ cnt) {
  int e = blockIdx.x * 256 + threadIdx.x;
  if (e >= NE) return;
  atomicAdd(&cnt[ld_dst(ei, e, flags[1])], 1u);
}

// ---- 3-phase exclusive scan of cnt -> row_ptr ----
__global__ __launch_bounds__(256) void k_sc1(const unsigned* __restrict__ cnt,
                                             unsigned* __restrict__ bsum) {
  int b = blockIdx.x, tid = threadIdx.x, i = b * 256 + tid;
  unsigned v = (i < NN) ? cnt[i] : 0u;
  #pragma unroll
  for (int off = 32; off > 0; off >>= 1) v += __shfl_down(v, off);
  __shared__ unsigned w4[4];
  if ((tid & 63) == 0) w4[tid >> 6] = v;
  __syncthreads();
  if (tid == 0) bsum[b] = w4[0] + w4[1] + w4[2] + w4[3];
}
__global__ __launch_bounds__(256) void k_sc2(const unsigned* __restrict__ bsum,
                                             unsigned* __restrict__ boff,
                                             unsigned* __restrict__ row_ptr) {
  int tid = threadIdx.x, lane = tid & 63, w = tid >> 6;
  unsigned v = (tid < NSCB) ? bsum[tid] : 0u;
  unsigned x = v;
  #pragma unroll
  for (int off = 1; off < 64; off <<= 1) {
    unsigned y = __shfl_up(x, off);
    if (lane >= off) x += y;
  }
  __shared__ unsigned w4[4];
  if (lane == 63) w4[w] = x;
  __syncthreads();
  unsigned woff = 0;
  #pragma unroll
  for (int k = 0; k < 4; ++k) woff += (k < w) ? w4[k] : 0u;
  if (tid < NSCB) boff[tid] = woff + x - v;
  if (tid == 255) row_ptr[NN] = woff + x;
}
__global__ __launch_bounds__(256) void k_sc3(const unsigned* __restrict__ cnt,
                                             const unsigned* __restrict__ boff,
                                             unsigned* __restrict__ row_ptr) {
  int b = blockIdx.x, tid = threadIdx.x, lane = tid & 63, w = tid >> 6;
  int i = b * 256 + tid;
  unsigned v = (i < NN) ? cnt[i] : 0u;
  unsigned x = v;
  #pragma unroll
  for (int off = 1; off < 64; off <<= 1) {
    unsigned y = __shfl_up(x, off);
    if (lane >= off) x += y;
  }
  __shared__ unsigned w4[4];
  if (lane == 63) w4[w] = x;
  __syncthreads();
  unsigned woff = 0;
  #pragma unroll
  for (int k = 0; k < 4; ++k) woff += (k < w) ? w4[k] : 0u;
  if (i < NN) row_ptr[i] = boff[b] + woff + x - v;
}

// ---- CSR fill: place {src, raw ew0..2}; normalization deferred ----
__global__ void k_fill(const void* ei, const int* __restrict__ flags,
                       const unsigned* __restrict__ row_ptr, const void* aew,
                       unsigned* __restrict__ fill,
                       int* __restrict__ csr_s, float4* __restrict__ csr_w) {
  int e = blockIdx.x * 256 + threadIdx.x;
  if (e >= NE) return;
  int f32 = flags[0], i64 = flags[1];
  int s = ld_src(ei, e, i64);
  int d = ld_dst(ei, e, i64);
  unsigned pos = row_ptr[d] + atomicAdd(&fill[d], 1u);
  csr_s[pos] = s;
  csr_w[pos] = make_float4(ldf(aew, e, f32),
                           ldf(aew, (size_t)NE + e, f32),
                           ldf(aew, (size_t)2 * NE + e, f32), 0.f);
}

// ---- per-node degree sums from CSR rows (atomic-free, coalesced) ----
__global__ __launch_bounds__(256) void k_degsum(const unsigned* __restrict__ row_ptr,
                                                const float4* __restrict__ csr_w,
                                                float* __restrict__ deg) {
  int tid = threadIdx.x, wid = tid >> 6, lane = tid & 63;
  int node = blockIdx.x * 16 + wid * 4 + (lane >> 4);  // NN%16==0
  int sl = lane & 15;
  unsigned beg = row_ptr[node], end = row_ptr[node + 1];
  float s0 = 0.f, s1 = 0.f, s2 = 0.f;
  for (unsigned p = beg + sl; p < end; p += 16) {
    float4 w = csr_w[p];
    s0 += w.x; s1 += w.y; s2 += w.z;
  }
  #pragma unroll
  for (int off = 1; off < 16; off <<= 1) {
    s0 += __shfl_xor(s0, off);
    s1 += __shfl_xor(s1, off);
    s2 += __shfl_xor(s2, off);
  }
  if (sl == 0) {
    deg[node] = s0; deg[NN + node] = s1; deg[2 * NN + node] = s2;
  }
}

__global__ void k_dis(float* __restrict__ deg, const unsigned* __restrict__ cnt,
                      float* __restrict__ dis2) {
  int i = blockIdx.x * 256 + threadIdx.x;
  if (i < 3 * NN) deg[i] = rsqrtf(deg[i] + 1.0f);
  if (i < NN) dis2[i] = rsqrtf((float)cnt[i] + 1.0f);
}

// ---- normalize CSR weights in place ----
__global__ void k_norm(const int* __restrict__ csr_s, const float* __restrict__ dis,
                       const float* __restrict__ dis2, float4* __restrict__ csr_w) {
  int p = blockIdx.x * 256 + threadIdx.x;
  if (p >= NE) return;
  int s = csr_s[p];
  float4 f = csr_w[p];
  csr_w[p] = make_float4(f.x * dis[s], f.y * dis[NN + s],
                         f.z * dis[2 * NN + s], dis2[s]);
}

// ---- h1 = x @ W1 via MFMA: 64 rows/block (4 waves x 16), W1^T in LDS ----
__global__ __launch_bounds__(256) void k_h1m(const void* x, const void* W1,
                                             const int* __restrict__ flags,
                                             float* __restrict__ h1) {
  __shared__ short w1t[64 * 264];  // W1^T: [col][k], stride 264 shorts (16B aligned)
  int tid = threadIdx.x, f32 = flags[0];
  for (int i = tid; i < 64 * 256; i += 256) {
    int col = i & 63, k = i >> 6;
    w1t[col * 264 + k] = (short)(f32 ? f2bf(((const float*)W1)[k * 64 + col])
                                     : ((const u16*)W1)[k * 64 + col]);
  }
  __syncthreads();
  int wid = tid >> 6, l = tid & 63;
  int rowbase = blockIdx.x * 64 + wid * 16;
  int arow = rowbase + (l & 15);
  if (arow >= NN) arow = NN - 1;
  int koff = (l >> 4) * 8;
  floatx4 acc[4];
  #pragma unroll
  for (int c = 0; c < 4; ++c) acc[c] = (floatx4){0.f, 0.f, 0.f, 0.f};
  #pragma unroll
  for (int kk = 0; kk < 8; ++kk) {
    int k0 = kk * 32 + koff;
    short8 a;
    if (f32) {
      const float* xp = (const float*)x + (size_t)arow * 256 + k0;
      float4 lo = *(const float4*)xp;
      float4 hi = *(const float4*)(xp + 4);
      a[0] = (short)f2bf(lo.x); a[1] = (short)f2bf(lo.y);
      a[2] = (short)f2bf(lo.z); a[3] = (short)f2bf(lo.w);
      a[4] = (short)f2bf(hi.x); a[5] = (short)f2bf(hi.y);
      a[6] = (short)f2bf(hi.z); a[7] = (short)f2bf(hi.w);
    } else {
      a = *(const short8*)((const u16*)x + (size_t)arow * 256 + k0);
    }
    #pragma unroll
    for (int c = 0; c < 4; ++c) {
      short8 b = *(const short8*)(&w1t[(c * 16 + (l & 15)) * 264 + k0]);
      acc[c] = __builtin_amdgcn_mfma_f32_16x16x32_bf16(a, b, acc[c], 0, 0, 0);
    }
  }
  int r0 = rowbase + (l >> 4) * 4;
  int colb = l & 15;
  #pragma unroll
  for (int c = 0; c < 4; ++c)
    #pragma unroll
    for (int r = 0; r < 4; ++r) {
      int rr = r0 + r;
      if (rr < NN) h1[(size_t)rr * 64 + c * 16 + colb] = acc[c][r];
    }
}

// ---- gather layer1 only (3 graphs), max occupancy ----
__global__ __launch_bounds__(256) void k_gath1(
    const float* __restrict__ h1, const int* __restrict__ csr_s,
    const float4* __restrict__ csr_w, const unsigned* __restrict__ row_ptr,
    const float* __restrict__ deg_dis, const void* b1,
    const int* __restrict__ flags, float* __restrict__ dout) {
  __shared__ float4 eWL[4][64];  // 4 KB per-wave edge staging
  __shared__ float b1L[64];
  int tid = threadIdx.x, f32 = flags[0];
  if (tid < 64) b1L[tid] = ldf(b1, tid, f32);
  __syncthreads();
  int wid = tid >> 6, lane = tid & 63;
  int n = blockIdx.x * 4 + wid;
  if (n >= NN) return;

  float dd0 = deg_dis[n], dd1 = deg_dis[NN + n], dd2 = deg_dis[2 * NN + n];
  float a0[4] = {0,0,0,0}, a1[4] = {0,0,0,0}, a2[4] = {0,0,0,0};
  int g = lane >> 4, dq = lane & 15;
  unsigned beg = row_ptr[n], end = row_ptr[n + 1];
  for (unsigned base = beg; base < end; base += 64) {
    unsigned rem = end - base;
    int m = (rem > 64u) ? 64 : (int)rem;
    float4 st = make_float4(0.f, 0.f, 0.f, __int_as_float(0));
    if (lane < m) {
      float4 cw = csr_w[base + lane];
      int s = csr_s[base + lane];
      st = make_float4(cw.x * dd0, cw.y * dd1, cw.z * dd2, __int_as_float(s));
    }
    eWL[wid][lane] = st;   // wave-private row; same-wave LDS ops are in-order
    int jmax = (m + 3) >> 2;
    for (int j = 0; j < jmax; ++j) {
      float4 e = eWL[wid][j * 4 + g];
      int sj = __float_as_int(e.w);
      float4 hr = *(const float4*)&h1[(size_t)sj * 64 + dq * 4];
      a0[0] += e.x * hr.x; a0[1] += e.x * hr.y; a0[2] += e.x * hr.z; a0[3] += e.x * hr.w;
      a1[0] += e.y * hr.x; a1[1] += e.y * hr.y; a1[2] += e.y * hr.z; a1[3] += e.y * hr.w;
      a2[0] += e.z * hr.x; a2[1] += e.z * hr.y; a2[2] += e.z * hr.z; a2[3] += e.z * hr.w;
    }
  }
  #pragma unroll
  for (int c = 0; c < 4; ++c) {
    a0[c] += __shfl_xor(a0[c], 16); a0[c] += __shfl_xor(a0[c], 32);
    a1[c] += __shfl_xor(a1[c], 16); a1[c] += __shfl_xor(a1[c], 32);
    a2[c] += __shfl_xor(a2[c], 16); a2[c] += __shfl_xor(a2[c], 32);
  }
  // redistribute to lane=dim layout
  int srcl = lane >> 2, cc = lane & 3;
  float t0, t1, t2, t3, r0, r1, r2;
  t0 = __shfl(a0[0], srcl); t1 = __shfl(a0[1], srcl);
  t2 = __shfl(a0[2], srcl); t3 = __shfl(a0[3], srcl);
  r0 = cc == 0 ? t0 : cc == 1 ? t1 : cc == 2 ? t2 : t3;
  t0 = __shfl(a1[0], srcl); t1 = __shfl(a1[1], srcl);
  t2 = __shfl(a1[2], srcl); t3 = __shfl(a1[3], srcl);
  r1 = cc == 0 ? t0 : cc == 1 ? t1 : cc == 2 ? t2 : t3;
  t0 = __shfl(a2[0], srcl); t1 = __shfl(a2[1], srcl);
  t2 = __shfl(a2[2], srcl); t3 = __shfl(a2[3], srcl);
  r2 = cc == 0 ? t0 : cc == 1 ? t1 : cc == 2 ? t2 : t3;

  float selfv = h1[(size_t)n * 64 + lane];
  float b1v = b1L[lane];
  dout[OFF_HID + ((size_t)0 * NN + n) * 64 + lane] = fmaxf(r0 + dd0 * dd0 * selfv + b1v, 0.f);
  dout[OFF_HID + ((size_t)1 * NN + n) * 64 + lane] = fmaxf(r1 + dd1 * dd1 * selfv + b1v, 0.f);
  dout[OFF_HID + ((size_t)2 * NN + n) * 64 + lane] = fmaxf(r2 + dd2 * dd2 * selfv + b1v, 0.f);
}

// ---- dense attention: 16 nodes/block, node-per-lane-group, no reductions ----
#define WFS 66   // Wf LDS row stride in shorts
#define AT_ROWS 16
#define HS 68    // hid LDS row stride in floats
__global__ __launch_bounds__(256) void k_attn(
    const void* Wf, const void* bfv, const void* qf,
    const int* __restrict__ flags, float* __restrict__ dout) {
  __shared__ u16 WfL[3 * 64 * WFS];
  __shared__ float hidL[3][AT_ROWS][HS];
  __shared__ float qfL[192], bfL[192];
  int tid = threadIdx.x, f32 = flags[0];
  int n0 = blockIdx.x * AT_ROWS;
  for (int i = tid; i < 3 * 64 * 64; i += 256) {
    int gi = i >> 12, rem = i & 4095, k = rem >> 6, j = rem & 63;
    WfL[gi * 64 * WFS + k * WFS + j] =
        f32 ? f2bf(((const float*)Wf)[i]) : ((const u16*)Wf)[i];
  }
  for (int i = tid; i < 3 * AT_ROWS * 64; i += 256) {
    int gi = i >> 10, rem = i & 1023, node = rem >> 6, k = rem & 63;
    hidL[gi][node][k] = dout[OFF_HID + ((size_t)gi * NN + (n0 + node)) * 64 + k];
  }
  if (tid < 192) { qfL[tid] = ldf(qf, tid, f32); bfL[tid] = ldf(bfv, tid, f32); }
  __syncthreads();
  int wid = tid >> 6, lane = tid & 63;
  int ng = lane >> 4, dq = lane & 15;
  int node = wid * 4 + ng;
  int n = n0 + node;

  float u0[4] = {0,0,0,0}, u1[4] = {0,0,0,0}, u2[4] = {0,0,0,0};
  #pragma unroll 8
  for (int k = 0; k < 64; ++k) {
    ushort4 w0v = *(const ushort4*)&WfL[k * WFS + dq * 4];
    ushort4 w1v = *(const ushort4*)&WfL[64 * WFS + k * WFS + dq * 4];
    ushort4 w2v = *(const ushort4*)&WfL[128 * WFS + k * WFS + dq * 4];
    float h0 = hidL[0][node][k], h1b = hidL[1][node][k], h2b = hidL[2][node][k];
    u0[0] += h0 * bf2f(w0v.x); u0[1] += h0 * bf2f(w0v.y);
    u0[2] += h0 * bf2f(w0v.z); u0[3] += h0 * bf2f(w0v.w);
    u1[0] += h1b * bf2f(w1v.x); u1[1] += h1b * bf2f(w1v.y);
    u1[2] += h1b * bf2f(w1v.z); u1[3] += h1b * bf2f(w1v.w);
    u2[0] += h2b * bf2f(w2v.x); u2[1] += h2b * bf2f(w2v.y);
    u2[2] += h2b * bf2f(w2v.z); u2[3] += h2b * bf2f(w2v.w);
  }
  float p0 = 0.f, p1 = 0.f, p2 = 0.f;
  #pragma unroll
  for (int c = 0; c < 4; ++c) {
    int j = dq * 4 + c;
    p0 += tanhf(u0[c] + bfL[j])       * qfL[j];
    p1 += tanhf(u1[c] + bfL[64 + j])  * qfL[64 + j];
    p2 += tanhf(u2[c] + bfL[128 + j]) * qfL[128 + j];
  }
  #pragma unroll
  for (int off = 1; off < 16; off <<= 1) {
    p0 += __shfl_xor(p0, off);
    p1 += __shfl_xor(p1, off);
    p2 += __shfl_xor(p2, off);
  }
  float mx = fmaxf(p0, fmaxf(p1, p2));
  float e0 = expf(p0 - mx), e1 = expf(p1 - mx), e2 = expf(p2 - mx);
  float inv = 1.0f / (e0 + e1 + e2);
  float aw0 = e0 * inv, aw1 = e1 * inv, aw2 = e2 * inv;
  float4 h0v = *(const float4*)&hidL[0][node][dq * 4];
  float4 h1v = *(const float4*)&hidL[1][node][dq * 4];
  float4 h2v = *(const float4*)&hidL[2][node][dq * 4];
  *(float4*)&dout[OFF_FUSED + (size_t)n * 64 + dq * 4] =
      make_float4(aw0 * h0v.x + aw1 * h1v.x + aw2 * h2v.x,
                  aw0 * h0v.y + aw1 * h1v.y + aw2 * h2v.y,
                  aw0 * h0v.z + aw1 * h1v.z + aw2 * h2v.z,
                  aw0 * h0v.w + aw1 * h1v.w + aw2 * h2v.w);
  if (dq < 3) dout[OFF_ATTN + (size_t)n * 3 + dq] =
                  (dq == 0 ? aw0 : (dq == 1 ? aw1 : aw2));
}

// ---- layer2 gather (packed LDS staging): agg = sym-aggregate(fused) ----
__global__ __launch_bounds__(256) void k_agg2(
    const int* __restrict__ csr_s, const float4* __restrict__ csr_w,
    const unsigned* __restrict__ row_ptr, const float* __restrict__ dis2,
    const float* __restrict__ dout, float* __restrict__ agg) {
  __shared__ uint2 eL[4][64];
  const float* fused = dout + OFF_FUSED;
  int tid = threadIdx.x, wid = tid >> 6, lane = tid & 63;
  int n = blockIdx.x * 4 + wid;
  if (n >= NN) return;
  float dd = dis2[n];
  float acc[4] = {0.f, 0.f, 0.f, 0.f};
  int g = lane >> 4, dq = lane & 15;
  unsigned beg = row_ptr[n], end = row_ptr[n + 1];
  for (unsigned base = beg; base < end; base += 64) {
    unsigned rem = end - base;
    int m = (rem > 64u) ? 64 : (int)rem;
    uint2 st = make_uint2(0u, 0u);
    if (lane < m)
      st = make_uint2((unsigned)csr_s[base + lane],
                      __float_as_uint(csr_w[base + lane].w * dd));
    eL[wid][lane] = st;
    int jmax = (m + 3) >> 2;
    for (int j = 0; j < jmax; ++j) {
      uint2 e = eL[wid][j * 4 + g];
      int sj = (int)e.x;
      float wj = __uint_as_float(e.y);
      float4 fr = *(const float4*)&fused[(size_t)sj * 64 + dq * 4];
      acc[0] += wj * fr.x; acc[1] += wj * fr.y;
      acc[2] += wj * fr.z; acc[3] += wj * fr.w;
    }
  }
  #pragma unroll
  for (int c = 0; c < 4; ++c) {
    acc[c] += __shfl_xor(acc[c], 16);
    acc[c] += __shfl_xor(acc[c], 32);
  }
  if (lane < 16) {
    float4 sf = *(const float4*)&fused[(size_t)n * 64 + lane * 4];
    float sw = dd * dd;
    *(float4*)&agg[(size_t)n * 64 + lane * 4] =
        make_float4(acc[0] + sw * sf.x, acc[1] + sw * sf.y,
                    acc[2] + sw * sf.z, acc[3] + sw * sf.w);
  }
}

// ---- emb = relu(agg @ W2 + b2) via MFMA: 64 rows/block, W2^T in LDS ----
__global__ __launch_bounds__(256) void k_emb2m(const float* __restrict__ agg,
                                               const void* W2, const void* b2,
                                               const int* __restrict__ flags,
                                               float* __restrict__ dout) {
  __shared__ short w2t[256 * 72];  // W2^T: [col][k], stride 72 shorts (16B aligned)
  __shared__ float b2L[256];
  int tid = threadIdx.x, f32 = flags[0];
  for (int i = tid; i < 256 * 64; i += 256) {
    int col = i & 255, k = i >> 8;
    w2t[col * 72 + k] = (short)(f32 ? f2bf(((const float*)W2)[k * 256 + col])
                                    : ((const u16*)W2)[k * 256 + col]);
  }
  b2L[tid] = ldf(b2, tid, f32);
  __syncthreads();
  int wid = tid >> 6, l = tid & 63;
  int rowbase = blockIdx.x * 64 + wid * 16;
  int arow = rowbase + (l & 15);
  if (arow >= NN) arow = NN - 1;
  int koff = (l >> 4) * 8;
  floatx4 acc[16];
  #pragma unroll
  for (int c = 0; c < 16; ++c) acc[c] = (floatx4){0.f, 0.f, 0.f, 0.f};
  #pragma unroll
  for (int kk = 0; kk < 2; ++kk) {
    int k0 = kk * 32 + koff;
    const float* ap = agg + (size_t)arow * 64 + k0;
    float4 lo = *(const float4*)ap;
    float4 hi = *(const float4*)(ap + 4);
    short8 a;
    a[0] = (short)f2bf(lo.x); a[1] = (short)f2bf(lo.y);
    a[2] = (short)f2bf(lo.z); a[3] = (short)f2bf(lo.w);
    a[4] = (short)f2bf(hi.x); a[5] = (short)f2bf(hi.y);
    a[6] = (short)f2bf(hi.z); a[7] = (short)f2bf(hi.w);
    #pragma unroll
    for (int c = 0; c < 16; ++c) {
      short8 b = *(const short8*)(&w2t[(c * 16 + (l & 15)) * 72 + k0]);
      acc[c] = __builtin_amdgcn_mfma_f32_16x16x32_bf16(a, b, acc[c], 0, 0, 0);
    }
  }
  int r0 = rowbase + (l >> 4) * 4;
  int colb = l & 15;
  #pragma unroll
  for (int c = 0; c < 16; ++c) {
    float bb = b2L[c * 16 + colb];
    #pragma unroll
    for (int r = 0; r < 4; ++r) {
      int rr = r0 + r;
      if (rr < NN)
        dout[OFF_EMB + (size_t)rr * 256 + c * 16 + colb] = fmaxf(acc[c][r] + bb, 0.f);
    }
  }
}

// ---- vsum = graph_neigh @ fused (LDS gn tiles) + fused row sums ----
__global__ __launch_bounds__(256) void k_vsum(const void* gn,
                                              const float* __restrict__ dout,
                                              const int* __restrict__ flags,
                                              float* __restrict__ part,
                                              float* __restrict__ rspart) {
  __shared__ float gnL[8][1024];
  const float* fused = dout + OFF_FUSED;
  int tid = threadIdx.x, wid = tid >> 6, lane = tid & 63;
  int f32 = flags[0];
  int ks = blockIdx.x, bg = blockIdx.y;
  int nbase = ks * 1024;
  #pragma unroll
  for (int r = 0; r < 8; ++r) {
    #pragma unroll
    for (int i = 0; i < 4; ++i) {
      int colv = i * 256 + tid;
      int nn = nbase + colv;
      gnL[r][colv] = (nn < NN) ? ldf(gn, (size_t)(bg * 8 + r) * NN + nn, f32) : 0.f;
    }
  }
  __syncthreads();
  #pragma unroll
  for (int rr = 0; rr < 2; ++rr) {
    int r = wid * 2 + rr;
    float s = 0.f;
    #pragma unroll
    for (int i = 0; i < 16; ++i) s += gnL[r][i * 64 + lane];
    #pragma unroll
    for (int off = 32; off > 0; off >>= 1) s += __shfl_down(s, off);
    if (lane == 0) rspart[(size_t)ks * 256 + bg * 8 + r] = s;
  }
  int g = lane >> 4, dq = lane & 15;
  float acc[8][4];
  #pragma unroll
  for (int r = 0; r < 8; ++r)
    #pragma unroll
    for (int c = 0; c < 4; ++c) acc[r][c] = 0.f;
  for (int i = 0; i < 64; ++i) {
    int nloc = wid * 256 + i * 4 + g;
    int nn = nbase + nloc;
    float4 fr = (nn < NN) ? *(const float4*)&fused[(size_t)nn * 64 + dq * 4]
                          : make_float4(0.f, 0.f, 0.f, 0.f);
    #pragma unroll
    for (int r = 0; r < 8; ++r) {
      float gv = gnL[r][nloc];
      acc[r][0] += gv * fr.x; acc[r][1] += gv * fr.y;
      acc[r][2] += gv * fr.z; acc[r][3] += gv * fr.w;
    }
  }
  #pragma unroll
  for (int r = 0; r < 8; ++r)
    #pragma unroll
    for (int c = 0; c < 4; ++c) {
      acc[r][c] += __shfl_xor(acc[r][c], 16);
      acc[r][c] += __shfl_xor(acc[r][c], 32);
    }
  if (lane < 16) {
    int slice = ks * 4 + wid;
    #pragma unroll
    for (int r = 0; r < 8; ++r)
      *(float4*)&part[((size_t)slice * 256 + bg * 8 + r) * 64 + lane * 4] =
          make_float4(acc[r][0], acc[r][1], acc[r][2], acc[r][3]);
  }
}

// ---- g finalize: reduce partials, divide by row_sum, L2 normalize ----
__global__ __launch_bounds__(64) void k_gfinal(const float* __restrict__ part,
                                               const float* __restrict__ rspart,
                                               float* __restrict__ dout) {
  int b = blockIdx.x, j = threadIdx.x;
  float acc = 0.f;
  for (int k = 0; k < VS_SL; ++k) acc += part[((size_t)k * 256 + b) * 64 + j];
  float rs = 0.f;
  for (int k = 0; k < VS_NC; ++k) rs += rspart[(size_t)k * 256 + b];
  float v = acc / rs;
  float sq = v * v;
  #pragma unroll
  for (int off = 32; off > 0; off >>= 1) sq += __shfl_xor(sq, off);
  float nrm = sqrtf(sq);
  dout[OFF_G + (size_t)b * 64 + j] = v / fmaxf(nrm, 1e-12f);
}

extern "C" void kernel_launch(void* const* d_in, const int* in_sizes, int n_in,
                              void* d_out, int out_size, void* d_ws, size_t ws_size,
                              hipStream_t stream) {
  const void* x   = d_in[0];
  const void* ei  = d_in[1];
  const void* gn  = d_in[2];
  const void* aew = d_in[3];
  const void* W1  = d_in[4];
  const void* b1  = d_in[5];
  const void* W2  = d_in[6];
  const void* b2  = d_in[7];
  const void* Wf  = d_in[8];
  const void* bfv = d_in[9];
  const void* qf  = d_in[10];

  char* ws = (char*)d_ws;
  size_t off = 0;
  auto alloc = [&](size_t bytes) -> void* {
    void* p = ws + off;
    off += (bytes + 255) & ~(size_t)255;
    return p;
  };
  // zero-init region (atomically accumulated buffers only)
  unsigned* cnt     = (unsigned*)alloc((size_t)NN * 4);
  unsigned* fill    = (unsigned*)alloc((size_t)NN * 4);
  size_t zero_bytes = off;
  float*    deg     = (float*)alloc((size_t)3 * NN * 4);
  int*      flags   = (int*)alloc(64);
  float*    dis2    = (float*)alloc((size_t)NN * 4);
  unsigned* row_ptr = (unsigned*)alloc((size_t)(NN + 1) * 4);
  unsigned* bsum    = (unsigned*)alloc((size_t)NSCB * 4);
  unsigned* boff    = (unsigned*)alloc((size_t)NSCB * 4);
  int*      csr_s   = (int*)alloc((size_t)NE * 4);
  float4*   csr_w   = (float4*)alloc((size_t)NE * 16);
  // time-shared region: h1 (k_h1m->k_gath1), agg (k_agg2->k_emb2m), part (k_vsum->k_gfinal)
  size_t regA_bytes = (size_t)VS_SL * NB * 64 * 4;
  char*  regA       = (char*)alloc(regA_bytes);
  float* h1   = (float*)regA;
  float* agg  = (float*)regA;
  float* part = (float*)regA;
  float* rspart = (float*)alloc((size_t)VS_NC * NB * 4);

  float* dout = (float*)d_out;

  hipMemsetAsync(d_ws, 0, zero_bytes, stream);
  k_detect<<<1, 64, 0, stream>>>(x, ei, flags);
  k_cnt<<<(NE + 255) / 256, 256, 0, stream>>>(ei, flags, cnt);
  k_sc1<<<NSCB, 256, 0, stream>>>(cnt, bsum);
  k_sc2<<<1, 256, 0, stream>>>(bsum, boff, row_ptr);
  k_sc3<<<NSCB, 256, 0, stream>>>(cnt, boff, row_ptr);
  k_fill<<<(NE + 255) / 256, 256, 0, stream>>>(ei, flags, row_ptr, aew, fill,
                                               csr_s, csr_w);
  k_degsum<<<NN / 16, 256, 0, stream>>>(row_ptr, csr_w, deg);
  k_dis<<<(3 * NN + 255) / 256, 256, 0, stream>>>(deg, cnt, dis2);
  k_norm<<<(NE + 255) / 256, 256, 0, stream>>>(csr_s, deg, dis2, csr_w);
  k_h1m<<<(NN + 63) / 64, 256, 0, stream>>>(x, W1, flags, h1);
  k_gath1<<<(NN + 3) / 4, 256, 0, stream>>>(h1, csr_s, csr_w, row_ptr, deg, b1,
                                            flags, dout);
  k_attn<<<NN / AT_ROWS, 256, 0, stream>>>(Wf, bfv, qf, flags, dout);
  k_agg2<<<(NN + 3) / 4, 256, 0, stream>>>(csr_s, csr_w, row_ptr, dis2, dout, agg);
  k_emb2m<<<(NN + 63) / 64, 256, 0, stream>>>(agg, W2, b2, flags, dout);
  {
    dim3 gdim(VS_NC, 32);
    k_vsum<<<gdim, 256, 0, stream>>>(gn, dout, flags, part, rspart);
  }
  k_gfinal<<<NB, 64, 0, stream>>>(part, rspart, dout);
}

// Round 15
// 372.393 us; speedup vs baseline: 7.6959x; 1.1904x over previous
//
#include <hip/hip_runtime.h>
#include <hip/hip_bf16.h>

#define NN 50000
#define NE 800000
#define NG 3
#define NB 256
#define NSCB 196  // ceil(NN/256)

#define OFF_FUSED ((size_t)0)
#define OFF_EMB   ((size_t)NN * 64)
#define OFF_G     (OFF_EMB + (size_t)NN * 256)
#define OFF_HID   (OFF_G + (size_t)NB * 64)
#define OFF_ATTN  (OFF_HID + (size_t)3 * NN * 64)

// k_vsum geometry: 49 n-chunks of 1024; 32 b-groups of 8 rows; slice = ks*4+wave
#define VS_NC 49
#define VS_SL (VS_NC * 4)

typedef unsigned short u16;
typedef __attribute__((ext_vector_type(8))) short short8;
typedef __attribute__((ext_vector_type(4))) float floatx4;

__device__ __forceinline__ float bf2f(u16 u) {
  union { unsigned int i; float f; } v; v.i = ((unsigned int)u) << 16; return v.f;
}
__device__ __forceinline__ u16 f2bf(float f) {
  unsigned int x = __float_as_uint(f);
  unsigned int r = (x + 0x7FFFu + ((x >> 16) & 1u)) >> 16;
  return (u16)r;
}
__device__ __forceinline__ float ldf(const void* p, size_t i, int f32) {
  return f32 ? ((const float*)p)[i] : bf2f(((const u16*)p)[i]);
}
__device__ __forceinline__ int ld_src(const void* ei, int e, int i64) {
  return i64 ? (int)((const long long*)ei)[e] : ((const int*)ei)[e];
}
__device__ __forceinline__ int ld_dst(const void* ei, int e, int i64) {
  return i64 ? (int)((const long long*)ei)[(size_t)NE + e] : ((const int*)ei)[(size_t)NE + e];
}

// ---- dtype detection ----
__global__ void k_detect(const void* x, const void* ei, int* flags) {
  if (threadIdx.x != 0 || blockIdx.x != 0) return;
  const u16* xw = (const u16*)x;
  int sane = 0;
  for (int i = 0; i < 64; ++i) {
    unsigned ex = (xw[2 * i] >> 7) & 0xFF;
    sane += (ex >= 96 && ex <= 141);
  }
  flags[0] = (sane < 48) ? 1 : 0;  // 1 => inputs are float32
  const int* e32 = (const int*)ei;
  int zeros = 0;
  for (int t = 1; t < 32; t += 2) zeros += (e32[t] == 0);
  flags[1] = (zeros >= 12) ? 1 : 0;  // 1 => edge_index is int64
}

// ---- edge count histogram ----
__global__ void k_cnt(const void* ei, const int* __restrict__ flags,
                      unsigned* __restrict__ cnt) {
  int e = blockIdx.x * 256 + threadIdx.x;
  if (e >= NE) return;
  atomicAdd(&cnt[ld_dst(ei, e, flags[1])], 1u);
}

// ---- 3-phase exclusive scan of cnt -> row_ptr ----
__global__ __launch_bounds__(256) void k_sc1(const unsigned* __restrict__ cnt,
                                             unsigned* __restrict__ bsum) {
  int b = blockIdx.x, tid = threadIdx.x, i = b * 256 + tid;
  unsigned v = (i < NN) ? cnt[i] : 0u;
  #pragma unroll
  for (int off = 32; off > 0; off >>= 1) v += __shfl_down(v, off);
  __shared__ unsigned w4[4];
  if ((tid & 63) == 0) w4[tid >> 6] = v;
  __syncthreads();
  if (tid == 0) bsum[b] = w4[0] + w4[1] + w4[2] + w4[3];
}
__global__ __launch_bounds__(256) void k_sc2(const unsigned* __restrict__ bsum,
                                             unsigned* __restrict__ boff,
                                             unsigned* __restrict__ row_ptr) {
  int tid = threadIdx.x, lane = tid & 63, w = tid >> 6;
  unsigned v = (tid < NSCB) ? bsum[tid] : 0u;
  unsigned x = v;
  #pragma unroll
  for (int off = 1; off < 64; off <<= 1) {
    unsigned y = __shfl_up(x, off);
    if (lane >= off) x += y;
  }
  __shared__ unsigned w4[4];
  if (lane == 63) w4[w] = x;
  __syncthreads();
  unsigned woff = 0;
  #pragma unroll
  for (int k = 0; k < 4; ++k) woff += (k < w) ? w4[k] : 0u;
  if (tid < NSCB) boff[tid] = woff + x - v;
  if (tid == 255) row_ptr[NN] = woff + x;
}
__global__ __launch_bounds__(256) void k_sc3(const unsigned* __restrict__ cnt,
                                             const unsigned* __restrict__ boff,
                                             unsigned* __restrict__ row_ptr) {
  int b = blockIdx.x, tid = threadIdx.x, lane = tid & 63, w = tid >> 6;
  int i = b * 256 + tid;
  unsigned v = (i < NN) ? cnt[i] : 0u;
  unsigned x = v;
  #pragma unroll
  for (int off = 1; off < 64; off <<= 1) {
    unsigned y = __shfl_up(x, off);
    if (lane >= off) x += y;
  }
  __shared__ unsigned w4[4];
  if (lane == 63) w4[w] = x;
  __syncthreads();
  unsigned woff = 0;
  #pragma unroll
  for (int k = 0; k < 4; ++k) woff += (k < w) ? w4[k] : 0u;
  if (i < NN) row_ptr[i] = boff[b] + woff + x - v;
}

// ---- CSR fill: place {src, raw ew0..2}; normalization deferred ----
__global__ void k_fill(const void* ei, const int* __restrict__ flags,
                       const unsigned* __restrict__ row_ptr, const void* aew,
                       unsigned* __restrict__ fill,
                       int* __restrict__ csr_s, float4* __restrict__ csr_w) {
  int e = blockIdx.x * 256 + threadIdx.x;
  if (e >= NE) return;
  int f32 = flags[0], i64 = flags[1];
  int s = ld_src(ei, e, i64);
  int d = ld_dst(ei, e, i64);
  unsigned pos = row_ptr[d] + atomicAdd(&fill[d], 1u);
  csr_s[pos] = s;
  csr_w[pos] = make_float4(ldf(aew, e, f32),
                           ldf(aew, (size_t)NE + e, f32),
                           ldf(aew, (size_t)2 * NE + e, f32), 0.f);
}

// ---- per-node degree sums from CSR rows (atomic-free, coalesced) ----
__global__ __launch_bounds__(256) void k_degsum(const unsigned* __restrict__ row_ptr,
                                                const float4* __restrict__ csr_w,
                                                float* __restrict__ deg) {
  int tid = threadIdx.x, wid = tid >> 6, lane = tid & 63;
  int node = blockIdx.x * 16 + wid * 4 + (lane >> 4);  // NN%16==0
  int sl = lane & 15;
  unsigned beg = row_ptr[node], end = row_ptr[node + 1];
  float s0 = 0.f, s1 = 0.f, s2 = 0.f;
  for (unsigned p = beg + sl; p < end; p += 16) {
    float4 w = csr_w[p];
    s0 += w.x; s1 += w.y; s2 += w.z;
  }
  #pragma unroll
  for (int off = 1; off < 16; off <<= 1) {
    s0 += __shfl_xor(s0, off);
    s1 += __shfl_xor(s1, off);
    s2 += __shfl_xor(s2, off);
  }
  if (sl == 0) {
    deg[node] = s0; deg[NN + node] = s1; deg[2 * NN + node] = s2;
  }
}

__global__ void k_dis(float* __restrict__ deg, const unsigned* __restrict__ cnt,
                      float* __restrict__ dis2) {
  int i = blockIdx.x * 256 + threadIdx.x;
  if (i < 3 * NN) deg[i] = rsqrtf(deg[i] + 1.0f);
  if (i < NN) dis2[i] = rsqrtf((float)cnt[i] + 1.0f);
}

// ---- normalize CSR weights in place ----
__global__ void k_norm(const int* __restrict__ csr_s, const float* __restrict__ dis,
                       const float* __restrict__ dis2, float4* __restrict__ csr_w) {
  int p = blockIdx.x * 256 + threadIdx.x;
  if (p >= NE) return;
  int s = csr_s[p];
  float4 f = csr_w[p];
  csr_w[p] = make_float4(f.x * dis[s], f.y * dis[NN + s],
                         f.z * dis[2 * NN + s], dis2[s]);
}

// ---- h1 = x @ W1 via MFMA: 64 rows/block (4 waves x 16), W1^T in LDS ----
__global__ __launch_bounds__(256) void k_h1m(const void* x, const void* W1,
                                             const int* __restrict__ flags,
                                             float* __restrict__ h1) {
  __shared__ short w1t[64 * 264];  // W1^T: [col][k], stride 264 shorts
  int tid = threadIdx.x, f32 = flags[0];
  for (int i = tid; i < 64 * 256; i += 256) {
    int col = i & 63, k = i >> 6;
    w1t[col * 264 + k] = (short)(f32 ? f2bf(((const float*)W1)[k * 64 + col])
                                     : ((const u16*)W1)[k * 64 + col]);
  }
  __syncthreads();
  int wid = tid >> 6, l = tid & 63;
  int rowbase = blockIdx.x * 64 + wid * 16;
  int arow = rowbase + (l & 15);
  if (arow >= NN) arow = NN - 1;
  int koff = (l >> 4) * 8;
  floatx4 acc[4];
  #pragma unroll
  for (int c = 0; c < 4; ++c) acc[c] = (floatx4){0.f, 0.f, 0.f, 0.f};
  #pragma unroll
  for (int kk = 0; kk < 8; ++kk) {
    int k0 = kk * 32 + koff;
    short8 a;
    if (f32) {
      const float* xp = (const float*)x + (size_t)arow * 256 + k0;
      float4 lo = *(const float4*)xp;
      float4 hi = *(const float4*)(xp + 4);
      a[0] = (short)f2bf(lo.x); a[1] = (short)f2bf(lo.y);
      a[2] = (short)f2bf(lo.z); a[3] = (short)f2bf(lo.w);
      a[4] = (short)f2bf(hi.x); a[5] = (short)f2bf(hi.y);
      a[6] = (short)f2bf(hi.z); a[7] = (short)f2bf(hi.w);
    } else {
      a = *(const short8*)((const u16*)x + (size_t)arow * 256 + k0);
    }
    #pragma unroll
    for (int c = 0; c < 4; ++c) {
      short8 b = *(const short8*)(&w1t[(c * 16 + (l & 15)) * 264 + k0]);
      acc[c] = __builtin_amdgcn_mfma_f32_16x16x32_bf16(a, b, acc[c], 0, 0, 0);
    }
  }
  int r0 = rowbase + (l >> 4) * 4;
  int colb = l & 15;
  #pragma unroll
  for (int c = 0; c < 4; ++c)
    #pragma unroll
    for (int r = 0; r < 4; ++r) {
      int rr = r0 + r;
      if (rr < NN) h1[(size_t)rr * 64 + c * 16 + colb] = acc[c][r];
    }
}

// ---- gather layer1 only (3 graphs), max occupancy ----
__global__ __launch_bounds__(256) void k_gath1(
    const float* __restrict__ h1, const int* __restrict__ csr_s,
    const float4* __restrict__ csr_w, const unsigned* __restrict__ row_ptr,
    const float* __restrict__ deg_dis, const void* b1,
    const int* __restrict__ flags, float* __restrict__ dout) {
  __shared__ float4 eWL[4][64];  // 4 KB per-wave edge staging
  __shared__ float b1L[64];
  int tid = threadIdx.x, f32 = flags[0];
  if (tid < 64) b1L[tid] = ldf(b1, tid, f32);
  __syncthreads();
  int wid = tid >> 6, lane = tid & 63;
  int n = blockIdx.x * 4 + wid;
  if (n >= NN) return;

  float dd0 = deg_dis[n], dd1 = deg_dis[NN + n], dd2 = deg_dis[2 * NN + n];
  float a0[4] = {0,0,0,0}, a1[4] = {0,0,0,0}, a2[4] = {0,0,0,0};
  int g = lane >> 4, dq = lane & 15;
  unsigned beg = row_ptr[n], end = row_ptr[n + 1];
  for (unsigned base = beg; base < end; base += 64) {
    unsigned rem = end - base;
    int m = (rem > 64u) ? 64 : (int)rem;
    float4 st = make_float4(0.f, 0.f, 0.f, __int_as_float(0));
    if (lane < m) {
      float4 cw = csr_w[base + lane];
      int s = csr_s[base + lane];
      st = make_float4(cw.x * dd0, cw.y * dd1, cw.z * dd2, __int_as_float(s));
    }
    eWL[wid][lane] = st;   // wave-private row; same-wave LDS ops are in-order
    int jmax = (m + 3) >> 2;
    for (int j = 0; j < jmax; ++j) {
      float4 e = eWL[wid][j * 4 + g];
      int sj = __float_as_int(e.w);
      float4 hr = *(const float4*)&h1[(size_t)sj * 64 + dq * 4];
      a0[0] += e.x * hr.x; a0[1] += e.x * hr.y; a0[2] += e.x * hr.z; a0[3] += e.x * hr.w;
      a1[0] += e.y * hr.x; a1[1] += e.y * hr.y; a1[2] += e.y * hr.z; a1[3] += e.y * hr.w;
      a2[0] += e.z * hr.x; a2[1] += e.z * hr.y; a2[2] += e.z * hr.z; a2[3] += e.z * hr.w;
    }
  }
  #pragma unroll
  for (int c = 0; c < 4; ++c) {
    a0[c] += __shfl_xor(a0[c], 16); a0[c] += __shfl_xor(a0[c], 32);
    a1[c] += __shfl_xor(a1[c], 16); a1[c] += __shfl_xor(a1[c], 32);
    a2[c] += __shfl_xor(a2[c], 16); a2[c] += __shfl_xor(a2[c], 32);
  }
  // redistribute to lane=dim layout
  int srcl = lane >> 2, cc = lane & 3;
  float t0, t1, t2, t3, r0, r1, r2;
  t0 = __shfl(a0[0], srcl); t1 = __shfl(a0[1], srcl);
  t2 = __shfl(a0[2], srcl); t3 = __shfl(a0[3], srcl);
  r0 = cc == 0 ? t0 : cc == 1 ? t1 : cc == 2 ? t2 : t3;
  t0 = __shfl(a1[0], srcl); t1 = __shfl(a1[1], srcl);
  t2 = __shfl(a1[2], srcl); t3 = __shfl(a1[3], srcl);
  r1 = cc == 0 ? t0 : cc == 1 ? t1 : cc == 2 ? t2 : t3;
  t0 = __shfl(a2[0], srcl); t1 = __shfl(a2[1], srcl);
  t2 = __shfl(a2[2], srcl); t3 = __shfl(a2[3], srcl);
  r2 = cc == 0 ? t0 : cc == 1 ? t1 : cc == 2 ? t2 : t3;

  float selfv = h1[(size_t)n * 64 + lane];
  float b1v = b1L[lane];
  dout[OFF_HID + ((size_t)0 * NN + n) * 64 + lane] = fmaxf(r0 + dd0 * dd0 * selfv + b1v, 0.f);
  dout[OFF_HID + ((size_t)1 * NN + n) * 64 + lane] = fmaxf(r1 + dd1 * dd1 * selfv + b1v, 0.f);
  dout[OFF_HID + ((size_t)2 * NN + n) * 64 + lane] = fmaxf(r2 + dd2 * dd2 * selfv + b1v, 0.f);
}

// ---- attention via MFMA: u = hid @ Wf per graph, tanh/qf epilogue, softmax ----
__global__ __launch_bounds__(256) void k_attnm(
    const void* Wf, const void* bfv, const void* qf,
    const int* __restrict__ flags, float* __restrict__ dout) {
  __shared__ short wft[3 * 64 * 72];   // Wf^T: [g][j][k], stride 72 shorts
  __shared__ float qfL[192], bfL[192];
  int tid = threadIdx.x, f32 = flags[0];
  for (int i = tid; i < 3 * 64 * 64; i += 256) {
    int g = i >> 12, rem = i & 4095, k = rem >> 6, j = rem & 63;
    wft[(g * 64 + j) * 72 + k] =
        (short)(f32 ? f2bf(((const float*)Wf)[i]) : ((const u16*)Wf)[i]);
  }
  if (tid < 192) { qfL[tid] = ldf(qf, tid, f32); bfL[tid] = ldf(bfv, tid, f32); }
  __syncthreads();
  int wid = tid >> 6, l = tid & 63;
  int rowT = blockIdx.x * 64 + wid * 16;
  int colb = l & 15, rg = l >> 4;
  int arow = rowT + colb;
  if (arow >= NN) arow = NN - 1;
  int koff = rg * 8;
  float p[3][4];
  #pragma unroll
  for (int g = 0; g < 3; ++g) {
    floatx4 acc[4];
    #pragma unroll
    for (int c = 0; c < 4; ++c) acc[c] = (floatx4){0.f, 0.f, 0.f, 0.f};
    #pragma unroll
    for (int kk = 0; kk < 2; ++kk) {
      int k0 = kk * 32 + koff;
      const float* hp = dout + OFF_HID + ((size_t)g * NN + arow) * 64 + k0;
      float4 lo = *(const float4*)hp;
      float4 hi = *(const float4*)(hp + 4);
      short8 a;
      a[0] = (short)f2bf(lo.x); a[1] = (short)f2bf(lo.y);
      a[2] = (short)f2bf(lo.z); a[3] = (short)f2bf(lo.w);
      a[4] = (short)f2bf(hi.x); a[5] = (short)f2bf(hi.y);
      a[6] = (short)f2bf(hi.z); a[7] = (short)f2bf(hi.w);
      #pragma unroll
      for (int c = 0; c < 4; ++c) {
        short8 b = *(const short8*)(&wft[((size_t)g * 64 + c * 16 + colb) * 72 + k0]);
        acc[c] = __builtin_amdgcn_mfma_f32_16x16x32_bf16(a, b, acc[c], 0, 0, 0);
      }
    }
    #pragma unroll
    for (int r = 0; r < 4; ++r) {
      float t = 0.f;
      #pragma unroll
      for (int c = 0; c < 4; ++c) {
        int j = c * 16 + colb;
        t += tanhf(acc[c][r] + bfL[g * 64 + j]) * qfL[g * 64 + j];
      }
      t += __shfl_xor(t, 1); t += __shfl_xor(t, 2);
      t += __shfl_xor(t, 4); t += __shfl_xor(t, 8);
      p[g][r] = t;
    }
  }
  #pragma unroll
  for (int r = 0; r < 4; ++r) {
    int rr = rowT + rg * 4 + r;
    if (rr >= NN) continue;
    float p0 = p[0][r], p1 = p[1][r], p2 = p[2][r];
    float mx = fmaxf(p0, fmaxf(p1, p2));
    float e0 = expf(p0 - mx), e1 = expf(p1 - mx), e2 = expf(p2 - mx);
    float inv = 1.0f / (e0 + e1 + e2);
    float aw0 = e0 * inv, aw1 = e1 * inv, aw2 = e2 * inv;
    float4 h0 = *(const float4*)(dout + OFF_HID + ((size_t)0 * NN + rr) * 64 + colb * 4);
    float4 h1 = *(const float4*)(dout + OFF_HID + ((size_t)1 * NN + rr) * 64 + colb * 4);
    float4 h2 = *(const float4*)(dout + OFF_HID + ((size_t)2 * NN + rr) * 64 + colb * 4);
    *(float4*)(dout + OFF_FUSED + (size_t)rr * 64 + colb * 4) =
        make_float4(aw0 * h0.x + aw1 * h1.x + aw2 * h2.x,
                    aw0 * h0.y + aw1 * h1.y + aw2 * h2.y,
                    aw0 * h0.z + aw1 * h1.z + aw2 * h2.z,
                    aw0 * h0.w + aw1 * h1.w + aw2 * h2.w);
    if (colb < 3)
      dout[OFF_ATTN + (size_t)rr * 3 + colb] = (colb == 0 ? aw0 : (colb == 1 ? aw1 : aw2));
  }
}

// ---- layer2 gather (packed LDS staging): agg = sym-aggregate(fused) ----
__global__ __launch_bounds__(256) void k_agg2(
    const int* __restrict__ csr_s, const float4* __restrict__ csr_w,
    const unsigned* __restrict__ row_ptr, const float* __restrict__ dis2,
    const float* __restrict__ dout, float* __restrict__ agg) {
  __shared__ uint2 eL[4][64];
  const float* fused = dout + OFF_FUSED;
  int tid = threadIdx.x, wid = tid >> 6, lane = tid & 63;
  int n = blockIdx.x * 4 + wid;
  if (n >= NN) return;
  float dd = dis2[n];
  float acc[4] = {0.f, 0.f, 0.f, 0.f};
  int g = lane >> 4, dq = lane & 15;
  unsigned beg = row_ptr[n], end = row_ptr[n + 1];
  for (unsigned base = beg; base < end; base += 64) {
    unsigned rem = end - base;
    int m = (rem > 64u) ? 64 : (int)rem;
    uint2 st = make_uint2(0u, 0u);
    if (lane < m)
      st = make_uint2((unsigned)csr_s[base + lane],
                      __float_as_uint(csr_w[base + lane].w * dd));
    eL[wid][lane] = st;
    int jmax = (m + 3) >> 2;
    for (int j = 0; j < jmax; ++j) {
      uint2 e = eL[wid][j * 4 + g];
      int sj = (int)e.x;
      float wj = __uint_as_float(e.y);
      float4 fr = *(const float4*)&fused[(size_t)sj * 64 + dq * 4];
      acc[0] += wj * fr.x; acc[1] += wj * fr.y;
      acc[2] += wj * fr.z; acc[3] += wj * fr.w;
    }
  }
  #pragma unroll
  for (int c = 0; c < 4; ++c) {
    acc[c] += __shfl_xor(acc[c], 16);
    acc[c] += __shfl_xor(acc[c], 32);
  }
  if (lane < 16) {
    float4 sf = *(const float4*)&fused[(size_t)n * 64 + lane * 4];
    float sw = dd * dd;
    *(float4*)&agg[(size_t)n * 64 + lane * 4] =
        make_float4(acc[0] + sw * sf.x, acc[1] + sw * sf.y,
                    acc[2] + sw * sf.z, acc[3] + sw * sf.w);
  }
}

// ---- emb = relu(agg @ W2 + b2) via MFMA: 64 rows/block, W2^T in LDS ----
__global__ __launch_bounds__(256) void k_emb2m(const float* __restrict__ agg,
                                               const void* W2, const void* b2,
                                               const int* __restrict__ flags,
                                               float* __restrict__ dout) {
  __shared__ short w2t[256 * 72];  // W2^T: [col][k], stride 72 shorts
  __shared__ float b2L[256];
  int tid = threadIdx.x, f32 = flags[0];
  for (int i = tid; i < 256 * 64; i += 256) {
    int col = i & 255, k = i >> 8;
    w2t[col * 72 + k] = (short)(f32 ? f2bf(((const float*)W2)[k * 256 + col])
                                    : ((const u16*)W2)[k * 256 + col]);
  }
  b2L[tid] = ldf(b2, tid, f32);
  __syncthreads();
  int wid = tid >> 6, l = tid & 63;
  int rowbase = blockIdx.x * 64 + wid * 16;
  int arow = rowbase + (l & 15);
  if (arow >= NN) arow = NN - 1;
  int koff = (l >> 4) * 8;
  floatx4 acc[16];
  #pragma unroll
  for (int c = 0; c < 16; ++c) acc[c] = (floatx4){0.f, 0.f, 0.f, 0.f};
  #pragma unroll
  for (int kk = 0; kk < 2; ++kk) {
    int k0 = kk * 32 + koff;
    const float* ap = agg + (size_t)arow * 64 + k0;
    float4 lo = *(const float4*)ap;
    float4 hi = *(const float4*)(ap + 4);
    short8 a;
    a[0] = (short)f2bf(lo.x); a[1] = (short)f2bf(lo.y);
    a[2] = (short)f2bf(lo.z); a[3] = (short)f2bf(lo.w);
    a[4] = (short)f2bf(hi.x); a[5] = (short)f2bf(hi.y);
    a[6] = (short)f2bf(hi.z); a[7] = (short)f2bf(hi.w);
    #pragma unroll
    for (int c = 0; c < 16; ++c) {
      short8 b = *(const short8*)(&w2t[(c * 16 + (l & 15)) * 72 + k0]);
      acc[c] = __builtin_amdgcn_mfma_f32_16x16x32_bf16(a, b, acc[c], 0, 0, 0);
    }
  }
  int r0 = rowbase + (l >> 4) * 4;
  int colb = l & 15;
  #pragma unroll
  for (int c = 0; c < 16; ++c) {
    float bb = b2L[c * 16 + colb];
    #pragma unroll
    for (int r = 0; r < 4; ++r) {
      int rr = r0 + r;
      if (rr < NN)
        dout[OFF_EMB + (size_t)rr * 256 + c * 16 + colb] = fmaxf(acc[c][r] + bb, 0.f);
    }
  }
}

// ---- vsum = graph_neigh @ fused (LDS gn tiles) + fused row sums ----
__global__ __launch_bounds__(256) void k_vsum(const void* gn,
                                              const float* __restrict__ dout,
                                              const int* __restrict__ flags,
                                              float* __restrict__ part,
                                              float* __restrict__ rspart) {
  __shared__ float gnL[8][1024];
  const float* fused = dout + OFF_FUSED;
  int tid = threadIdx.x, wid = tid >> 6, lane = tid & 63;
  int f32 = flags[0];
  int ks = blockIdx.x, bg = blockIdx.y;
  int nbase = ks * 1024;
  #pragma unroll
  for (int r = 0; r < 8; ++r) {
    #pragma unroll
    for (int i = 0; i < 4; ++i) {
      int colv = i * 256 + tid;
      int nn = nbase + colv;
      gnL[r][colv] = (nn < NN) ? ldf(gn, (size_t)(bg * 8 + r) * NN + nn, f32) : 0.f;
    }
  }
  __syncthreads();
  #pragma unroll
  for (int rr = 0; rr < 2; ++rr) {
    int r = wid * 2 + rr;
    float s = 0.f;
    #pragma unroll
    for (int i = 0; i < 16; ++i) s += gnL[r][i * 64 + lane];
    #pragma unroll
    for (int off = 32; off > 0; off >>= 1) s += __shfl_down(s, off);
    if (lane == 0) rspart[(size_t)ks * 256 + bg * 8 + r] = s;
  }
  int g = lane >> 4, dq = lane & 15;
  float acc[8][4];
  #pragma unroll
  for (int r = 0; r < 8; ++r)
    #pragma unroll
    for (int c = 0; c < 4; ++c) acc[r][c] = 0.f;
  for (int i = 0; i < 64; ++i) {
    int nloc = wid * 256 + i * 4 + g;
    int nn = nbase + nloc;
    float4 fr = (nn < NN) ? *(const float4*)&fused[(size_t)nn * 64 + dq * 4]
                          : make_float4(0.f, 0.f, 0.f, 0.f);
    #pragma unroll
    for (int r = 0; r < 8; ++r) {
      float gv = gnL[r][nloc];
      acc[r][0] += gv * fr.x; acc[r][1] += gv * fr.y;
      acc[r][2] += gv * fr.z; acc[r][3] += gv * fr.w;
    }
  }
  #pragma unroll
  for (int r = 0; r < 8; ++r)
    #pragma unroll
    for (int c = 0; c < 4; ++c) {
      acc[r][c] += __shfl_xor(acc[r][c], 16);
      acc[r][c] += __shfl_xor(acc[r][c], 32);
    }
  if (lane < 16) {
    int slice = ks * 4 + wid;
    #pragma unroll
    for (int r = 0; r < 8; ++r)
      *(float4*)&part[((size_t)slice * 256 + bg * 8 + r) * 64 + lane * 4] =
          make_float4(acc[r][0], acc[r][1], acc[r][2], acc[r][3]);
  }
}

// ---- g finalize: reduce partials, divide by row_sum, L2 normalize ----
__global__ __launch_bounds__(64) void k_gfinal(const float* __restrict__ part,
                                               const float* __restrict__ rspart,
                                               float* __restrict__ dout) {
  int b = blockIdx.x, j = threadIdx.x;
  float acc = 0.f;
  for (int k = 0; k < VS_SL; ++k) acc += part[((size_t)k * 256 + b) * 64 + j];
  float rs = 0.f;
  for (int k = 0; k < VS_NC; ++k) rs += rspart[(size_t)k * 256 + b];
  float v = acc / rs;
  float sq = v * v;
  #pragma unroll
  for (int off = 32; off > 0; off >>= 1) sq += __shfl_xor(sq, off);
  float nrm = sqrtf(sq);
  dout[OFF_G + (size_t)b * 64 + j] = v / fmaxf(nrm, 1e-12f);
}

extern "C" void kernel_launch(void* const* d_in, const int* in_sizes, int n_in,
                              void* d_out, int out_size, void* d_ws, size_t ws_size,
                              hipStream_t stream) {
  const void* x   = d_in[0];
  const void* ei  = d_in[1];
  const void* gn  = d_in[2];
  const void* aew = d_in[3];
  const void* W1  = d_in[4];
  const void* b1  = d_in[5];
  const void* W2  = d_in[6];
  const void* b2  = d_in[7];
  const void* Wf  = d_in[8];
  const void* bfv = d_in[9];
  const void* qf  = d_in[10];

  char* ws = (char*)d_ws;
  size_t off = 0;
  auto alloc = [&](size_t bytes) -> void* {
    void* p = ws + off;
    off += (bytes + 255) & ~(size_t)255;
    return p;
  };
  // zero-init region (atomically accumulated buffers only)
  unsigned* cnt     = (unsigned*)alloc((size_t)NN * 4);
  unsigned* fill    = (unsigned*)alloc((size_t)NN * 4);
  size_t zero_bytes = off;
  float*    deg     = (float*)alloc((size_t)3 * NN * 4);
  int*      flags   = (int*)alloc(64);
  float*    dis2    = (float*)alloc((size_t)NN * 4);
  unsigned* row_ptr = (unsigned*)alloc((size_t)(NN + 1) * 4);
  unsigned* bsum    = (unsigned*)alloc((size_t)NSCB * 4);
  unsigned* boff    = (unsigned*)alloc((size_t)NSCB * 4);
  int*      csr_s   = (int*)alloc((size_t)NE * 4);
  float4*   csr_w   = (float4*)alloc((size_t)NE * 16);
  // time-shared region: h1 (k_h1m->k_gath1), agg (k_agg2->k_emb2m), part (k_vsum->k_gfinal)
  size_t regA_bytes = (size_t)VS_SL * NB * 64 * 4;
  char*  regA       = (char*)alloc(regA_bytes);
  float* h1   = (float*)regA;
  float* agg  = (float*)regA;
  float* part = (float*)regA;
  float* rspart = (float*)alloc((size_t)VS_NC * NB * 4);

  float* dout = (float*)d_out;

  hipMemsetAsync(d_ws, 0, zero_bytes, stream);
  k_detect<<<1, 64, 0, stream>>>(x, ei, flags);
  k_cnt<<<(NE + 255) / 256, 256, 0, stream>>>(ei, flags, cnt);
  k_sc1<<<NSCB, 256, 0, stream>>>(cnt, bsum);
  k_sc2<<<1, 256, 0, stream>>>(bsum, boff, row_ptr);
  k_sc3<<<NSCB, 256, 0, stream>>>(cnt, boff, row_ptr);
  k_fill<<<(NE + 255) / 256, 256, 0, stream>>>(ei, flags, row_ptr, aew, fill,
                                               csr_s, csr_w);
  k_degsum<<<NN / 16, 256, 0, stream>>>(row_ptr, csr_w, deg);
  k_dis<<<(3 * NN + 255) / 256, 256, 0, stream>>>(deg, cnt, dis2);
  k_norm<<<(NE + 255) / 256, 256, 0, stream>>>(csr_s, deg, dis2, csr_w);
  k_h1m<<<(NN + 63) / 64, 256, 0, stream>>>(x, W1, flags, h1);
  k_gath1<<<(NN + 3) / 4, 256, 0, stream>>>(h1, csr_s, csr_w, row_ptr, deg, b1,
                                            flags, dout);
  k_attnm<<<(NN + 63) / 64, 256, 0, stream>>>(Wf, bfv, qf, flags, dout);
  k_agg2<<<(NN + 3) / 4, 256, 0, stream>>>(csr_s, csr_w, row_ptr, dis2, dout, agg);
  k_emb2m<<<(NN + 63) / 64, 256, 0, stream>>>(agg, W2, b2, flags, dout);
  {
    dim3 gdim(VS_NC, 32);
    k_vsum<<<gdim, 256, 0, stream>>>(gn, dout, flags, part, rspart);
  }
  k_gfinal<<<NB, 64, 0, stream>>>(part, rspart, dout);
}

// Round 16
// 367.926 us; speedup vs baseline: 7.7893x; 1.0121x over previous
//
#include <hip/hip_runtime.h>
#include <hip/hip_bf16.h>

#define NN 50000
#define NE 800000
#define NG 3
#define NB 256
#define NSCB 196  // ceil(NN/256)

#define OFF_FUSED ((size_t)0)
#define OFF_EMB   ((size_t)NN * 64)
#define OFF_G     (OFF_EMB + (size_t)NN * 256)
#define OFF_HID   (OFF_G + (size_t)NB * 64)
#define OFF_ATTN  (OFF_HID + (size_t)3 * NN * 64)

// k_vsum: 196 n-chunks of 256 nodes, each block covers all 256 b rows
#define VS_SP 196

typedef unsigned short u16;
typedef __attribute__((ext_vector_type(8))) short short8;
typedef __attribute__((ext_vector_type(4))) float floatx4;

__device__ __forceinline__ float bf2f(u16 u) {
  union { unsigned int i; float f; } v; v.i = ((unsigned int)u) << 16; return v.f;
}
__device__ __forceinline__ u16 f2bf(float f) {
  unsigned int x = __float_as_uint(f);
  unsigned int r = (x + 0x7FFFu + ((x >> 16) & 1u)) >> 16;
  return (u16)r;
}
__device__ __forceinline__ float ldf(const void* p, size_t i, int f32) {
  return f32 ? ((const float*)p)[i] : bf2f(((const u16*)p)[i]);
}
__device__ __forceinline__ int ld_src(const void* ei, int e, int i64) {
  return i64 ? (int)((const long long*)ei)[e] : ((const int*)ei)[e];
}
__device__ __forceinline__ int ld_dst(const void* ei, int e, int i64) {
  return i64 ? (int)((const long long*)ei)[(size_t)NE + e] : ((const int*)ei)[(size_t)NE + e];
}

// ---- dtype detection ----
__global__ void k_detect(const void* x, const void* ei, int* flags) {
  if (threadIdx.x != 0 || blockIdx.x != 0) return;
  const u16* xw = (const u16*)x;
  int sane = 0;
  for (int i = 0; i < 64; ++i) {
    unsigned ex = (xw[2 * i] >> 7) & 0xFF;
    sane += (ex >= 96 && ex <= 141);
  }
  flags[0] = (sane < 48) ? 1 : 0;  // 1 => inputs are float32
  const int* e32 = (const int*)ei;
  int zeros = 0;
  for (int t = 1; t < 32; t += 2) zeros += (e32[t] == 0);
  flags[1] = (zeros >= 12) ? 1 : 0;  // 1 => edge_index is int64
}

// ---- edge count histogram ----
__global__ void k_cnt(const void* ei, const int* __restrict__ flags,
                      unsigned* __restrict__ cnt) {
  int e = blockIdx.x * 256 + threadIdx.x;
  if (e >= NE) return;
  atomicAdd(&cnt[ld_dst(ei, e, flags[1])], 1u);
}

// ---- 3-phase exclusive scan of cnt -> row_ptr ----
__global__ __launch_bounds__(256) void k_sc1(const unsigned* __restrict__ cnt,
                                             unsigned* __restrict__ bsum) {
  int b = blockIdx.x, tid = threadIdx.x, i = b * 256 + tid;
  unsigned v = (i < NN) ? cnt[i] : 0u;
  #pragma unroll
  for (int off = 32; off > 0; off >>= 1) v += __shfl_down(v, off);
  __shared__ unsigned w4[4];
  if ((tid & 63) == 0) w4[tid >> 6] = v;
  __syncthreads();
  if (tid == 0) bsum[b] = w4[0] + w4[1] + w4[2] + w4[3];
}
__global__ __launch_bounds__(256) void k_sc2(const unsigned* __restrict__ bsum,
                                             unsigned* __restrict__ boff,
                                             unsigned* __restrict__ row_ptr) {
  int tid = threadIdx.x, lane = tid & 63, w = tid >> 6;
  unsigned v = (tid < NSCB) ? bsum[tid] : 0u;
  unsigned x = v;
  #pragma unroll
  for (int off = 1; off < 64; off <<= 1) {
    unsigned y = __shfl_up(x, off);
    if (lane >= off) x += y;
  }
  __shared__ unsigned w4[4];
  if (lane == 63) w4[w] = x;
  __syncthreads();
  unsigned woff = 0;
  #pragma unroll
  for (int k = 0; k < 4; ++k) woff += (k < w) ? w4[k] : 0u;
  if (tid < NSCB) boff[tid] = woff + x - v;
  if (tid == 255) row_ptr[NN] = woff + x;
}
__global__ __launch_bounds__(256) void k_sc3(const unsigned* __restrict__ cnt,
                                             const unsigned* __restrict__ boff,
                                             unsigned* __restrict__ row_ptr) {
  int b = blockIdx.x, tid = threadIdx.x, lane = tid & 63, w = tid >> 6;
  int i = b * 256 + tid;
  unsigned v = (i < NN) ? cnt[i] : 0u;
  unsigned x = v;
  #pragma unroll
  for (int off = 1; off < 64; off <<= 1) {
    unsigned y = __shfl_up(x, off);
    if (lane >= off) x += y;
  }
  __shared__ unsigned w4[4];
  if (lane == 63) w4[w] = x;
  __syncthreads();
  unsigned woff = 0;
  #pragma unroll
  for (int k = 0; k < 4; ++k) woff += (k < w) ? w4[k] : 0u;
  if (i < NN) row_ptr[i] = boff[b] + woff + x - v;
}

// ---- CSR fill: place {src, raw ew0..2}; normalization deferred ----
__global__ void k_fill(const void* ei, const int* __restrict__ flags,
                       const unsigned* __restrict__ row_ptr, const void* aew,
                       unsigned* __restrict__ fill,
                       int* __restrict__ csr_s, float4* __restrict__ csr_w) {
  int e = blockIdx.x * 256 + threadIdx.x;
  if (e >= NE) return;
  int f32 = flags[0], i64 = flags[1];
  int s = ld_src(ei, e, i64);
  int d = ld_dst(ei, e, i64);
  unsigned pos = row_ptr[d] + atomicAdd(&fill[d], 1u);
  csr_s[pos] = s;
  csr_w[pos] = make_float4(ldf(aew, e, f32),
                           ldf(aew, (size_t)NE + e, f32),
                           ldf(aew, (size_t)2 * NE + e, f32), 0.f);
}

// ---- per-node degree sums from CSR rows (atomic-free, coalesced) ----
__global__ __launch_bounds__(256) void k_degsum(const unsigned* __restrict__ row_ptr,
                                                const float4* __restrict__ csr_w,
                                                float* __restrict__ deg) {
  int tid = threadIdx.x, wid = tid >> 6, lane = tid & 63;
  int node = blockIdx.x * 16 + wid * 4 + (lane >> 4);  // NN%16==0
  int sl = lane & 15;
  unsigned beg = row_ptr[node], end = row_ptr[node + 1];
  float s0 = 0.f, s1 = 0.f, s2 = 0.f;
  for (unsigned p = beg + sl; p < end; p += 16) {
    float4 w = csr_w[p];
    s0 += w.x; s1 += w.y; s2 += w.z;
  }
  #pragma unroll
  for (int off = 1; off < 16; off <<= 1) {
    s0 += __shfl_xor(s0, off);
    s1 += __shfl_xor(s1, off);
    s2 += __shfl_xor(s2, off);
  }
  if (sl == 0) {
    deg[node] = s0; deg[NN + node] = s1; deg[2 * NN + node] = s2;
  }
}

__global__ void k_dis(float* __restrict__ deg, const unsigned* __restrict__ cnt,
                      float* __restrict__ dis2) {
  int i = blockIdx.x * 256 + threadIdx.x;
  if (i < 3 * NN) deg[i] = rsqrtf(deg[i] + 1.0f);
  if (i < NN) dis2[i] = rsqrtf((float)cnt[i] + 1.0f);
}

// ---- normalize CSR weights in place ----
__global__ void k_norm(const int* __restrict__ csr_s, const float* __restrict__ dis,
                       const float* __restrict__ dis2, float4* __restrict__ csr_w) {
  int p = blockIdx.x * 256 + threadIdx.x;
  if (p >= NE) return;
  int s = csr_s[p];
  float4 f = csr_w[p];
  csr_w[p] = make_float4(f.x * dis[s], f.y * dis[NN + s],
                         f.z * dis[2 * NN + s], dis2[s]);
}

// ---- h1 = x @ W1 via MFMA: 64 rows/block (4 waves x 16), W1^T in LDS ----
__global__ __launch_bounds__(256) void k_h1m(const void* x, const void* W1,
                                             const int* __restrict__ flags,
                                             float* __restrict__ h1) {
  __shared__ short w1t[64 * 264];  // W1^T: [col][k], stride 264 shorts
  int tid = threadIdx.x, f32 = flags[0];
  for (int i = tid; i < 64 * 256; i += 256) {
    int col = i & 63, k = i >> 6;
    w1t[col * 264 + k] = (short)(f32 ? f2bf(((const float*)W1)[k * 64 + col])
                                     : ((const u16*)W1)[k * 64 + col]);
  }
  __syncthreads();
  int wid = tid >> 6, l = tid & 63;
  int rowbase = blockIdx.x * 64 + wid * 16;
  int arow = rowbase + (l & 15);
  if (arow >= NN) arow = NN - 1;
  int koff = (l >> 4) * 8;
  floatx4 acc[4];
  #pragma unroll
  for (int c = 0; c < 4; ++c) acc[c] = (floatx4){0.f, 0.f, 0.f, 0.f};
  #pragma unroll
  for (int kk = 0; kk < 8; ++kk) {
    int k0 = kk * 32 + koff;
    short8 a;
    if (f32) {
      const float* xp = (const float*)x + (size_t)arow * 256 + k0;
      float4 lo = *(const float4*)xp;
      float4 hi = *(const float4*)(xp + 4);
      a[0] = (short)f2bf(lo.x); a[1] = (short)f2bf(lo.y);
      a[2] = (short)f2bf(lo.z); a[3] = (short)f2bf(lo.w);
      a[4] = (short)f2bf(hi.x); a[5] = (short)f2bf(hi.y);
      a[6] = (short)f2bf(hi.z); a[7] = (short)f2bf(hi.w);
    } else {
      a = *(const short8*)((const u16*)x + (size_t)arow * 256 + k0);
    }
    #pragma unroll
    for (int c = 0; c < 4; ++c) {
      short8 b = *(const short8*)(&w1t[(c * 16 + (l & 15)) * 264 + k0]);
      acc[c] = __builtin_amdgcn_mfma_f32_16x16x32_bf16(a, b, acc[c], 0, 0, 0);
    }
  }
  int r0 = rowbase + (l >> 4) * 4;
  int colb = l & 15;
  #pragma unroll
  for (int c = 0; c < 4; ++c)
    #pragma unroll
    for (int r = 0; r < 4; ++r) {
      int rr = r0 + r;
      if (rr < NN) h1[(size_t)rr * 64 + c * 16 + colb] = acc[c][r];
    }
}

// ---- gather layer1 only (3 graphs), max occupancy ----
__global__ __launch_bounds__(256) void k_gath1(
    const float* __restrict__ h1, const int* __restrict__ csr_s,
    const float4* __restrict__ csr_w, const unsigned* __restrict__ row_ptr,
    const float* __restrict__ deg_dis, const void* b1,
    const int* __restrict__ flags, float* __restrict__ dout) {
  __shared__ float4 eWL[4][64];  // 4 KB per-wave edge staging
  __shared__ float b1L[64];
  int tid = threadIdx.x, f32 = flags[0];
  if (tid < 64) b1L[tid] = ldf(b1, tid, f32);
  __syncthreads();
  int wid = tid >> 6, lane = tid & 63;
  int n = blockIdx.x * 4 + wid;
  if (n >= NN) return;

  float dd0 = deg_dis[n], dd1 = deg_dis[NN + n], dd2 = deg_dis[2 * NN + n];
  float a0[4] = {0,0,0,0}, a1[4] = {0,0,0,0}, a2[4] = {0,0,0,0};
  int g = lane >> 4, dq = lane & 15;
  unsigned beg = row_ptr[n], end = row_ptr[n + 1];
  for (unsigned base = beg; base < end; base += 64) {
    unsigned rem = end - base;
    int m = (rem > 64u) ? 64 : (int)rem;
    float4 st = make_float4(0.f, 0.f, 0.f, __int_as_float(0));
    if (lane < m) {
      float4 cw = csr_w[base + lane];
      int s = csr_s[base + lane];
      st = make_float4(cw.x * dd0, cw.y * dd1, cw.z * dd2, __int_as_float(s));
    }
    eWL[wid][lane] = st;   // wave-private row; same-wave LDS ops are in-order
    int jmax = (m + 3) >> 2;
    for (int j = 0; j < jmax; ++j) {
      float4 e = eWL[wid][j * 4 + g];
      int sj = __float_as_int(e.w);
      float4 hr = *(const float4*)&h1[(size_t)sj * 64 + dq * 4];
      a0[0] += e.x * hr.x; a0[1] += e.x * hr.y; a0[2] += e.x * hr.z; a0[3] += e.x * hr.w;
      a1[0] += e.y * hr.x; a1[1] += e.y * hr.y; a1[2] += e.y * hr.z; a1[3] += e.y * hr.w;
      a2[0] += e.z * hr.x; a2[1] += e.z * hr.y; a2[2] += e.z * hr.z; a2[3] += e.z * hr.w;
    }
  }
  #pragma unroll
  for (int c = 0; c < 4; ++c) {
    a0[c] += __shfl_xor(a0[c], 16); a0[c] += __shfl_xor(a0[c], 32);
    a1[c] += __shfl_xor(a1[c], 16); a1[c] += __shfl_xor(a1[c], 32);
    a2[c] += __shfl_xor(a2[c], 16); a2[c] += __shfl_xor(a2[c], 32);
  }
  // redistribute to lane=dim layout
  int srcl = lane >> 2, cc = lane & 3;
  float t0, t1, t2, t3, r0, r1, r2;
  t0 = __shfl(a0[0], srcl); t1 = __shfl(a0[1], srcl);
  t2 = __shfl(a0[2], srcl); t3 = __shfl(a0[3], srcl);
  r0 = cc == 0 ? t0 : cc == 1 ? t1 : cc == 2 ? t2 : t3;
  t0 = __shfl(a1[0], srcl); t1 = __shfl(a1[1], srcl);
  t2 = __shfl(a1[2], srcl); t3 = __shfl(a1[3], srcl);
  r1 = cc == 0 ? t0 : cc == 1 ? t1 : cc == 2 ? t2 : t3;
  t0 = __shfl(a2[0], srcl); t1 = __shfl(a2[1], srcl);
  t2 = __shfl(a2[2], srcl); t3 = __shfl(a2[3], srcl);
  r2 = cc == 0 ? t0 : cc == 1 ? t1 : cc == 2 ? t2 : t3;

  float selfv = h1[(size_t)n * 64 + lane];
  float b1v = b1L[lane];
  dout[OFF_HID + ((size_t)0 * NN + n) * 64 + lane] = fmaxf(r0 + dd0 * dd0 * selfv + b1v, 0.f);
  dout[OFF_HID + ((size_t)1 * NN + n) * 64 + lane] = fmaxf(r1 + dd1 * dd1 * selfv + b1v, 0.f);
  dout[OFF_HID + ((size_t)2 * NN + n) * 64 + lane] = fmaxf(r2 + dd2 * dd2 * selfv + b1v, 0.f);
}

// ---- attention via MFMA: u = hid @ Wf per graph, tanh/qf epilogue, softmax ----
__global__ __launch_bounds__(256) void k_attnm(
    const void* Wf, const void* bfv, const void* qf,
    const int* __restrict__ flags, float* __restrict__ dout) {
  __shared__ short wft[3 * 64 * 72];   // Wf^T: [g][j][k], stride 72 shorts
  __shared__ float qfL[192], bfL[192];
  int tid = threadIdx.x, f32 = flags[0];
  for (int i = tid; i < 3 * 64 * 64; i += 256) {
    int g = i >> 12, rem = i & 4095, k = rem >> 6, j = rem & 63;
    wft[(g * 64 + j) * 72 + k] =
        (short)(f32 ? f2bf(((const float*)Wf)[i]) : ((const u16*)Wf)[i]);
  }
  if (tid < 192) { qfL[tid] = ldf(qf, tid, f32); bfL[tid] = ldf(bfv, tid, f32); }
  __syncthreads();
  int wid = tid >> 6, l = tid & 63;
  int rowT = blockIdx.x * 64 + wid * 16;
  int colb = l & 15, rg = l >> 4;
  int arow = rowT + colb;
  if (arow >= NN) arow = NN - 1;
  int koff = rg * 8;
  float p[3][4];
  #pragma unroll
  for (int g = 0; g < 3; ++g) {
    floatx4 acc[4];
    #pragma unroll
    for (int c = 0; c < 4; ++c) acc[c] = (floatx4){0.f, 0.f, 0.f, 0.f};
    #pragma unroll
    for (int kk = 0; kk < 2; ++kk) {
      int k0 = kk * 32 + koff;
      const float* hp = dout + OFF_HID + ((size_t)g * NN + arow) * 64 + k0;
      float4 lo = *(const float4*)hp;
      float4 hi = *(const float4*)(hp + 4);
      short8 a;
      a[0] = (short)f2bf(lo.x); a[1] = (short)f2bf(lo.y);
      a[2] = (short)f2bf(lo.z); a[3] = (short)f2bf(lo.w);
      a[4] = (short)f2bf(hi.x); a[5] = (short)f2bf(hi.y);
      a[6] = (short)f2bf(hi.z); a[7] = (short)f2bf(hi.w);
      #pragma unroll
      for (int c = 0; c < 4; ++c) {
        short8 b = *(const short8*)(&wft[((size_t)g * 64 + c * 16 + colb) * 72 + k0]);
        acc[c] = __builtin_amdgcn_mfma_f32_16x16x32_bf16(a, b, acc[c], 0, 0, 0);
      }
    }
    #pragma unroll
    for (int r = 0; r < 4; ++r) {
      float t = 0.f;
      #pragma unroll
      for (int c = 0; c < 4; ++c) {
        int j = c * 16 + colb;
        t += tanhf(acc[c][r] + bfL[g * 64 + j]) * qfL[g * 64 + j];
      }
      t += __shfl_xor(t, 1); t += __shfl_xor(t, 2);
      t += __shfl_xor(t, 4); t += __shfl_xor(t, 8);
      p[g][r] = t;
    }
  }
  #pragma unroll
  for (int r = 0; r < 4; ++r) {
    int rr = rowT + rg * 4 + r;
    if (rr >= NN) continue;
    float p0 = p[0][r], p1 = p[1][r], p2 = p[2][r];
    float mx = fmaxf(p0, fmaxf(p1, p2));
    float e0 = expf(p0 - mx), e1 = expf(p1 - mx), e2 = expf(p2 - mx);
    float inv = 1.0f / (e0 + e1 + e2);
    float aw0 = e0 * inv, aw1 = e1 * inv, aw2 = e2 * inv;
    float4 h0 = *(const float4*)(dout + OFF_HID + ((size_t)0 * NN + rr) * 64 + colb * 4);
    float4 h1 = *(const float4*)(dout + OFF_HID + ((size_t)1 * NN + rr) * 64 + colb * 4);
    float4 h2 = *(const float4*)(dout + OFF_HID + ((size_t)2 * NN + rr) * 64 + colb * 4);
    *(float4*)(dout + OFF_FUSED + (size_t)rr * 64 + colb * 4) =
        make_float4(aw0 * h0.x + aw1 * h1.x + aw2 * h2.x,
                    aw0 * h0.y + aw1 * h1.y + aw2 * h2.y,
                    aw0 * h0.z + aw1 * h1.z + aw2 * h2.z,
                    aw0 * h0.w + aw1 * h1.w + aw2 * h2.w);
    if (colb < 3)
      dout[OFF_ATTN + (size_t)rr * 3 + colb] = (colb == 0 ? aw0 : (colb == 1 ? aw1 : aw2));
  }
}

// ---- layer2 gather (packed LDS staging): agg = sym-aggregate(fused) ----
__global__ __launch_bounds__(256) void k_agg2(
    const int* __restrict__ csr_s, const float4* __restrict__ csr_w,
    const unsigned* __restrict__ row_ptr, const float* __restrict__ dis2,
    const float* __restrict__ dout, float* __restrict__ agg) {
  __shared__ uint2 eL[4][64];
  const float* fused = dout + OFF_FUSED;
  int tid = threadIdx.x, wid = tid >> 6, lane = tid & 63;
  int n = blockIdx.x * 4 + wid;
  if (n >= NN) return;
  float dd = dis2[n];
  float acc[4] = {0.f, 0.f, 0.f, 0.f};
  int g = lane >> 4, dq = lane & 15;
  unsigned beg = row_ptr[n], end = row_ptr[n + 1];
  for (unsigned base = beg; base < end; base += 64) {
    unsigned rem = end - base;
    int m = (rem > 64u) ? 64 : (int)rem;
    uint2 st = make_uint2(0u, 0u);
    if (lane < m)
      st = make_uint2((unsigned)csr_s[base + lane],
                      __float_as_uint(csr_w[base + lane].w * dd));
    eL[wid][lane] = st;
    int jmax = (m + 3) >> 2;
    for (int j = 0; j < jmax; ++j) {
      uint2 e = eL[wid][j * 4 + g];
      int sj = (int)e.x;
      float wj = __uint_as_float(e.y);
      float4 fr = *(const float4*)&fused[(size_t)sj * 64 + dq * 4];
      acc[0] += wj * fr.x; acc[1] += wj * fr.y;
      acc[2] += wj * fr.z; acc[3] += wj * fr.w;
    }
  }
  #pragma unroll
  for (int c = 0; c < 4; ++c) {
    acc[c] += __shfl_xor(acc[c], 16);
    acc[c] += __shfl_xor(acc[c], 32);
  }
  if (lane < 16) {
    float4 sf = *(const float4*)&fused[(size_t)n * 64 + lane * 4];
    float sw = dd * dd;
    *(float4*)&agg[(size_t)n * 64 + lane * 4] =
        make_float4(acc[0] + sw * sf.x, acc[1] + sw * sf.y,
                    acc[2] + sw * sf.z, acc[3] + sw * sf.w);
  }
}

// ---- emb = relu(agg @ W2 + b2) via MFMA: 64 rows/block, W2^T in LDS ----
__global__ __launch_bounds__(256) void k_emb2m(const float* __restrict__ agg,
                                               const void* W2, const void* b2,
                                               const int* __restrict__ flags,
                                               float* __restrict__ dout) {
  __shared__ short w2t[256 * 72];  // W2^T: [col][k], stride 72 shorts
  __shared__ float b2L[256];
  int tid = threadIdx.x, f32 = flags[0];
  for (int i = tid; i < 256 * 64; i += 256) {
    int col = i & 255, k = i >> 8;
    w2t[col * 72 + k] = (short)(f32 ? f2bf(((const float*)W2)[k * 256 + col])
                                    : ((const u16*)W2)[k * 256 + col]);
  }
  b2L[tid] = ldf(b2, tid, f32);
  __syncthreads();
  int wid = tid >> 6, l = tid & 63;
  int rowbase = blockIdx.x * 64 + wid * 16;
  int arow = rowbase + (l & 15);
  if (arow >= NN) arow = NN - 1;
  int koff = (l >> 4) * 8;
  floatx4 acc[16];
  #pragma unroll
  for (int c = 0; c < 16; ++c) acc[c] = (floatx4){0.f, 0.f, 0.f, 0.f};
  #pragma unroll
  for (int kk = 0; kk < 2; ++kk) {
    int k0 = kk * 32 + koff;
    const float* ap = agg + (size_t)arow * 64 + k0;
    float4 lo = *(const float4*)ap;
    float4 hi = *(const float4*)(ap + 4);
    short8 a;
    a[0] = (short)f2bf(lo.x); a[1] = (short)f2bf(lo.y);
    a[2] = (short)f2bf(lo.z); a[3] = (short)f2bf(lo.w);
    a[4] = (short)f2bf(hi.x); a[5] = (short)f2bf(hi.y);
    a[6] = (short)f2bf(hi.z); a[7] = (short)f2bf(hi.w);
    #pragma unroll
    for (int c = 0; c < 16; ++c) {
      short8 b = *(const short8*)(&w2t[(c * 16 + (l & 15)) * 72 + k0]);
      acc[c] = __builtin_amdgcn_mfma_f32_16x16x32_bf16(a, b, acc[c], 0, 0, 0);
    }
  }
  int r0 = rowbase + (l >> 4) * 4;
  int colb = l & 15;
  #pragma unroll
  for (int c = 0; c < 16; ++c) {
    float bb = b2L[c * 16 + colb];
    #pragma unroll
    for (int r = 0; r < 4; ++r) {
      int rr = r0 + r;
      if (rr < NN)
        dout[OFF_EMB + (size_t)rr * 256 + c * 16 + colb] = fmaxf(acc[c][r] + bb, 0.f);
    }
  }
}

// ---- vsum = gn @ fused via MFMA split-K: block = all 256 b x 64 j x 256 n ----
#define VST 40  // LDS tile stride in shorts (80 B: 16B-aligned, conflict-free 16-lane)
__global__ __launch_bounds__(256) void k_vsum(const void* gn,
                                              const float* __restrict__ dout,
                                              const int* __restrict__ flags,
                                              float* __restrict__ part,
                                              float* __restrict__ rspart) {
  __shared__ short gnT[256 * VST];  // [b][k] bf16
  __shared__ short fT[64 * VST];    // [j][k] bf16 (fused^T)
  const float* fused = dout + OFF_FUSED;
  int tid = threadIdx.x, f32 = flags[0];
  int sp = blockIdx.x;
  int nbase = sp * 256;
  int wid = tid >> 6, l = tid & 63;
  int colb = l & 15, rg = l >> 4;
  int koff = rg * 8;
  floatx4 acc[4][4];
  #pragma unroll
  for (int t = 0; t < 4; ++t)
    #pragma unroll
    for (int c = 0; c < 4; ++c) acc[t][c] = (floatx4){0.f, 0.f, 0.f, 0.f};
  float rs = 0.f;  // thread tid owns gn row b=tid row-sum (this chunk)
  for (int kk = 0; kk < 8; ++kk) {
    int n0 = nbase + kk * 32;
    __syncthreads();  // protect tiles from previous iteration's readers
    // stage gn row b=tid, k=0..31
    {
      float v[32];
      #pragma unroll
      for (int i = 0; i < 32; ++i) {
        int n = n0 + i;
        v[i] = (n < NN) ? ldf(gn, (size_t)tid * NN + n, f32) : 0.f;
        rs += v[i];
      }
      #pragma unroll
      for (int i = 0; i < 32; ++i) gnT[tid * VST + i] = (short)f2bf(v[i]);
    }
    // stage fused^T: 2048 elems; pass p covers k = p*16 + (tid>>4), j = (tid&15)*4
    #pragma unroll
    for (int p = 0; p < 2; ++p) {
      int k = p * 16 + (tid >> 4);
      int j = (tid & 15) * 4;
      int n = n0 + k;
      float4 fr = (n < NN) ? *(const float4*)&fused[(size_t)n * 64 + j]
                           : make_float4(0.f, 0.f, 0.f, 0.f);
      fT[(j + 0) * VST + k] = (short)f2bf(fr.x);
      fT[(j + 1) * VST + k] = (short)f2bf(fr.y);
      fT[(j + 2) * VST + k] = (short)f2bf(fr.z);
      fT[(j + 3) * VST + k] = (short)f2bf(fr.w);
    }
    __syncthreads();
    #pragma unroll
    for (int t = 0; t < 4; ++t) {
      int brow = (wid * 4 + t) * 16 + colb;
      short8 a = *(const short8*)(&gnT[brow * VST + koff]);
      #pragma unroll
      for (int c = 0; c < 4; ++c) {
        short8 b = *(const short8*)(&fT[(c * 16 + colb) * VST + koff]);
        acc[t][c] = __builtin_amdgcn_mfma_f32_16x16x32_bf16(a, b, acc[t][c], 0, 0, 0);
      }
    }
  }
  rspart[(size_t)sp * 256 + tid] = rs;
  #pragma unroll
  for (int t = 0; t < 4; ++t) {
    int rbase = (wid * 4 + t) * 16 + rg * 4;
    #pragma unroll
    for (int c = 0; c < 4; ++c)
      #pragma unroll
      for (int r = 0; r < 4; ++r)
        part[((size_t)sp * 256 + rbase + r) * 64 + c * 16 + colb] = acc[t][c][r];
  }
}

// ---- g finalize: reduce partials, divide by row_sum, L2 normalize ----
__global__ __launch_bounds__(64) void k_gfinal(const float* __restrict__ part,
                                               const float* __restrict__ rspart,
                                               float* __restrict__ dout) {
  int b = blockIdx.x, j = threadIdx.x;
  float acc = 0.f;
  for (int k = 0; k < VS_SP; ++k) acc += part[((size_t)k * 256 + b) * 64 + j];
  float rs = 0.f;
  for (int k = 0; k < VS_SP; ++k) rs += rspart[(size_t)k * 256 + b];
  float v = acc / rs;
  float sq = v * v;
  #pragma unroll
  for (int off = 32; off > 0; off >>= 1) sq += __shfl_xor(sq, off);
  float nrm = sqrtf(sq);
  dout[OFF_G + (size_t)b * 64 + j] = v / fmaxf(nrm, 1e-12f);
}

extern "C" void kernel_launch(void* const* d_in, const int* in_sizes, int n_in,
                              void* d_out, int out_size, void* d_ws, size_t ws_size,
                              hipStream_t stream) {
  const void* x   = d_in[0];
  const void* ei  = d_in[1];
  const void* gn  = d_in[2];
  const void* aew = d_in[3];
  const void* W1  = d_in[4];
  const void* b1  = d_in[5];
  const void* W2  = d_in[6];
  const void* b2  = d_in[7];
  const void* Wf  = d_in[8];
  const void* bfv = d_in[9];
  const void* qf  = d_in[10];

  char* ws = (char*)d_ws;
  size_t off = 0;
  auto alloc = [&](size_t bytes) -> void* {
    void* p = ws + off;
    off += (bytes + 255) & ~(size_t)255;
    return p;
  };
  // zero-init region (atomically accumulated buffers only)
  unsigned* cnt     = (unsigned*)alloc((size_t)NN * 4);
  unsigned* fill    = (unsigned*)alloc((size_t)NN * 4);
  size_t zero_bytes = off;
  float*    deg     = (float*)alloc((size_t)3 * NN * 4);
  int*      flags   = (int*)alloc(64);
  float*    dis2    = (float*)alloc((size_t)NN * 4);
  unsigned* row_ptr = (unsigned*)alloc((size_t)(NN + 1) * 4);
  unsigned* bsum    = (unsigned*)alloc((size_t)NSCB * 4);
  unsigned* boff    = (unsigned*)alloc((size_t)NSCB * 4);
  int*      csr_s   = (int*)alloc((size_t)NE * 4);
  float4*   csr_w   = (float4*)alloc((size_t)NE * 16);
  // time-shared region: h1 (k_h1m->k_gath1), agg (k_agg2->k_emb2m), part (k_vsum->k_gfinal)
  size_t regA_bytes = (size_t)VS_SP * NB * 64 * 4;  // 12.85 MB
  char*  regA       = (char*)alloc(regA_bytes);
  float* h1   = (float*)regA;
  float* agg  = (float*)regA;
  float* part = (float*)regA;
  float* rspart = (float*)alloc((size_t)VS_SP * NB * 4);

  float* dout = (float*)d_out;

  hipMemsetAsync(d_ws, 0, zero_bytes, stream);
  k_detect<<<1, 64, 0, stream>>>(x, ei, flags);
  k_cnt<<<(NE + 255) / 256, 256, 0, stream>>>(ei, flags, cnt);
  k_sc1<<<NSCB, 256, 0, stream>>>(cnt, bsum);
  k_sc2<<<1, 256, 0, stream>>>(bsum, boff, row_ptr);
  k_sc3<<<NSCB, 256, 0, stream>>>(cnt, boff, row_ptr);
  k_fill<<<(NE + 255) / 256, 256, 0, stream>>>(ei, flags, row_ptr, aew, fill,
                                               csr_s, csr_w);
  k_degsum<<<NN / 16, 256, 0, stream>>>(row_ptr, csr_w, deg);
  k_dis<<<(3 * NN + 255) / 256, 256, 0, stream>>>(deg, cnt, dis2);
  k_norm<<<(NE + 255) / 256, 256, 0, stream>>>(csr_s, deg, dis2, csr_w);
  k_h1m<<<(NN + 63) / 64, 256, 0, stream>>>(x, W1, flags, h1);
  k_gath1<<<(NN + 3) / 4, 256, 0, stream>>>(h1, csr_s, csr_w, row_ptr, deg, b1,
                                            flags, dout);
  k_attnm<<<(NN + 63) / 64, 256, 0, stream>>>(Wf, bfv, qf, flags, dout);
  k_agg2<<<(NN + 3) / 4, 256, 0, stream>>>(csr_s, csr_w, row_ptr, dis2, dout, agg);
  k_emb2m<<<(NN + 63) / 64, 256, 0, stream>>>(agg, W2, b2, flags, dout);
  k_vsum<<<VS_SP, 256, 0, stream>>>(gn, dout, flags, part, rspart);
  k_gfinal<<<NB, 64, 0, stream>>>(part, rspart, dout);
}